// Round 5
// baseline (572.115 us; speedup 1.0000x reference)
//
#include <hip/hip_runtime.h>
#include <cstddef>

// IPA + surface cross-attention, B=1, N=512, M=2048, H=12, C_H=16, C_S=384.
// Round 3: split monolithic k_attn (139us, latency-bound, serial phase4)
// into k_attn_a (logits+wave-softmax) / k_attn_pair / k_gemm_ov / k_optfin.

#define CS 384
#define INFV 100000.0f

__device__ __forceinline__ float softplusf(float x) { return log1pf(__expf(x)); }

// ---------------------------------------------------------------- pack
__global__ __launch_bounds__(256) void k_pack(
    const float* __restrict__ Wq, const float* __restrict__ Wsq,
    const float* __restrict__ Wkv, const float* __restrict__ Wqp,
    const float* __restrict__ Wkvp, const float* __restrict__ Wsk,
    const float* __restrict__ Wsv, const float* __restrict__ Wout,
    const float* __restrict__ bq, const float* __restrict__ bsq,
    const float* __restrict__ bkv, const float* __restrict__ bqp,
    const float* __restrict__ bkvp, const float* __restrict__ bsk,
    const float* __restrict__ bsv,
    float* __restrict__ wt1, float* __restrict__ wt2, float* __restrict__ wt3,
    float* __restrict__ b1, float* __restrict__ b2)
{
    const int b = blockIdx.x, t = threadIdx.x;
    if (b >= 1092) {
        int idx = (b - 1092) * 256 + t;
        if (idx < 1344) {
            float v;
            if (idx < 192) v = bq[idx];
            else if (idx < 384) v = bsq[idx - 192];
            else if (idx < 768) v = bkv[idx - 384];
            else if (idx < 912) v = bqp[idx - 768];
            else v = bkvp[idx - 912];
            b1[idx] = v;
        } else if (idx < 1728) {
            int i2 = idx - 1344;
            b2[i2] = (i2 < 192) ? bsk[i2] : bsv[i2 - 192];
        }
        return;
    }
    const float* src; float* dst; int C, coff, tile, ldd;
    if (b < 72)       { src = Wq;   C = 192; dst = wt1; coff = 0;   ldd = 384;  tile = b; }
    else if (b < 144) { src = Wsq;  C = 192; dst = wt1; coff = 192; ldd = 384;  tile = b - 72; }
    else if (b < 288) { src = Wkv;  C = 384; dst = wt1; coff = 384; ldd = 384;  tile = b - 144; }
    else if (b < 348) { src = Wqp;  C = 144; dst = wt1; coff = 768; ldd = 384;  tile = b - 288; }
    else if (b < 516) { src = Wkvp; C = 432; dst = wt1; coff = 912; ldd = 384;  tile = b - 348; }
    else if (b < 588) { src = Wsk;  C = 192; dst = wt2; coff = 0;   ldd = 384;  tile = b - 516; }
    else if (b < 660) { src = Wsv;  C = 192; dst = wt2; coff = 192; ldd = 384;  tile = b - 588; }
    else              { src = Wout; C = 384; dst = wt3; coff = 0;   ldd = 1152; tile = b - 660; }
    const int cT = (C + 31) >> 5;
    const int tk = tile / cT, tc = tile % cT;
    __shared__ float l[32][33];
    const int tr = t >> 5, tcc = t & 31;
    #pragma unroll
    for (int rr = 0; rr < 4; ++rr) {
        int kloc = tr * 4 + rr;
        int cg = tc * 32 + tcc;
        l[kloc][tcc] = (cg < C) ? src[(size_t)(tk * 32 + kloc) * C + cg] : 0.f;
    }
    __syncthreads();
    #pragma unroll
    for (int rr = 0; rr < 4; ++rr) {
        int cloc = tr * 4 + rr;
        int cg = tc * 32 + cloc;
        if (cg < C) dst[(size_t)(coff + cg) * ldd + tk * 32 + tcc] = l[tcc][cloc];
    }
}

// ---------------------------------------------------------------- transpose
__global__ __launch_bounds__(256) void k_transp(
    const float* __restrict__ A, float* __restrict__ At)
{
    __shared__ float tile[32][33];
    const int r0 = blockIdx.y * 32, c0 = blockIdx.x * 32;
    const int tr = threadIdx.x >> 5, tc = threadIdx.x & 31;
    #pragma unroll
    for (int rr = 0; rr < 4; ++rr)
        tile[tr + rr * 8][tc] = A[(size_t)(r0 + tr + rr * 8) * 384 + c0 + tc];
    __syncthreads();
    #pragma unroll
    for (int rr = 0; rr < 4; ++rr)
        At[(size_t)(c0 + tr + rr * 8) * 512 + r0 + tc] = tile[tc][tr + rr * 8];
}

// ---------------------------------------------------------------- gemm
template<int KTOT, bool HB>
__global__ __launch_bounds__(256) void k_gemm(
    const float* __restrict__ A, const float* __restrict__ Wt,
    const float* __restrict__ bias, float* __restrict__ C, int ldc)
{
    __shared__ float As[64][68];
    __shared__ float Ws[64][68];
    const int t = threadIdx.x;
    const int c0 = blockIdx.x * 64, m0 = blockIdx.y * 64;
    const int sr = t >> 4, sk4 = (t & 15) << 2;
    const int wid = t >> 6, lane = t & 63;
    const int wr = (wid >> 1) * 32, wc = (wid & 1) * 32;
    const int lr = lane >> 3, lc = lane & 7;
    float acc[4][4];
    #pragma unroll
    for (int j = 0; j < 4; ++j) {
        float bv = HB ? bias[c0 + wc + lc + 8 * j] : 0.f;
        #pragma unroll
        for (int i = 0; i < 4; ++i) acc[i][j] = bv;
    }
    for (int kc = 0; kc < KTOT; kc += 64) {
        __syncthreads();
        #pragma unroll
        for (int rep = 0; rep < 4; ++rep) {
            int row = sr + rep * 16;
            *(float4*)&As[row][sk4] = *(const float4*)&A[(size_t)(m0 + row) * KTOT + kc + sk4];
            *(float4*)&Ws[row][sk4] = *(const float4*)&Wt[(size_t)(c0 + row) * KTOT + kc + sk4];
        }
        __syncthreads();
        #pragma unroll 4
        for (int k4 = 0; k4 < 16; ++k4) {
            float4 a[4], w[4];
            #pragma unroll
            for (int i = 0; i < 4; ++i) a[i] = *(float4*)&As[wr + lr + 8 * i][k4 * 4];
            #pragma unroll
            for (int j = 0; j < 4; ++j) w[j] = *(float4*)&Ws[wc + lc + 8 * j][k4 * 4];
            #pragma unroll
            for (int i = 0; i < 4; ++i) {
                #pragma unroll
                for (int j = 0; j < 4; ++j) {
                    acc[i][j] = fmaf(a[i].x, w[j].x, acc[i][j]);
                    acc[i][j] = fmaf(a[i].y, w[j].y, acc[i][j]);
                    acc[i][j] = fmaf(a[i].z, w[j].z, acc[i][j]);
                    acc[i][j] = fmaf(a[i].w, w[j].w, acc[i][j]);
                }
            }
        }
    }
    #pragma unroll
    for (int i = 0; i < 4; ++i) {
        #pragma unroll
        for (int j = 0; j < 4; ++j)
            C[(size_t)(m0 + wr + lr + 8 * i) * ldc + c0 + wc + lc + 8 * j] = acc[i][j];
    }
}

// ---------------------------------------------------------------- scatter
__global__ __launch_bounds__(256) void k_scatter(
    const float* __restrict__ proj, const float* __restrict__ rots,
    const float* __restrict__ trans,
    float* __restrict__ qw, float* __restrict__ kw, float* __restrict__ vw,
    float* __restrict__ sqw, float* __restrict__ qpw, float* __restrict__ kpw,
    float* __restrict__ vpw)
{
    __shared__ float p[4][1344];
    const int n0 = blockIdx.x * 4, t = threadIdx.x;
    for (int idx = t; idx < 1344; idx += 256) {
        #pragma unroll
        for (int r = 0; r < 4; ++r) p[r][idx] = proj[(size_t)(n0 + r) * 1344 + idx];
    }
    __syncthreads();
    for (int idx = t; idx < 3072; idx += 256) {
        int r = idx / 768, c = idx % 768;
        int n = n0 + r;
        float v = p[r][c];
        if (c < 192) qw[(size_t)n * 192 + c] = v;
        else if (c < 384) sqw[(size_t)n * 192 + (c - 192)] = v;
        else {
            int cc = c - 384, h = cc >> 5, sub = cc & 31;
            if (sub < 16) kw[(size_t)n * 192 + h * 16 + sub] = v;
            else          vw[(size_t)n * 192 + h * 16 + (sub - 16)] = v;
        }
    }
    for (int idx = t; idx < 2304; idx += 256) {
        int r = idx / 576, rem = idx % 576;
        int n = n0 + r;
        const float* R = &rots[(size_t)n * 9];
        const float* tr = &trans[(size_t)n * 3];
        if (rem < 144) {
            int pp = rem / 3, d = rem % 3;
            float v = fmaf(R[d*3+0], p[r][768 + pp],
                      fmaf(R[d*3+1], p[r][768 + 48 + pp],
                      fmaf(R[d*3+2], p[r][768 + 96 + pp], tr[d])));
            qpw[(size_t)n * 144 + pp * 3 + d] = v;
        } else {
            int rem2 = rem - 144; int pp = rem2 / 3, d = rem2 % 3;
            float v = fmaf(R[d*3+0], p[r][912 + pp],
                      fmaf(R[d*3+1], p[r][912 + 144 + pp],
                      fmaf(R[d*3+2], p[r][912 + 288 + pp], tr[d])));
            int h = pp / 12, ii = pp % 12;
            if (ii < 4) kpw[(size_t)n * 144 + h * 12 + ii * 3 + d] = v;
            else        vpw[(size_t)n * 288 + h * 24 + (ii - 4) * 3 + d] = v;
        }
    }
}

// ---------------------------------------------------------------- sfeat
__global__ __launch_bounds__(256) void k_sfeat(
    const float* __restrict__ sf, const float* __restrict__ Wse,
    const float* __restrict__ bse, float* __restrict__ sfeat)
{
    __shared__ float wl[16 * 384];
    __shared__ float sfl[8][16];
    const int m0 = blockIdx.x * 8, t = threadIdx.x;
    for (int idx = t; idx < 6144; idx += 256) wl[idx] = Wse[idx];
    if (t < 128) sfl[t >> 4][t & 15] = sf[(size_t)(m0 + (t >> 4)) * 16 + (t & 15)];
    __syncthreads();
    #pragma unroll
    for (int u = 0; u < 12; ++u) {
        int idx = t + u * 256;
        int r = idx / 384, c = idx % 384;
        float a = bse[c];
        #pragma unroll
        for (int kk = 0; kk < 16; ++kk) a = fmaf(sfl[r][kk], wl[kk * 384 + c], a);
        sfeat[(size_t)(m0 + r) * 384 + c] = a;
    }
}

// ---------------------------------------------------------------- zpass
__global__ __launch_bounds__(256) void k_zpass(
    const float* __restrict__ z, const float* __restrict__ Wb, const float* __restrict__ bb,
    const float* __restrict__ Wdz, const float* __restrict__ bdz, float* __restrict__ bpz)
{
    __shared__ float Wt[44][128];
    __shared__ float bias_s[44];
    __shared__ float zt[64][132];
    const int i = blockIdx.x, t = threadIdx.x;
    const float s3 = 0.5773502691896258f;
    for (int idx = t; idx < 44 * 128; idx += 256) {
        int c = idx >> 7, kk = idx & 127;
        Wt[c][kk] = (c < 12) ? s3 * Wb[kk * 12 + c] : Wdz[kk * 32 + (c - 12)];
    }
    if (t < 44) bias_s[t] = (t < 12) ? s3 * bb[t] : bdz[t - 12];
    const int jl = t & 63, cg = t >> 6;
    for (int j0 = 0; j0 < 512; j0 += 64) {
        __syncthreads();
        for (int idx = t; idx < 2048; idx += 256) {
            int r = idx >> 5, c4 = (idx & 31) << 2;
            *(float4*)&zt[r][c4] = *(const float4*)&z[((size_t)i * 512 + j0 + r) * 128 + c4];
        }
        __syncthreads();
        float acc[11];
        #pragma unroll
        for (int u = 0; u < 11; ++u) acc[u] = bias_s[cg * 11 + u];
        #pragma unroll 2
        for (int k4 = 0; k4 < 128; k4 += 4) {
            float4 zv = *(float4*)&zt[jl][k4];
            #pragma unroll
            for (int u = 0; u < 11; ++u) {
                float4 wv = *(float4*)&Wt[cg * 11 + u][k4];
                acc[u] = fmaf(zv.x, wv.x, acc[u]);
                acc[u] = fmaf(zv.y, wv.y, acc[u]);
                acc[u] = fmaf(zv.z, wv.z, acc[u]);
                acc[u] = fmaf(zv.w, wv.w, acc[u]);
            }
        }
        #pragma unroll
        for (int u = 0; u < 11; ++u)
            bpz[((size_t)i * 44 + cg * 11 + u) * 512 + j0 + jl] = acc[u];
    }
}

// ---------------------------------------------------------------- attn_a
// logits + per-wave softmax for 4 heads; writes a[h][i][j] (post-softmax).
__global__ __launch_bounds__(256) void k_attn_a(
    const float* __restrict__ qw, const float* __restrict__ kw,
    const float* __restrict__ qpw, const float* __restrict__ kpw,
    const float* __restrict__ bpz, const float* __restrict__ mask,
    const float* __restrict__ hwp, float* __restrict__ abuf)
{
    __shared__ float pls[4][520];
    __shared__ float qs[64], qps[48], cpt4[4];
    const int i = blockIdx.x, hg = blockIdx.y;
    const int t = threadIdx.x;
    if (t < 64) qs[t] = qw[(size_t)i * 192 + hg * 64 + t];
    if (t < 48) qps[t] = qpw[(size_t)i * 144 + hg * 48 + t];
    if (t < 4) cpt4[t] = -0.5f * 0.13608276348795434f * softplusf(hwp[hg * 4 + t]);
    const float mask_i = mask[i];
    __syncthreads();
    #pragma unroll 2
    for (int it = 0; it < 8; ++it) {
        int idx = t + it * 256;
        int hh = idx >> 9, j = idx & 511;
        int h = hg * 4 + hh;
        float kj[16], kpj[12];
        { const float4* kr = (const float4*)&kw[(size_t)j * 192 + h * 16];
          *(float4*)&kj[0] = kr[0]; *(float4*)&kj[4] = kr[1];
          *(float4*)&kj[8] = kr[2]; *(float4*)&kj[12] = kr[3]; }
        { const float4* kr = (const float4*)&kpw[(size_t)j * 144 + h * 12];
          *(float4*)&kpj[0] = kr[0]; *(float4*)&kpj[4] = kr[1]; *(float4*)&kpj[8] = kr[2]; }
        float qk = 0.f;
        #pragma unroll
        for (int c = 0; c < 16; ++c) qk = fmaf(qs[hh * 16 + c], kj[c], qk);
        float pts = 0.f;
        #pragma unroll
        for (int p = 0; p < 4; ++p) {
            float dx = qps[hh*12+p*3+0] - kpj[p*3+0];
            float dy = qps[hh*12+p*3+1] - kpj[p*3+1];
            float dz = qps[hh*12+p*3+2] - kpj[p*3+2];
            pts += dx*dx + dy*dy + dz*dz;
        }
        float lg = fmaf(0.14433756729740643f, qk, bpz[((size_t)i * 44 + h) * 512 + j]);
        lg = fmaf(cpt4[hh], pts, lg);
        lg += INFV * (mask_i * mask[j] - 1.0f);
        pls[hh][j] = lg;
    }
    __syncthreads();
    // per-wave softmax: wave w handles head hg*4+w, no further barriers
    const int w = t >> 6, lane = t & 63;
    float v[8];
    #pragma unroll
    for (int k = 0; k < 8; ++k) v[k] = pls[w][lane + k * 64];
    float mx = v[0];
    #pragma unroll
    for (int k = 1; k < 8; ++k) mx = fmaxf(mx, v[k]);
    #pragma unroll
    for (int off = 32; off; off >>= 1) mx = fmaxf(mx, __shfl_xor(mx, off));
    float sm = 0.f;
    #pragma unroll
    for (int k = 0; k < 8; ++k) { v[k] = __expf(v[k] - mx); sm += v[k]; }
    #pragma unroll
    for (int off = 32; off; off >>= 1) sm += __shfl_xor(sm, off);
    const float inv = 1.0f / sm;
    float* dst = abuf + ((size_t)(hg * 4 + w) * 512 + i) * 512;
    #pragma unroll
    for (int k = 0; k < 8; ++k) dst[lane + k * 64] = v[k] * inv;
}

// ---------------------------------------------------------------- attn_pair
// o_pair[h][c] = sum_j a[h][j] * pz[c][j]; a staged in LDS (broadcast reads).
__global__ __launch_bounds__(256) void k_attn_pair(
    const float* __restrict__ abuf, const float* __restrict__ bpz,
    float* __restrict__ ocat)
{
    __shared__ float al[12][512];
    const int i = blockIdx.x, t = threadIdx.x;
    #pragma unroll
    for (int u = 0; u < 12; ++u) {
        al[u][t] = abuf[(size_t)u * 262144 + (size_t)i * 512 + t];
        al[u][t + 256] = abuf[(size_t)u * 262144 + (size_t)i * 512 + t + 256];
    }
    __syncthreads();
    const int c = t & 31;
    const int h1 = t >> 5;             // 0..7
    const bool dual = (t < 128);       // also handles h1+8 (8..11)
    const float* pz = bpz + ((size_t)i * 44 + 12 + c) * 512;
    const float* a1 = al[h1];
    const float* a2 = al[dual ? h1 + 8 : 0];
    float acc1 = 0.f, acc2 = 0.f;
    for (int j = 0; j < 512; j += 4) {
        float4 p = *(const float4*)&pz[j];
        acc1 = fmaf(a1[j+0], p.x, acc1);
        acc1 = fmaf(a1[j+1], p.y, acc1);
        acc1 = fmaf(a1[j+2], p.z, acc1);
        acc1 = fmaf(a1[j+3], p.w, acc1);
        if (dual) {
            acc2 = fmaf(a2[j+0], p.x, acc2);
            acc2 = fmaf(a2[j+1], p.y, acc2);
            acc2 = fmaf(a2[j+2], p.z, acc2);
            acc2 = fmaf(a2[j+3], p.w, acc2);
        }
    }
    ocat[(size_t)i * 1152 + 576 + h1 * 32 + c] = acc1;
    if (dual) ocat[(size_t)i * 1152 + 576 + (h1 + 8) * 32 + c] = acc2;
}

// ---------------------------------------------------------------- gemm_ov
// per-head: C_h[512 i][40] = A_h[512 i][512 j] @ [v_h(16) | vp_h(24)]
__global__ __launch_bounds__(256) void k_gemm_ov(
    const float* __restrict__ abuf, const float* __restrict__ vw,
    const float* __restrict__ vpw, float* __restrict__ cbuf)
{
    __shared__ float As[64][68];
    __shared__ float Bs[64][44];
    const int i0 = blockIdx.x * 64, h = blockIdx.y;
    const int t = threadIdx.x;
    const int sr = t >> 4, sk4 = (t & 15) << 2;
    const int r1 = t >> 3;        // 0..31 (also r1+32)
    const int cb = t & 7;
    float acc[2][5];
    #pragma unroll
    for (int u = 0; u < 5; ++u) { acc[0][u] = 0.f; acc[1][u] = 0.f; }
    for (int kc = 0; kc < 512; kc += 64) {
        __syncthreads();
        #pragma unroll
        for (int rep = 0; rep < 4; ++rep) {
            int row = sr + rep * 16;
            *(float4*)&As[row][sk4] =
                *(const float4*)&abuf[(size_t)h * 262144 + (size_t)(i0 + row) * 512 + kc + sk4];
        }
        #pragma unroll
        for (int u = 0; u < 10; ++u) {
            int idx = t + u * 256;
            int r = idx / 40, cc = idx % 40;
            Bs[r][cc] = (cc < 16) ? vw[(size_t)(kc + r) * 192 + h * 16 + cc]
                                  : vpw[(size_t)(kc + r) * 288 + h * 24 + (cc - 16)];
        }
        __syncthreads();
        #pragma unroll 4
        for (int kk = 0; kk < 64; ++kk) {
            float av1 = As[r1][kk], av2 = As[r1 + 32][kk];
            #pragma unroll
            for (int u = 0; u < 5; ++u) {
                float b = Bs[kk][cb + 8 * u];
                acc[0][u] = fmaf(av1, b, acc[0][u]);
                acc[1][u] = fmaf(av2, b, acc[1][u]);
            }
        }
    }
    #pragma unroll
    for (int u = 0; u < 5; ++u) {
        cbuf[((size_t)h * 512 + i0 + r1) * 40 + cb + 8 * u] = acc[0][u];
        cbuf[((size_t)h * 512 + i0 + r1 + 32) * 40 + cb + 8 * u] = acc[1][u];
    }
}

// ---------------------------------------------------------------- optfin
__global__ __launch_bounds__(256) void k_optfin(
    const float* __restrict__ cbuf, const float* __restrict__ rots,
    const float* __restrict__ trans, float* __restrict__ ocat)
{
    __shared__ float cl[4][12][40];
    const int i0 = blockIdx.x * 4, t = threadIdx.x;
    for (int idx = t; idx < 1920; idx += 256) {
        int ii = idx / 480, rem = idx % 480;
        int h = rem / 40, c = rem % 40;
        cl[ii][h][c] = cbuf[((size_t)h * 512 + i0 + ii) * 40 + c];
    }
    __syncthreads();
    for (int idx = t; idx < 768; idx += 256) {
        int ii = idx / 192, o = idx % 192;
        ocat[(size_t)(i0 + ii) * 1152 + o] = cl[ii][o >> 4][o & 15];
    }
    for (int idx = t; idx < 384; idx += 256) {
        int ii = idx / 96, hp = idx % 96;
        int h = hp >> 3, p = hp & 7;
        int i = i0 + ii;
        const float* R = &rots[(size_t)i * 9];
        float gx = cl[ii][h][16 + p*3 + 0] - trans[(size_t)i*3 + 0];
        float gy = cl[ii][h][16 + p*3 + 1] - trans[(size_t)i*3 + 1];
        float gz = cl[ii][h][16 + p*3 + 2] - trans[(size_t)i*3 + 2];
        float lx = R[0]*gx + R[3]*gy + R[6]*gz;
        float ly = R[1]*gx + R[4]*gy + R[7]*gz;
        float lz = R[2]*gx + R[5]*gy + R[8]*gz;
        float nm = sqrtf(lx*lx + ly*ly + lz*lz + 1e-8f);
        int col = h * 8 + p;
        size_t base = (size_t)i * 1152;
        ocat[base + 192 + col] = lx;
        ocat[base + 288 + col] = ly;
        ocat[base + 384 + col] = lz;
        ocat[base + 480 + col] = nm;
    }
}

// ---------------------------------------------------------------- surf attn (single-pass flash)
__global__ __launch_bounds__(256) void k_surf(
    const float* __restrict__ sqw, const float* __restrict__ skv,
    const float* __restrict__ trans, const float* __restrict__ mask,
    const float* __restrict__ sp, const float* __restrict__ smask,
    const float* __restrict__ sbwp, float* __restrict__ ocat)
{
    __shared__ float sk_t[256][17];
    __shared__ float sv_t[256][17];
    __shared__ float sp_t[768];
    __shared__ float smask_t[256];
    const int h = blockIdx.x >> 5;
    const int n0 = (blockIdx.x & 31) * 16;
    const int t = threadIdx.x;
    const int tn = t >> 4, tm = t & 15;
    const int n = n0 + tn;
    const float sbw = softplusf(sbwp[0]);
    float qreg[16];
    #pragma unroll
    for (int c = 0; c < 16; ++c) qreg[c] = sqw[(size_t)n * 192 + h * 16 + c];
    const float trx = trans[(size_t)n*3+0], tryy = trans[(size_t)n*3+1], trz = trans[(size_t)n*3+2];
    const float mask_n = mask[n];
    float mx = -1e30f, l = 0.f;
    float acc[16];
    #pragma unroll
    for (int c = 0; c < 16; ++c) acc[c] = 0.f;
    for (int tile = 0; tile < 8; ++tile) {
        __syncthreads();
        const int mb = tile * 256;
        for (int idx = t; idx < 1024; idx += 256) {
            int ml = idx >> 2, c4 = (idx & 3) << 2;
            float4 v4 = *(const float4*)&skv[(size_t)(mb + ml) * 384 + h * 16 + c4];
            sk_t[ml][c4+0]=v4.x; sk_t[ml][c4+1]=v4.y; sk_t[ml][c4+2]=v4.z; sk_t[ml][c4+3]=v4.w;
            float4 w4 = *(const float4*)&skv[(size_t)(mb + ml) * 384 + 192 + h * 16 + c4];
            sv_t[ml][c4+0]=w4.x; sv_t[ml][c4+1]=w4.y; sv_t[ml][c4+2]=w4.z; sv_t[ml][c4+3]=w4.w;
        }
        for (int idx = t; idx < 768; idx += 256) sp_t[idx] = sp[(size_t)mb * 3 + idx];
        smask_t[t] = smask[mb + t];
        __syncthreads();
        float lgr[16];
        float tmax = -1e30f;
        #pragma unroll
        for (int kk = 0; kk < 16; ++kk) {
            int ml = tm + (kk << 4);
            float dot = 0.f;
            #pragma unroll
            for (int c = 0; c < 16; ++c) dot = fmaf(qreg[c], sk_t[ml][c], dot);
            float dx = trx - sp_t[ml*3+0], dy = tryy - sp_t[ml*3+1], dz = trz - sp_t[ml*3+2];
            float lg = fmaf(0.25f, dot, -0.5f * sbw * (dx*dx + dy*dy + dz*dz));
            lg += INFV * (mask_n * smask_t[ml] - 1.0f);
            lgr[kk] = lg;
            tmax = fmaxf(tmax, lg);
        }
        float mn = fmaxf(mx, tmax);
        float scale = __expf(mx - mn);
        l *= scale;
        #pragma unroll
        for (int c = 0; c < 16; ++c) acc[c] *= scale;
        #pragma unroll
        for (int kk = 0; kk < 16; ++kk) {
            int ml = tm + (kk << 4);
            float w = __expf(lgr[kk] - mn);
            l += w;
            #pragma unroll
            for (int c = 0; c < 16; ++c) acc[c] = fmaf(w, sv_t[ml][c], acc[c]);
        }
        mx = mn;
    }
    #pragma unroll
    for (int off = 1; off < 16; off <<= 1) {
        float m2 = __shfl_xor(mx, off), l2 = __shfl_xor(l, off);
        float mn = fmaxf(mx, m2);
        float e1 = __expf(mx - mn), e2 = __expf(m2 - mn);
        l = l * e1 + l2 * e2;
        #pragma unroll
        for (int c = 0; c < 16; ++c) {
            float a2 = __shfl_xor(acc[c], off);
            acc[c] = acc[c] * e1 + a2 * e2;
        }
        mx = mn;
    }
    const float invl = 1.0f / l;
    float outv = 0.f;
    #pragma unroll
    for (int c = 0; c < 16; ++c) if (tm == c) outv = acc[c];
    ocat[(size_t)n * 1152 + 960 + h * 16 + tm] = outv * invl;
}

// ---------------------------------------------------------------- tlog
__global__ __launch_bounds__(256) void k_tlog(
    const float* __restrict__ sqw, const float* __restrict__ skv,
    const float* __restrict__ trans, const float* __restrict__ mask,
    const float* __restrict__ sp, const float* __restrict__ smask,
    const float* __restrict__ sbwp, float* __restrict__ logits,
    float* __restrict__ stat_m, float* __restrict__ stat_il)
{
    __shared__ float sk_s[32][16];
    __shared__ float sq_s[32][16];
    __shared__ float trans_s[96];
    __shared__ float mask_s[32];
    __shared__ float spm_s[96];
    __shared__ float smask_s[32];
    const int h = blockIdx.y;
    const int m0 = blockIdx.x * 32;
    const int t = threadIdx.x;
    const int tmg = t >> 5, tnl = t & 31;
    const float sbw = softplusf(sbwp[0]);
    for (int idx = t; idx < 512; idx += 256) {
        int row = idx >> 4, c = idx & 15;
        sk_s[row][c] = skv[(size_t)(m0 + row) * 384 + h * 16 + c];
    }
    if (t < 96) spm_s[t] = sp[(size_t)m0 * 3 + t];
    if (t < 32) smask_s[t] = smask[m0 + t];
    __syncthreads();
    float skr[4][16];
    float spx[4], spy[4], spz[4], smk[4];
    #pragma unroll
    for (int mi = 0; mi < 4; ++mi) {
        int row = tmg * 4 + mi;
        #pragma unroll
        for (int c4 = 0; c4 < 16; c4 += 4)
            *(float4*)&skr[mi][c4] = *(float4*)&sk_s[row][c4];
        spx[mi] = spm_s[row*3+0]; spy[mi] = spm_s[row*3+1]; spz[mi] = spm_s[row*3+2];
        smk[mi] = smask_s[row];
    }
    float mxr[4], lr[4];
    #pragma unroll
    for (int mi = 0; mi < 4; ++mi) { mxr[mi] = -1e30f; lr[mi] = 0.f; }
    for (int nt = 0; nt < 16; ++nt) {
        __syncthreads();
        const int nb = nt * 32;
        if (t < 128) {
            int nn = t >> 2, c4 = (t & 3) << 2;
            *(float4*)&sq_s[nn][c4] = *(const float4*)&sqw[(size_t)(nb + nn) * 192 + h * 16 + c4];
        }
        if (t < 96) trans_s[t] = trans[(size_t)nb * 3 + t];
        if (t < 32) mask_s[t] = mask[nb + t];
        __syncthreads();
        float q[16];
        #pragma unroll
        for (int c4 = 0; c4 < 16; c4 += 4)
            *(float4*)&q[c4] = *(float4*)&sq_s[tnl][c4];
        const float tx = trans_s[tnl*3+0], ty = trans_s[tnl*3+1], tz = trans_s[tnl*3+2];
        const float mkn = mask_s[tnl];
        #pragma unroll
        for (int mi = 0; mi < 4; ++mi) {
            float dot = 0.f;
            #pragma unroll
            for (int c = 0; c < 16; ++c) dot = fmaf(skr[mi][c], q[c], dot);
            float dx = tx - spx[mi], dy = ty - spy[mi], dz = tz - spz[mi];
            float mterm = INFV * (mkn * smk[mi] - 1.0f) - 0.5f * sbw * (dx*dx + dy*dy + dz*dz);
            float lg = fmaf(0.25f, dot, mterm);
            logits[((size_t)(m0 + tmg * 4 + mi) * 12 + h) * 512 + nb + tnl] = lg;
            float newm = fmaxf(mxr[mi], lg);
            lr[mi] = lr[mi] * __expf(mxr[mi] - newm) + __expf(lg - newm);
            mxr[mi] = newm;
        }
    }
    #pragma unroll
    for (int off = 1; off < 32; off <<= 1) {
        #pragma unroll
        for (int mi = 0; mi < 4; ++mi) {
            float m2 = __shfl_xor(mxr[mi], off), l2 = __shfl_xor(lr[mi], off);
            float newm = fmaxf(mxr[mi], m2);
            lr[mi] = lr[mi] * __expf(mxr[mi] - newm) + l2 * __expf(m2 - newm);
            mxr[mi] = newm;
        }
    }
    if (tnl == 0) {
        #pragma unroll
        for (int mi = 0; mi < 4; ++mi) {
            int m = m0 + tmg * 4 + mi;
            stat_m[(size_t)m * 12 + h] = mxr[mi];
            stat_il[(size_t)m * 12 + h] = 1.0f / lr[mi];
        }
    }
}

// ---------------------------------------------------------------- tw
__global__ __launch_bounds__(256) void k_tw(
    const float* __restrict__ logits, const float* __restrict__ stat_m,
    const float* __restrict__ stat_il, float* __restrict__ w)
{
    __shared__ float mxs[12], ils[12];
    const int m = blockIdx.x, t = threadIdx.x;
    if (t < 12) { mxs[t] = stat_m[(size_t)m * 12 + t]; ils[t] = stat_il[(size_t)m * 12 + t]; }
    __syncthreads();
    const float* lp = logits + (size_t)m * 12 * 512;
    float a0 = 0.f, a1 = 0.f;
    #pragma unroll
    for (int h = 0; h < 12; ++h) {
        a0 += __expf(lp[h * 512 + t] - mxs[h]) * ils[h];
        a1 += __expf(lp[h * 512 + 256 + t] - mxs[h]) * ils[h];
    }
    w[(size_t)m * 512 + t] = a0 * (1.0f / 12.0f);
    w[(size_t)m * 512 + 256 + t] = a1 * (1.0f / 12.0f);
}

// ---------------------------------------------------------------- surf out
__global__ __launch_bounds__(256) void k_surf_out(
    const float* __restrict__ sfeat, const float* __restrict__ saggw,
    const float* __restrict__ Wso, const float* __restrict__ bso,
    float* __restrict__ out)
{
    __shared__ float wl[12304];
    const int t = threadIdx.x;
    for (int idx = t; idx < 12288; idx += 256) {
        int k = idx >> 4, c = idx & 15;
        wl[(k / 192) * 3076 + (k % 192) * 16 + c] = Wso[idx];
    }
    const int m = blockIdx.x * 64 + (t >> 2);
    const int kq = t & 3;
    const float* src = (kq < 2) ? &sfeat[(size_t)m * 384 + kq * 192]
                                : &saggw[(size_t)m * 384 + (kq - 2) * 192];
    __syncthreads();
    float acc[16];
    #pragma unroll
    for (int c = 0; c < 16; ++c) acc[c] = 0.f;
    const float* wb = &wl[kq * 3076];
    for (int k = 0; k < 192; k += 4) {
        float4 v = *(const float4*)&src[k];
        #pragma unroll
        for (int e = 0; e < 4; ++e) {
            float sv = (&v.x)[e];
            #pragma unroll
            for (int c = 0; c < 16; ++c)
                acc[c] = fmaf(sv, wb[(k + e) * 16 + c], acc[c]);
        }
    }
    #pragma unroll
    for (int c = 0; c < 16; ++c) {
        acc[c] += __shfl_xor(acc[c], 1);
        acc[c] += __shfl_xor(acc[c], 2);
    }
    #pragma unroll
    for (int c = 0; c < 16; ++c) {
        if ((c >> 2) == kq) out[196608 + (size_t)m * 16 + c] = acc[c] + bso[c];
    }
}

// ----------------------------------------------------------------
extern "C" void kernel_launch(void* const* d_in, const int* in_sizes, int n_in,
                              void* d_out, int out_size, void* d_ws, size_t ws_size,
                              hipStream_t stream)
{
    (void)in_sizes; (void)n_in; (void)out_size; (void)ws_size;
    const float* s     = (const float*)d_in[0];
    const float* z     = (const float*)d_in[1];
    const float* rots  = (const float*)d_in[2];
    const float* trans = (const float*)d_in[3];
    const float* mask  = (const float*)d_in[4];
    const float* sp    = (const float*)d_in[5];
    const float* sf    = (const float*)d_in[6];
    const float* smask = (const float*)d_in[7];
    const float* Wq    = (const float*)d_in[8];  const float* bq   = (const float*)d_in[9];
    const float* Wkv   = (const float*)d_in[10]; const float* bkv  = (const float*)d_in[11];
    const float* Wqp   = (const float*)d_in[12]; const float* bqp  = (const float*)d_in[13];
    const float* Wkvp  = (const float*)d_in[14]; const float* bkvp = (const float*)d_in[15];
    const float* Wse   = (const float*)d_in[16]; const float* bse  = (const float*)d_in[17];
    const float* Wsq   = (const float*)d_in[18]; const float* bsq  = (const float*)d_in[19];
    const float* Wsk   = (const float*)d_in[20]; const float* bsk  = (const float*)d_in[21];
    const float* Wsv   = (const float*)d_in[22]; const float* bsv  = (const float*)d_in[23];
    const float* Wb    = (const float*)d_in[24]; const float* bb   = (const float*)d_in[25];
    const float* Wdz   = (const float*)d_in[26]; const float* bdz  = (const float*)d_in[27];
    const float* hw    = (const float*)d_in[28]; const float* sbw  = (const float*)d_in[29];
    const float* Wout  = (const float*)d_in[30]; const float* bout = (const float*)d_in[31];
    const float* Wso   = (const float*)d_in[32]; const float* bso  = (const float*)d_in[33];
    float* out = (float*)d_out;

    float* qw    = (float*)d_ws;
    float* kw    = qw    + (size_t)512 * 192;
    float* vw    = kw    + (size_t)512 * 192;
    float* sqw   = vw    + (size_t)512 * 192;
    float* qpw   = sqw   + (size_t)512 * 192;
    float* kpw   = qpw   + (size_t)512 * 144;
    float* vpw   = kpw   + (size_t)512 * 144;
    float* sfeat = vpw   + (size_t)512 * 288;
    float* skv   = sfeat + (size_t)2048 * 384;
    float* ocat  = skv   + (size_t)2048 * 384;
    float* sagg  = ocat  + (size_t)512 * 1152;
    // region: proj (688K fl) -> bpz (11.5M fl) -> logits (12.6M fl), stream-serialized
    float* region = sagg + (size_t)2048 * 384;
    float* proj   = region;
    float* bpz    = region;
    float* logits = region;
    float* wt1   = region + (size_t)2048 * 12 * 512;
    float* wt2   = wt1   + (size_t)1344 * 384;
    float* wt3   = wt2   + (size_t)384 * 384;
    float* b1    = wt3   + (size_t)384 * 1152;
    float* b2    = b1    + 1344;
    float* st    = b2    + 384;
    float* wbuf  = st    + (size_t)384 * 512;
    float* statm = wbuf  + (size_t)2048 * 512;
    float* stati = statm + (size_t)2048 * 12;
    float* abuf  = stati + (size_t)2048 * 12;     // a[12][512][512]
    float* cbuf  = abuf  + (size_t)12 * 512 * 512; // c[12][512][40]

    k_pack<<<dim3(1099), dim3(256), 0, stream>>>(Wq, Wsq, Wkv, Wqp, Wkvp, Wsk, Wsv, Wout,
        bq, bsq, bkv, bqp, bkvp, bsk, bsv, wt1, wt2, wt3, b1, b2);
    k_transp<<<dim3(12, 16), dim3(256), 0, stream>>>(s, st);
    k_gemm<384, true><<<dim3(21, 8), dim3(256), 0, stream>>>(s, wt1, b1, proj, 1344);
    k_scatter<<<dim3(128), dim3(256), 0, stream>>>(proj, rots, trans,
        qw, kw, vw, sqw, qpw, kpw, vpw);
    k_sfeat<<<dim3(256), dim3(256), 0, stream>>>(sf, Wse, bse, sfeat);
    k_gemm<384, true><<<dim3(6, 32), dim3(256), 0, stream>>>(sfeat, wt2, b2, skv, 384);
    k_zpass<<<dim3(512), dim3(256), 0, stream>>>(z, Wb, bb, Wdz, bdz, bpz);
    k_attn_a<<<dim3(512, 3), dim3(256), 0, stream>>>(qw, kw, qpw, kpw, bpz, mask, hw, abuf);
    k_attn_pair<<<dim3(512), dim3(256), 0, stream>>>(abuf, bpz, ocat);
    k_gemm_ov<<<dim3(8, 12), dim3(256), 0, stream>>>(abuf, vw, vpw, cbuf);
    k_optfin<<<dim3(128), dim3(256), 0, stream>>>(cbuf, rots, trans, ocat);
    k_surf<<<dim3(384), dim3(256), 0, stream>>>(sqw, skv, trans, mask, sp, smask,
        sbw, ocat);
    k_tlog<<<dim3(64, 12), dim3(256), 0, stream>>>(sqw, skv, trans, mask, sp, smask,
        sbw, logits, statm, stati);
    k_tw<<<dim3(2048), dim3(256), 0, stream>>>(logits, statm, stati, wbuf);
    k_gemm<512, false><<<dim3(6, 32), dim3(256), 0, stream>>>(wbuf, st, nullptr, sagg, 384);
    k_surf_out<<<dim3(32), dim3(256), 0, stream>>>(sfeat, sagg, Wso, bso, out);
    k_gemm<1152, true><<<dim3(6, 8), dim3(256), 0, stream>>>(ocat, wt3, bout, out, 384);
}

// Round 6
// 571.370 us; speedup vs baseline: 1.0013x; 1.0013x over previous
//
#include <hip/hip_runtime.h>
#include <cstddef>

// IPA + surface cross-attention, B=1, N=512, M=2048, H=12, C_H=16, C_S=384.
// Round 3: split monolithic k_attn (139us, latency-bound, serial phase4)
// into k_attn_a (logits+wave-softmax) / k_attn_pair / k_gemm_ov / k_optfin.

#define CS 384
#define INFV 100000.0f

__device__ __forceinline__ float softplusf(float x) { return log1pf(__expf(x)); }

// ---------------------------------------------------------------- pack
__global__ __launch_bounds__(256) void k_pack(
    const float* __restrict__ Wq, const float* __restrict__ Wsq,
    const float* __restrict__ Wkv, const float* __restrict__ Wqp,
    const float* __restrict__ Wkvp, const float* __restrict__ Wsk,
    const float* __restrict__ Wsv, const float* __restrict__ Wout,
    const float* __restrict__ bq, const float* __restrict__ bsq,
    const float* __restrict__ bkv, const float* __restrict__ bqp,
    const float* __restrict__ bkvp, const float* __restrict__ bsk,
    const float* __restrict__ bsv,
    float* __restrict__ wt1, float* __restrict__ wt2, float* __restrict__ wt3,
    float* __restrict__ b1, float* __restrict__ b2)
{
    const int b = blockIdx.x, t = threadIdx.x;
    if (b >= 1092) {
        int idx = (b - 1092) * 256 + t;
        if (idx < 1344) {
            float v;
            if (idx < 192) v = bq[idx];
            else if (idx < 384) v = bsq[idx - 192];
            else if (idx < 768) v = bkv[idx - 384];
            else if (idx < 912) v = bqp[idx - 768];
            else v = bkvp[idx - 912];
            b1[idx] = v;
        } else if (idx < 1728) {
            int i2 = idx - 1344;
            b2[i2] = (i2 < 192) ? bsk[i2] : bsv[i2 - 192];
        }
        return;
    }
    const float* src; float* dst; int C, coff, tile, ldd;
    if (b < 72)       { src = Wq;   C = 192; dst = wt1; coff = 0;   ldd = 384;  tile = b; }
    else if (b < 144) { src = Wsq;  C = 192; dst = wt1; coff = 192; ldd = 384;  tile = b - 72; }
    else if (b < 288) { src = Wkv;  C = 384; dst = wt1; coff = 384; ldd = 384;  tile = b - 144; }
    else if (b < 348) { src = Wqp;  C = 144; dst = wt1; coff = 768; ldd = 384;  tile = b - 288; }
    else if (b < 516) { src = Wkvp; C = 432; dst = wt1; coff = 912; ldd = 384;  tile = b - 348; }
    else if (b < 588) { src = Wsk;  C = 192; dst = wt2; coff = 0;   ldd = 384;  tile = b - 516; }
    else if (b < 660) { src = Wsv;  C = 192; dst = wt2; coff = 192; ldd = 384;  tile = b - 588; }
    else              { src = Wout; C = 384; dst = wt3; coff = 0;   ldd = 1152; tile = b - 660; }
    const int cT = (C + 31) >> 5;
    const int tk = tile / cT, tc = tile % cT;
    __shared__ float l[32][33];
    const int tr = t >> 5, tcc = t & 31;
    #pragma unroll
    for (int rr = 0; rr < 4; ++rr) {
        int kloc = tr * 4 + rr;
        int cg = tc * 32 + tcc;
        l[kloc][tcc] = (cg < C) ? src[(size_t)(tk * 32 + kloc) * C + cg] : 0.f;
    }
    __syncthreads();
    #pragma unroll
    for (int rr = 0; rr < 4; ++rr) {
        int cloc = tr * 4 + rr;
        int cg = tc * 32 + cloc;
        if (cg < C) dst[(size_t)(coff + cg) * ldd + tk * 32 + tcc] = l[tcc][cloc];
    }
}

// ---------------------------------------------------------------- transpose
__global__ __launch_bounds__(256) void k_transp(
    const float* __restrict__ A, float* __restrict__ At)
{
    __shared__ float tile[32][33];
    const int r0 = blockIdx.y * 32, c0 = blockIdx.x * 32;
    const int tr = threadIdx.x >> 5, tc = threadIdx.x & 31;
    #pragma unroll
    for (int rr = 0; rr < 4; ++rr)
        tile[tr + rr * 8][tc] = A[(size_t)(r0 + tr + rr * 8) * 384 + c0 + tc];
    __syncthreads();
    #pragma unroll
    for (int rr = 0; rr < 4; ++rr)
        At[(size_t)(c0 + tr + rr * 8) * 512 + r0 + tc] = tile[tc][tr + rr * 8];
}

// ---------------------------------------------------------------- gemm
template<int KTOT, bool HB>
__global__ __launch_bounds__(256) void k_gemm(
    const float* __restrict__ A, const float* __restrict__ Wt,
    const float* __restrict__ bias, float* __restrict__ C, int ldc)
{
    __shared__ float As[64][68];
    __shared__ float Ws[64][68];
    const int t = threadIdx.x;
    const int c0 = blockIdx.x * 64, m0 = blockIdx.y * 64;
    const int sr = t >> 4, sk4 = (t & 15) << 2;
    const int wid = t >> 6, lane = t & 63;
    const int wr = (wid >> 1) * 32, wc = (wid & 1) * 32;
    const int lr = lane >> 3, lc = lane & 7;
    float acc[4][4];
    #pragma unroll
    for (int j = 0; j < 4; ++j) {
        float bv = HB ? bias[c0 + wc + lc + 8 * j] : 0.f;
        #pragma unroll
        for (int i = 0; i < 4; ++i) acc[i][j] = bv;
    }
    for (int kc = 0; kc < KTOT; kc += 64) {
        __syncthreads();
        #pragma unroll
        for (int rep = 0; rep < 4; ++rep) {
            int row = sr + rep * 16;
            *(float4*)&As[row][sk4] = *(const float4*)&A[(size_t)(m0 + row) * KTOT + kc + sk4];
            *(float4*)&Ws[row][sk4] = *(const float4*)&Wt[(size_t)(c0 + row) * KTOT + kc + sk4];
        }
        __syncthreads();
        #pragma unroll 4
        for (int k4 = 0; k4 < 16; ++k4) {
            float4 a[4], w[4];
            #pragma unroll
            for (int i = 0; i < 4; ++i) a[i] = *(float4*)&As[wr + lr + 8 * i][k4 * 4];
            #pragma unroll
            for (int j = 0; j < 4; ++j) w[j] = *(float4*)&Ws[wc + lc + 8 * j][k4 * 4];
            #pragma unroll
            for (int i = 0; i < 4; ++i) {
                #pragma unroll
                for (int j = 0; j < 4; ++j) {
                    acc[i][j] = fmaf(a[i].x, w[j].x, acc[i][j]);
                    acc[i][j] = fmaf(a[i].y, w[j].y, acc[i][j]);
                    acc[i][j] = fmaf(a[i].z, w[j].z, acc[i][j]);
                    acc[i][j] = fmaf(a[i].w, w[j].w, acc[i][j]);
                }
            }
        }
    }
    #pragma unroll
    for (int i = 0; i < 4; ++i) {
        #pragma unroll
        for (int j = 0; j < 4; ++j)
            C[(size_t)(m0 + wr + lr + 8 * i) * ldc + c0 + wc + lc + 8 * j] = acc[i][j];
    }
}

// ---------------------------------------------------------------- scatter
__global__ __launch_bounds__(256) void k_scatter(
    const float* __restrict__ proj, const float* __restrict__ rots,
    const float* __restrict__ trans,
    float* __restrict__ qw, float* __restrict__ kw, float* __restrict__ vw,
    float* __restrict__ sqw, float* __restrict__ qpw, float* __restrict__ kpw,
    float* __restrict__ vpw)
{
    __shared__ float p[4][1344];
    const int n0 = blockIdx.x * 4, t = threadIdx.x;
    for (int idx = t; idx < 1344; idx += 256) {
        #pragma unroll
        for (int r = 0; r < 4; ++r) p[r][idx] = proj[(size_t)(n0 + r) * 1344 + idx];
    }
    __syncthreads();
    for (int idx = t; idx < 3072; idx += 256) {
        int r = idx / 768, c = idx % 768;
        int n = n0 + r;
        float v = p[r][c];
        if (c < 192) qw[(size_t)n * 192 + c] = v;
        else if (c < 384) sqw[(size_t)n * 192 + (c - 192)] = v;
        else {
            int cc = c - 384, h = cc >> 5, sub = cc & 31;
            if (sub < 16) kw[(size_t)n * 192 + h * 16 + sub] = v;
            else          vw[(size_t)n * 192 + h * 16 + (sub - 16)] = v;
        }
    }
    for (int idx = t; idx < 2304; idx += 256) {
        int r = idx / 576, rem = idx % 576;
        int n = n0 + r;
        const float* R = &rots[(size_t)n * 9];
        const float* tr = &trans[(size_t)n * 3];
        if (rem < 144) {
            int pp = rem / 3, d = rem % 3;
            float v = fmaf(R[d*3+0], p[r][768 + pp],
                      fmaf(R[d*3+1], p[r][768 + 48 + pp],
                      fmaf(R[d*3+2], p[r][768 + 96 + pp], tr[d])));
            qpw[(size_t)n * 144 + pp * 3 + d] = v;
        } else {
            int rem2 = rem - 144; int pp = rem2 / 3, d = rem2 % 3;
            float v = fmaf(R[d*3+0], p[r][912 + pp],
                      fmaf(R[d*3+1], p[r][912 + 144 + pp],
                      fmaf(R[d*3+2], p[r][912 + 288 + pp], tr[d])));
            int h = pp / 12, ii = pp % 12;
            if (ii < 4) kpw[(size_t)n * 144 + h * 12 + ii * 3 + d] = v;
            else        vpw[(size_t)n * 288 + h * 24 + (ii - 4) * 3 + d] = v;
        }
    }
}

// ---------------------------------------------------------------- sfeat
__global__ __launch_bounds__(256) void k_sfeat(
    const float* __restrict__ sf, const float* __restrict__ Wse,
    const float* __restrict__ bse, float* __restrict__ sfeat)
{
    __shared__ float wl[16 * 384];
    __shared__ float sfl[8][16];
    const int m0 = blockIdx.x * 8, t = threadIdx.x;
    for (int idx = t; idx < 6144; idx += 256) wl[idx] = Wse[idx];
    if (t < 128) sfl[t >> 4][t & 15] = sf[(size_t)(m0 + (t >> 4)) * 16 + (t & 15)];
    __syncthreads();
    #pragma unroll
    for (int u = 0; u < 12; ++u) {
        int idx = t + u * 256;
        int r = idx / 384, c = idx % 384;
        float a = bse[c];
        #pragma unroll
        for (int kk = 0; kk < 16; ++kk) a = fmaf(sfl[r][kk], wl[kk * 384 + c], a);
        sfeat[(size_t)(m0 + r) * 384 + c] = a;
    }
}

// ---------------------------------------------------------------- zpass
__global__ __launch_bounds__(256) void k_zpass(
    const float* __restrict__ z, const float* __restrict__ Wb, const float* __restrict__ bb,
    const float* __restrict__ Wdz, const float* __restrict__ bdz, float* __restrict__ bpz)
{
    __shared__ float Wt[44][128];
    __shared__ float bias_s[44];
    __shared__ float zt[64][132];
    const int i = blockIdx.x, t = threadIdx.x;
    const float s3 = 0.5773502691896258f;
    for (int idx = t; idx < 44 * 128; idx += 256) {
        int c = idx >> 7, kk = idx & 127;
        Wt[c][kk] = (c < 12) ? s3 * Wb[kk * 12 + c] : Wdz[kk * 32 + (c - 12)];
    }
    if (t < 44) bias_s[t] = (t < 12) ? s3 * bb[t] : bdz[t - 12];
    const int jl = t & 63, cg = t >> 6;
    for (int j0 = 0; j0 < 512; j0 += 64) {
        __syncthreads();
        for (int idx = t; idx < 2048; idx += 256) {
            int r = idx >> 5, c4 = (idx & 31) << 2;
            *(float4*)&zt[r][c4] = *(const float4*)&z[((size_t)i * 512 + j0 + r) * 128 + c4];
        }
        __syncthreads();
        float acc[11];
        #pragma unroll
        for (int u = 0; u < 11; ++u) acc[u] = bias_s[cg * 11 + u];
        #pragma unroll 2
        for (int k4 = 0; k4 < 128; k4 += 4) {
            float4 zv = *(float4*)&zt[jl][k4];
            #pragma unroll
            for (int u = 0; u < 11; ++u) {
                float4 wv = *(float4*)&Wt[cg * 11 + u][k4];
                acc[u] = fmaf(zv.x, wv.x, acc[u]);
                acc[u] = fmaf(zv.y, wv.y, acc[u]);
                acc[u] = fmaf(zv.z, wv.z, acc[u]);
                acc[u] = fmaf(zv.w, wv.w, acc[u]);
            }
        }
        #pragma unroll
        for (int u = 0; u < 11; ++u)
            bpz[((size_t)i * 44 + cg * 11 + u) * 512 + j0 + jl] = acc[u];
    }
}

// ---------------------------------------------------------------- attn_a
// logits + per-wave softmax for 4 heads; writes a[h][i][j] (post-softmax).
__global__ __launch_bounds__(256) void k_attn_a(
    const float* __restrict__ qw, const float* __restrict__ kw,
    const float* __restrict__ qpw, const float* __restrict__ kpw,
    const float* __restrict__ bpz, const float* __restrict__ mask,
    const float* __restrict__ hwp, float* __restrict__ abuf)
{
    __shared__ float pls[4][520];
    __shared__ float qs[64], qps[48], cpt4[4];
    const int i = blockIdx.x, hg = blockIdx.y;
    const int t = threadIdx.x;
    if (t < 64) qs[t] = qw[(size_t)i * 192 + hg * 64 + t];
    if (t < 48) qps[t] = qpw[(size_t)i * 144 + hg * 48 + t];
    if (t < 4) cpt4[t] = -0.5f * 0.13608276348795434f * softplusf(hwp[hg * 4 + t]);
    const float mask_i = mask[i];
    __syncthreads();
    #pragma unroll 2
    for (int it = 0; it < 8; ++it) {
        int idx = t + it * 256;
        int hh = idx >> 9, j = idx & 511;
        int h = hg * 4 + hh;
        float kj[16], kpj[12];
        { const float4* kr = (const float4*)&kw[(size_t)j * 192 + h * 16];
          *(float4*)&kj[0] = kr[0]; *(float4*)&kj[4] = kr[1];
          *(float4*)&kj[8] = kr[2]; *(float4*)&kj[12] = kr[3]; }
        { const float4* kr = (const float4*)&kpw[(size_t)j * 144 + h * 12];
          *(float4*)&kpj[0] = kr[0]; *(float4*)&kpj[4] = kr[1]; *(float4*)&kpj[8] = kr[2]; }
        float qk = 0.f;
        #pragma unroll
        for (int c = 0; c < 16; ++c) qk = fmaf(qs[hh * 16 + c], kj[c], qk);
        float pts = 0.f;
        #pragma unroll
        for (int p = 0; p < 4; ++p) {
            float dx = qps[hh*12+p*3+0] - kpj[p*3+0];
            float dy = qps[hh*12+p*3+1] - kpj[p*3+1];
            float dz = qps[hh*12+p*3+2] - kpj[p*3+2];
            pts += dx*dx + dy*dy + dz*dz;
        }
        float lg = fmaf(0.14433756729740643f, qk, bpz[((size_t)i * 44 + h) * 512 + j]);
        lg = fmaf(cpt4[hh], pts, lg);
        lg += INFV * (mask_i * mask[j] - 1.0f);
        pls[hh][j] = lg;
    }
    __syncthreads();
    // per-wave softmax: wave w handles head hg*4+w, no further barriers
    const int w = t >> 6, lane = t & 63;
    float v[8];
    #pragma unroll
    for (int k = 0; k < 8; ++k) v[k] = pls[w][lane + k * 64];
    float mx = v[0];
    #pragma unroll
    for (int k = 1; k < 8; ++k) mx = fmaxf(mx, v[k]);
    #pragma unroll
    for (int off = 32; off; off >>= 1) mx = fmaxf(mx, __shfl_xor(mx, off));
    float sm = 0.f;
    #pragma unroll
    for (int k = 0; k < 8; ++k) { v[k] = __expf(v[k] - mx); sm += v[k]; }
    #pragma unroll
    for (int off = 32; off; off >>= 1) sm += __shfl_xor(sm, off);
    const float inv = 1.0f / sm;
    float* dst = abuf + ((size_t)(hg * 4 + w) * 512 + i) * 512;
    #pragma unroll
    for (int k = 0; k < 8; ++k) dst[lane + k * 64] = v[k] * inv;
}

// ---------------------------------------------------------------- attn_pair
// o_pair[h][c] = sum_j a[h][j] * pz[c][j]; a staged in LDS (broadcast reads).
__global__ __launch_bounds__(256) void k_attn_pair(
    const float* __restrict__ abuf, const float* __restrict__ bpz,
    float* __restrict__ ocat)
{
    __shared__ float al[12][512];
    const int i = blockIdx.x, t = threadIdx.x;
    #pragma unroll
    for (int u = 0; u < 12; ++u) {
        al[u][t] = abuf[(size_t)u * 262144 + (size_t)i * 512 + t];
        al[u][t + 256] = abuf[(size_t)u * 262144 + (size_t)i * 512 + t + 256];
    }
    __syncthreads();
    const int c = t & 31;
    const int h1 = t >> 5;             // 0..7
    const bool dual = (t < 128);       // also handles h1+8 (8..11)
    const float* pz = bpz + ((size_t)i * 44 + 12 + c) * 512;
    const float* a1 = al[h1];
    const float* a2 = al[dual ? h1 + 8 : 0];
    float acc1 = 0.f, acc2 = 0.f;
    for (int j = 0; j < 512; j += 4) {
        float4 p = *(const float4*)&pz[j];
        acc1 = fmaf(a1[j+0], p.x, acc1);
        acc1 = fmaf(a1[j+1], p.y, acc1);
        acc1 = fmaf(a1[j+2], p.z, acc1);
        acc1 = fmaf(a1[j+3], p.w, acc1);
        if (dual) {
            acc2 = fmaf(a2[j+0], p.x, acc2);
            acc2 = fmaf(a2[j+1], p.y, acc2);
            acc2 = fmaf(a2[j+2], p.z, acc2);
            acc2 = fmaf(a2[j+3], p.w, acc2);
        }
    }
    ocat[(size_t)i * 1152 + 576 + h1 * 32 + c] = acc1;
    if (dual) ocat[(size_t)i * 1152 + 576 + (h1 + 8) * 32 + c] = acc2;
}

// ---------------------------------------------------------------- gemm_ov
// per-head: C_h[512 i][40] = A_h[512 i][512 j] @ [v_h(16) | vp_h(24)]
__global__ __launch_bounds__(256) void k_gemm_ov(
    const float* __restrict__ abuf, const float* __restrict__ vw,
    const float* __restrict__ vpw, float* __restrict__ cbuf)
{
    __shared__ float As[64][68];
    __shared__ float Bs[64][44];
    const int i0 = blockIdx.x * 64, h = blockIdx.y;
    const int t = threadIdx.x;
    const int sr = t >> 4, sk4 = (t & 15) << 2;
    const int r1 = t >> 3;        // 0..31 (also r1+32)
    const int cb = t & 7;
    float acc[2][5];
    #pragma unroll
    for (int u = 0; u < 5; ++u) { acc[0][u] = 0.f; acc[1][u] = 0.f; }
    for (int kc = 0; kc < 512; kc += 64) {
        __syncthreads();
        #pragma unroll
        for (int rep = 0; rep < 4; ++rep) {
            int row = sr + rep * 16;
            *(float4*)&As[row][sk4] =
                *(const float4*)&abuf[(size_t)h * 262144 + (size_t)(i0 + row) * 512 + kc + sk4];
        }
        #pragma unroll
        for (int u = 0; u < 10; ++u) {
            int idx = t + u * 256;
            int r = idx / 40, cc = idx % 40;
            Bs[r][cc] = (cc < 16) ? vw[(size_t)(kc + r) * 192 + h * 16 + cc]
                                  : vpw[(size_t)(kc + r) * 288 + h * 24 + (cc - 16)];
        }
        __syncthreads();
        #pragma unroll 4
        for (int kk = 0; kk < 64; ++kk) {
            float av1 = As[r1][kk], av2 = As[r1 + 32][kk];
            #pragma unroll
            for (int u = 0; u < 5; ++u) {
                float b = Bs[kk][cb + 8 * u];
                acc[0][u] = fmaf(av1, b, acc[0][u]);
                acc[1][u] = fmaf(av2, b, acc[1][u]);
            }
        }
    }
    #pragma unroll
    for (int u = 0; u < 5; ++u) {
        cbuf[((size_t)h * 512 + i0 + r1) * 40 + cb + 8 * u] = acc[0][u];
        cbuf[((size_t)h * 512 + i0 + r1 + 32) * 40 + cb + 8 * u] = acc[1][u];
    }
}

// ---------------------------------------------------------------- optfin
__global__ __launch_bounds__(256) void k_optfin(
    const float* __restrict__ cbuf, const float* __restrict__ rots,
    const float* __restrict__ trans, float* __restrict__ ocat)
{
    __shared__ float cl[4][12][40];
    const int i0 = blockIdx.x * 4, t = threadIdx.x;
    for (int idx = t; idx < 1920; idx += 256) {
        int ii = idx / 480, rem = idx % 480;
        int h = rem / 40, c = rem % 40;
        cl[ii][h][c] = cbuf[((size_t)h * 512 + i0 + ii) * 40 + c];
    }
    __syncthreads();
    for (int idx = t; idx < 768; idx += 256) {
        int ii = idx / 192, o = idx % 192;
        ocat[(size_t)(i0 + ii) * 1152 + o] = cl[ii][o >> 4][o & 15];
    }
    for (int idx = t; idx < 384; idx += 256) {
        int ii = idx / 96, hp = idx % 96;
        int h = hp >> 3, p = hp & 7;
        int i = i0 + ii;
        const float* R = &rots[(size_t)i * 9];
        float gx = cl[ii][h][16 + p*3 + 0] - trans[(size_t)i*3 + 0];
        float gy = cl[ii][h][16 + p*3 + 1] - trans[(size_t)i*3 + 1];
        float gz = cl[ii][h][16 + p*3 + 2] - trans[(size_t)i*3 + 2];
        float lx = R[0]*gx + R[3]*gy + R[6]*gz;
        float ly = R[1]*gx + R[4]*gy + R[7]*gz;
        float lz = R[2]*gx + R[5]*gy + R[8]*gz;
        float nm = sqrtf(lx*lx + ly*ly + lz*lz + 1e-8f);
        int col = h * 8 + p;
        size_t base = (size_t)i * 1152;
        ocat[base + 192 + col] = lx;
        ocat[base + 288 + col] = ly;
        ocat[base + 384 + col] = lz;
        ocat[base + 480 + col] = nm;
    }
}

// ---------------------------------------------------------------- surf attn (single-pass flash)
__global__ __launch_bounds__(256) void k_surf(
    const float* __restrict__ sqw, const float* __restrict__ skv,
    const float* __restrict__ trans, const float* __restrict__ mask,
    const float* __restrict__ sp, const float* __restrict__ smask,
    const float* __restrict__ sbwp, float* __restrict__ ocat)
{
    __shared__ float sk_t[256][17];
    __shared__ float sv_t[256][17];
    __shared__ float sp_t[768];
    __shared__ float smask_t[256];
    const int h = blockIdx.x >> 5;
    const int n0 = (blockIdx.x & 31) * 16;
    const int t = threadIdx.x;
    const int tn = t >> 4, tm = t & 15;
    const int n = n0 + tn;
    const float sbw = softplusf(sbwp[0]);
    float qreg[16];
    #pragma unroll
    for (int c = 0; c < 16; ++c) qreg[c] = sqw[(size_t)n * 192 + h * 16 + c];
    const float trx = trans[(size_t)n*3+0], tryy = trans[(size_t)n*3+1], trz = trans[(size_t)n*3+2];
    const float mask_n = mask[n];
    float mx = -1e30f, l = 0.f;
    float acc[16];
    #pragma unroll
    for (int c = 0; c < 16; ++c) acc[c] = 0.f;
    for (int tile = 0; tile < 8; ++tile) {
        __syncthreads();
        const int mb = tile * 256;
        for (int idx = t; idx < 1024; idx += 256) {
            int ml = idx >> 2, c4 = (idx & 3) << 2;
            float4 v4 = *(const float4*)&skv[(size_t)(mb + ml) * 384 + h * 16 + c4];
            sk_t[ml][c4+0]=v4.x; sk_t[ml][c4+1]=v4.y; sk_t[ml][c4+2]=v4.z; sk_t[ml][c4+3]=v4.w;
            float4 w4 = *(const float4*)&skv[(size_t)(mb + ml) * 384 + 192 + h * 16 + c4];
            sv_t[ml][c4+0]=w4.x; sv_t[ml][c4+1]=w4.y; sv_t[ml][c4+2]=w4.z; sv_t[ml][c4+3]=w4.w;
        }
        for (int idx = t; idx < 768; idx += 256) sp_t[idx] = sp[(size_t)mb * 3 + idx];
        smask_t[t] = smask[mb + t];
        __syncthreads();
        float lgr[16];
        float tmax = -1e30f;
        #pragma unroll
        for (int kk = 0; kk < 16; ++kk) {
            int ml = tm + (kk << 4);
            float dot = 0.f;
            #pragma unroll
            for (int c = 0; c < 16; ++c) dot = fmaf(qreg[c], sk_t[ml][c], dot);
            float dx = trx - sp_t[ml*3+0], dy = tryy - sp_t[ml*3+1], dz = trz - sp_t[ml*3+2];
            float lg = fmaf(0.25f, dot, -0.5f * sbw * (dx*dx + dy*dy + dz*dz));
            lg += INFV * (mask_n * smask_t[ml] - 1.0f);
            lgr[kk] = lg;
            tmax = fmaxf(tmax, lg);
        }
        float mn = fmaxf(mx, tmax);
        float scale = __expf(mx - mn);
        l *= scale;
        #pragma unroll
        for (int c = 0; c < 16; ++c) acc[c] *= scale;
        #pragma unroll
        for (int kk = 0; kk < 16; ++kk) {
            int ml = tm + (kk << 4);
            float w = __expf(lgr[kk] - mn);
            l += w;
            #pragma unroll
            for (int c = 0; c < 16; ++c) acc[c] = fmaf(w, sv_t[ml][c], acc[c]);
        }
        mx = mn;
    }
    #pragma unroll
    for (int off = 1; off < 16; off <<= 1) {
        float m2 = __shfl_xor(mx, off), l2 = __shfl_xor(l, off);
        float mn = fmaxf(mx, m2);
        float e1 = __expf(mx - mn), e2 = __expf(m2 - mn);
        l = l * e1 + l2 * e2;
        #pragma unroll
        for (int c = 0; c < 16; ++c) {
            float a2 = __shfl_xor(acc[c], off);
            acc[c] = acc[c] * e1 + a2 * e2;
        }
        mx = mn;
    }
    const float invl = 1.0f / l;
    float outv = 0.f;
    #pragma unroll
    for (int c = 0; c < 16; ++c) if (tm == c) outv = acc[c];
    ocat[(size_t)n * 1152 + 960 + h * 16 + tm] = outv * invl;
}

// ---------------------------------------------------------------- tlog
__global__ __launch_bounds__(256) void k_tlog(
    const float* __restrict__ sqw, const float* __restrict__ skv,
    const float* __restrict__ trans, const float* __restrict__ mask,
    const float* __restrict__ sp, const float* __restrict__ smask,
    const float* __restrict__ sbwp, float* __restrict__ logits,
    float* __restrict__ stat_m, float* __restrict__ stat_il)
{
    __shared__ float sk_s[32][16];
    __shared__ float sq_s[32][16];
    __shared__ float trans_s[96];
    __shared__ float mask_s[32];
    __shared__ float spm_s[96];
    __shared__ float smask_s[32];
    const int h = blockIdx.y;
    const int m0 = blockIdx.x * 32;
    const int t = threadIdx.x;
    const int tmg = t >> 5, tnl = t & 31;
    const float sbw = softplusf(sbwp[0]);
    for (int idx = t; idx < 512; idx += 256) {
        int row = idx >> 4, c = idx & 15;
        sk_s[row][c] = skv[(size_t)(m0 + row) * 384 + h * 16 + c];
    }
    if (t < 96) spm_s[t] = sp[(size_t)m0 * 3 + t];
    if (t < 32) smask_s[t] = smask[m0 + t];
    __syncthreads();
    float skr[4][16];
    float spx[4], spy[4], spz[4], smk[4];
    #pragma unroll
    for (int mi = 0; mi < 4; ++mi) {
        int row = tmg * 4 + mi;
        #pragma unroll
        for (int c4 = 0; c4 < 16; c4 += 4)
            *(float4*)&skr[mi][c4] = *(float4*)&sk_s[row][c4];
        spx[mi] = spm_s[row*3+0]; spy[mi] = spm_s[row*3+1]; spz[mi] = spm_s[row*3+2];
        smk[mi] = smask_s[row];
    }
    float mxr[4], lr[4];
    #pragma unroll
    for (int mi = 0; mi < 4; ++mi) { mxr[mi] = -1e30f; lr[mi] = 0.f; }
    for (int nt = 0; nt < 16; ++nt) {
        __syncthreads();
        const int nb = nt * 32;
        if (t < 128) {
            int nn = t >> 2, c4 = (t & 3) << 2;
            *(float4*)&sq_s[nn][c4] = *(const float4*)&sqw[(size_t)(nb + nn) * 192 + h * 16 + c4];
        }
        if (t < 96) trans_s[t] = trans[(size_t)nb * 3 + t];
        if (t < 32) mask_s[t] = mask[nb + t];
        __syncthreads();
        float q[16];
        #pragma unroll
        for (int c4 = 0; c4 < 16; c4 += 4)
            *(float4*)&q[c4] = *(float4*)&sq_s[tnl][c4];
        const float tx = trans_s[tnl*3+0], ty = trans_s[tnl*3+1], tz = trans_s[tnl*3+2];
        const float mkn = mask_s[tnl];
        #pragma unroll
        for (int mi = 0; mi < 4; ++mi) {
            float dot = 0.f;
            #pragma unroll
            for (int c = 0; c < 16; ++c) dot = fmaf(skr[mi][c], q[c], dot);
            float dx = tx - spx[mi], dy = ty - spy[mi], dz = tz - spz[mi];
            float mterm = INFV * (mkn * smk[mi] - 1.0f) - 0.5f * sbw * (dx*dx + dy*dy + dz*dz);
            float lg = fmaf(0.25f, dot, mterm);
            logits[((size_t)(m0 + tmg * 4 + mi) * 12 + h) * 512 + nb + tnl] = lg;
            float newm = fmaxf(mxr[mi], lg);
            lr[mi] = lr[mi] * __expf(mxr[mi] - newm) + __expf(lg - newm);
            mxr[mi] = newm;
        }
    }
    #pragma unroll
    for (int off = 1; off < 32; off <<= 1) {
        #pragma unroll
        for (int mi = 0; mi < 4; ++mi) {
            float m2 = __shfl_xor(mxr[mi], off), l2 = __shfl_xor(lr[mi], off);
            float newm = fmaxf(mxr[mi], m2);
            lr[mi] = lr[mi] * __expf(mxr[mi] - newm) + l2 * __expf(m2 - newm);
            mxr[mi] = newm;
        }
    }
    if (tnl == 0) {
        #pragma unroll
        for (int mi = 0; mi < 4; ++mi) {
            int m = m0 + tmg * 4 + mi;
            stat_m[(size_t)m * 12 + h] = mxr[mi];
            stat_il[(size_t)m * 12 + h] = 1.0f / lr[mi];
        }
    }
}

// ---------------------------------------------------------------- tw
__global__ __launch_bounds__(256) void k_tw(
    const float* __restrict__ logits, const float* __restrict__ stat_m,
    const float* __restrict__ stat_il, float* __restrict__ w)
{
    __shared__ float mxs[12], ils[12];
    const int m = blockIdx.x, t = threadIdx.x;
    if (t < 12) { mxs[t] = stat_m[(size_t)m * 12 + t]; ils[t] = stat_il[(size_t)m * 12 + t]; }
    __syncthreads();
    const float* lp = logits + (size_t)m * 12 * 512;
    float a0 = 0.f, a1 = 0.f;
    #pragma unroll
    for (int h = 0; h < 12; ++h) {
        a0 += __expf(lp[h * 512 + t] - mxs[h]) * ils[h];
        a1 += __expf(lp[h * 512 + 256 + t] - mxs[h]) * ils[h];
    }
    w[(size_t)m * 512 + t] = a0 * (1.0f / 12.0f);
    w[(size_t)m * 512 + 256 + t] = a1 * (1.0f / 12.0f);
}

// ---------------------------------------------------------------- surf out
__global__ __launch_bounds__(256) void k_surf_out(
    const float* __restrict__ sfeat, const float* __restrict__ saggw,
    const float* __restrict__ Wso, const float* __restrict__ bso,
    float* __restrict__ out)
{
    __shared__ float wl[12304];
    const int t = threadIdx.x;
    for (int idx = t; idx < 12288; idx += 256) {
        int k = idx >> 4, c = idx & 15;
        wl[(k / 192) * 3076 + (k % 192) * 16 + c] = Wso[idx];
    }
    const int m = blockIdx.x * 64 + (t >> 2);
    const int kq = t & 3;
    const float* src = (kq < 2) ? &sfeat[(size_t)m * 384 + kq * 192]
                                : &saggw[(size_t)m * 384 + (kq - 2) * 192];
    __syncthreads();
    float acc[16];
    #pragma unroll
    for (int c = 0; c < 16; ++c) acc[c] = 0.f;
    const float* wb = &wl[kq * 3076];
    for (int k = 0; k < 192; k += 4) {
        float4 v = *(const float4*)&src[k];
        #pragma unroll
        for (int e = 0; e < 4; ++e) {
            float sv = (&v.x)[e];
            #pragma unroll
            for (int c = 0; c < 16; ++c)
                acc[c] = fmaf(sv, wb[(k + e) * 16 + c], acc[c]);
        }
    }
    #pragma unroll
    for (int c = 0; c < 16; ++c) {
        acc[c] += __shfl_xor(acc[c], 1);
        acc[c] += __shfl_xor(acc[c], 2);
    }
    #pragma unroll
    for (int c = 0; c < 16; ++c) {
        if ((c >> 2) == kq) out[196608 + (size_t)m * 16 + c] = acc[c] + bso[c];
    }
}

// ----------------------------------------------------------------
extern "C" void kernel_launch(void* const* d_in, const int* in_sizes, int n_in,
                              void* d_out, int out_size, void* d_ws, size_t ws_size,
                              hipStream_t stream)
{
    (void)in_sizes; (void)n_in; (void)out_size; (void)ws_size;
    const float* s     = (const float*)d_in[0];
    const float* z     = (const float*)d_in[1];
    const float* rots  = (const float*)d_in[2];
    const float* trans = (const float*)d_in[3];
    const float* mask  = (const float*)d_in[4];
    const float* sp    = (const float*)d_in[5];
    const float* sf    = (const float*)d_in[6];
    const float* smask = (const float*)d_in[7];
    const float* Wq    = (const float*)d_in[8];  const float* bq   = (const float*)d_in[9];
    const float* Wkv   = (const float*)d_in[10]; const float* bkv  = (const float*)d_in[11];
    const float* Wqp   = (const float*)d_in[12]; const float* bqp  = (const float*)d_in[13];
    const float* Wkvp  = (const float*)d_in[14]; const float* bkvp = (const float*)d_in[15];
    const float* Wse   = (const float*)d_in[16]; const float* bse  = (const float*)d_in[17];
    const float* Wsq   = (const float*)d_in[18]; const float* bsq  = (const float*)d_in[19];
    const float* Wsk   = (const float*)d_in[20]; const float* bsk  = (const float*)d_in[21];
    const float* Wsv   = (const float*)d_in[22]; const float* bsv  = (const float*)d_in[23];
    const float* Wb    = (const float*)d_in[24]; const float* bb   = (const float*)d_in[25];
    const float* Wdz   = (const float*)d_in[26]; const float* bdz  = (const float*)d_in[27];
    const float* hw    = (const float*)d_in[28]; const float* sbw  = (const float*)d_in[29];
    const float* Wout  = (const float*)d_in[30]; const float* bout = (const float*)d_in[31];
    const float* Wso   = (const float*)d_in[32]; const float* bso  = (const float*)d_in[33];
    float* out = (float*)d_out;

    float* qw    = (float*)d_ws;
    float* kw    = qw    + (size_t)512 * 192;
    float* vw    = kw    + (size_t)512 * 192;
    float* sqw   = vw    + (size_t)512 * 192;
    float* qpw   = sqw   + (size_t)512 * 192;
    float* kpw   = qpw   + (size_t)512 * 144;
    float* vpw   = kpw   + (size_t)512 * 144;
    float* sfeat = vpw   + (size_t)512 * 288;
    float* skv   = sfeat + (size_t)2048 * 384;
    float* ocat  = skv   + (size_t)2048 * 384;
    float* sagg  = ocat  + (size_t)512 * 1152;
    // region: proj (688K fl) -> bpz (11.5M fl) -> logits (12.6M fl), stream-serialized
    float* region = sagg + (size_t)2048 * 384;
    float* proj   = region;
    float* bpz    = region;
    float* logits = region;
    float* wt1   = region + (size_t)2048 * 12 * 512;
    float* wt2   = wt1   + (size_t)1344 * 384;
    float* wt3   = wt2   + (size_t)384 * 384;
    float* b1    = wt3   + (size_t)384 * 1152;
    float* b2    = b1    + 1344;
    float* st    = b2    + 384;
    float* wbuf  = st    + (size_t)384 * 512;
    float* statm = wbuf  + (size_t)2048 * 512;
    float* stati = statm + (size_t)2048 * 12;
    float* abuf  = stati + (size_t)2048 * 12;     // a[12][512][512]
    float* cbuf  = abuf  + (size_t)12 * 512 * 512; // c[12][512][40]

    k_pack<<<dim3(1099), dim3(256), 0, stream>>>(Wq, Wsq, Wkv, Wqp, Wkvp, Wsk, Wsv, Wout,
        bq, bsq, bkv, bqp, bkvp, bsk, bsv, wt1, wt2, wt3, b1, b2);
    k_transp<<<dim3(12, 16), dim3(256), 0, stream>>>(s, st);
    k_gemm<384, true><<<dim3(21, 8), dim3(256), 0, stream>>>(s, wt1, b1, proj, 1344);
    k_scatter<<<dim3(128), dim3(256), 0, stream>>>(proj, rots, trans,
        qw, kw, vw, sqw, qpw, kpw, vpw);
    k_sfeat<<<dim3(256), dim3(256), 0, stream>>>(sf, Wse, bse, sfeat);
    k_gemm<384, true><<<dim3(6, 32), dim3(256), 0, stream>>>(sfeat, wt2, b2, skv, 384);
    k_zpass<<<dim3(512), dim3(256), 0, stream>>>(z, Wb, bb, Wdz, bdz, bpz);
    k_attn_a<<<dim3(512, 3), dim3(256), 0, stream>>>(qw, kw, qpw, kpw, bpz, mask, hw, abuf);
    k_attn_pair<<<dim3(512), dim3(256), 0, stream>>>(abuf, bpz, ocat);
    k_gemm_ov<<<dim3(8, 12), dim3(256), 0, stream>>>(abuf, vw, vpw, cbuf);
    k_optfin<<<dim3(128), dim3(256), 0, stream>>>(cbuf, rots, trans, ocat);
    k_surf<<<dim3(384), dim3(256), 0, stream>>>(sqw, skv, trans, mask, sp, smask,
        sbw, ocat);
    k_tlog<<<dim3(64, 12), dim3(256), 0, stream>>>(sqw, skv, trans, mask, sp, smask,
        sbw, logits, statm, stati);
    k_tw<<<dim3(2048), dim3(256), 0, stream>>>(logits, statm, stati, wbuf);
    k_gemm<512, false><<<dim3(6, 32), dim3(256), 0, stream>>>(wbuf, st, nullptr, sagg, 384);
    k_surf_out<<<dim3(32), dim3(256), 0, stream>>>(sfeat, sagg, Wso, bso, out);
    k_gemm<1152, true><<<dim3(6, 8), dim3(256), 0, stream>>>(ocat, wt3, bout, out, 384);
}

// Round 7
// 570.151 us; speedup vs baseline: 1.0034x; 1.0021x over previous
//
#include <hip/hip_runtime.h>
#include <cstddef>

// IPA + surface cross-attention, B=1, N=512, M=2048, H=12, C_H=16, C_S=384.
// Round 3: split monolithic k_attn (139us, latency-bound, serial phase4)
// into k_attn_a (logits+wave-softmax) / k_attn_pair / k_gemm_ov / k_optfin.

#define CS 384
#define INFV 100000.0f

__device__ __forceinline__ float softplusf(float x) { return log1pf(__expf(x)); }

// ---------------------------------------------------------------- pack
__global__ __launch_bounds__(256) void k_pack(
    const float* __restrict__ Wq, const float* __restrict__ Wsq,
    const float* __restrict__ Wkv, const float* __restrict__ Wqp,
    const float* __restrict__ Wkvp, const float* __restrict__ Wsk,
    const float* __restrict__ Wsv, const float* __restrict__ Wout,
    const float* __restrict__ bq, const float* __restrict__ bsq,
    const float* __restrict__ bkv, const float* __restrict__ bqp,
    const float* __restrict__ bkvp, const float* __restrict__ bsk,
    const float* __restrict__ bsv,
    float* __restrict__ wt1, float* __restrict__ wt2, float* __restrict__ wt3,
    float* __restrict__ b1, float* __restrict__ b2)
{
    const int b = blockIdx.x, t = threadIdx.x;
    if (b >= 1092) {
        int idx = (b - 1092) * 256 + t;
        if (idx < 1344) {
            float v;
            if (idx < 192) v = bq[idx];
            else if (idx < 384) v = bsq[idx - 192];
            else if (idx < 768) v = bkv[idx - 384];
            else if (idx < 912) v = bqp[idx - 768];
            else v = bkvp[idx - 912];
            b1[idx] = v;
        } else if (idx < 1728) {
            int i2 = idx - 1344;
            b2[i2] = (i2 < 192) ? bsk[i2] : bsv[i2 - 192];
        }
        return;
    }
    const float* src; float* dst; int C, coff, tile, ldd;
    if (b < 72)       { src = Wq;   C = 192; dst = wt1; coff = 0;   ldd = 384;  tile = b; }
    else if (b < 144) { src = Wsq;  C = 192; dst = wt1; coff = 192; ldd = 384;  tile = b - 72; }
    else if (b < 288) { src = Wkv;  C = 384; dst = wt1; coff = 384; ldd = 384;  tile = b - 144; }
    else if (b < 348) { src = Wqp;  C = 144; dst = wt1; coff = 768; ldd = 384;  tile = b - 288; }
    else if (b < 516) { src = Wkvp; C = 432; dst = wt1; coff = 912; ldd = 384;  tile = b - 348; }
    else if (b < 588) { src = Wsk;  C = 192; dst = wt2; coff = 0;   ldd = 384;  tile = b - 516; }
    else if (b < 660) { src = Wsv;  C = 192; dst = wt2; coff = 192; ldd = 384;  tile = b - 588; }
    else              { src = Wout; C = 384; dst = wt3; coff = 0;   ldd = 1152; tile = b - 660; }
    const int cT = (C + 31) >> 5;
    const int tk = tile / cT, tc = tile % cT;
    __shared__ float l[32][33];
    const int tr = t >> 5, tcc = t & 31;
    #pragma unroll
    for (int rr = 0; rr < 4; ++rr) {
        int kloc = tr * 4 + rr;
        int cg = tc * 32 + tcc;
        l[kloc][tcc] = (cg < C) ? src[(size_t)(tk * 32 + kloc) * C + cg] : 0.f;
    }
    __syncthreads();
    #pragma unroll
    for (int rr = 0; rr < 4; ++rr) {
        int cloc = tr * 4 + rr;
        int cg = tc * 32 + cloc;
        if (cg < C) dst[(size_t)(coff + cg) * ldd + tk * 32 + tcc] = l[tcc][cloc];
    }
}

// ---------------------------------------------------------------- transpose
__global__ __launch_bounds__(256) void k_transp(
    const float* __restrict__ A, float* __restrict__ At)
{
    __shared__ float tile[32][33];
    const int r0 = blockIdx.y * 32, c0 = blockIdx.x * 32;
    const int tr = threadIdx.x >> 5, tc = threadIdx.x & 31;
    #pragma unroll
    for (int rr = 0; rr < 4; ++rr)
        tile[tr + rr * 8][tc] = A[(size_t)(r0 + tr + rr * 8) * 384 + c0 + tc];
    __syncthreads();
    #pragma unroll
    for (int rr = 0; rr < 4; ++rr)
        At[(size_t)(c0 + tr + rr * 8) * 512 + r0 + tc] = tile[tc][tr + rr * 8];
}

// ---------------------------------------------------------------- gemm
template<int KTOT, bool HB>
__global__ __launch_bounds__(256) void k_gemm(
    const float* __restrict__ A, const float* __restrict__ Wt,
    const float* __restrict__ bias, float* __restrict__ C, int ldc)
{
    __shared__ float As[64][68];
    __shared__ float Ws[64][68];
    const int t = threadIdx.x;
    const int c0 = blockIdx.x * 64, m0 = blockIdx.y * 64;
    const int sr = t >> 4, sk4 = (t & 15) << 2;
    const int wid = t >> 6, lane = t & 63;
    const int wr = (wid >> 1) * 32, wc = (wid & 1) * 32;
    const int lr = lane >> 3, lc = lane & 7;
    float acc[4][4];
    #pragma unroll
    for (int j = 0; j < 4; ++j) {
        float bv = HB ? bias[c0 + wc + lc + 8 * j] : 0.f;
        #pragma unroll
        for (int i = 0; i < 4; ++i) acc[i][j] = bv;
    }
    for (int kc = 0; kc < KTOT; kc += 64) {
        __syncthreads();
        #pragma unroll
        for (int rep = 0; rep < 4; ++rep) {
            int row = sr + rep * 16;
            *(float4*)&As[row][sk4] = *(const float4*)&A[(size_t)(m0 + row) * KTOT + kc + sk4];
            *(float4*)&Ws[row][sk4] = *(const float4*)&Wt[(size_t)(c0 + row) * KTOT + kc + sk4];
        }
        __syncthreads();
        #pragma unroll 4
        for (int k4 = 0; k4 < 16; ++k4) {
            float4 a[4], w[4];
            #pragma unroll
            for (int i = 0; i < 4; ++i) a[i] = *(float4*)&As[wr + lr + 8 * i][k4 * 4];
            #pragma unroll
            for (int j = 0; j < 4; ++j) w[j] = *(float4*)&Ws[wc + lc + 8 * j][k4 * 4];
            #pragma unroll
            for (int i = 0; i < 4; ++i) {
                #pragma unroll
                for (int j = 0; j < 4; ++j) {
                    acc[i][j] = fmaf(a[i].x, w[j].x, acc[i][j]);
                    acc[i][j] = fmaf(a[i].y, w[j].y, acc[i][j]);
                    acc[i][j] = fmaf(a[i].z, w[j].z, acc[i][j]);
                    acc[i][j] = fmaf(a[i].w, w[j].w, acc[i][j]);
                }
            }
        }
    }
    #pragma unroll
    for (int i = 0; i < 4; ++i) {
        #pragma unroll
        for (int j = 0; j < 4; ++j)
            C[(size_t)(m0 + wr + lr + 8 * i) * ldc + c0 + wc + lc + 8 * j] = acc[i][j];
    }
}

// ---------------------------------------------------------------- scatter
__global__ __launch_bounds__(256) void k_scatter(
    const float* __restrict__ proj, const float* __restrict__ rots,
    const float* __restrict__ trans,
    float* __restrict__ qw, float* __restrict__ kw, float* __restrict__ vw,
    float* __restrict__ sqw, float* __restrict__ qpw, float* __restrict__ kpw,
    float* __restrict__ vpw)
{
    __shared__ float p[4][1344];
    const int n0 = blockIdx.x * 4, t = threadIdx.x;
    for (int idx = t; idx < 1344; idx += 256) {
        #pragma unroll
        for (int r = 0; r < 4; ++r) p[r][idx] = proj[(size_t)(n0 + r) * 1344 + idx];
    }
    __syncthreads();
    for (int idx = t; idx < 3072; idx += 256) {
        int r = idx / 768, c = idx % 768;
        int n = n0 + r;
        float v = p[r][c];
        if (c < 192) qw[(size_t)n * 192 + c] = v;
        else if (c < 384) sqw[(size_t)n * 192 + (c - 192)] = v;
        else {
            int cc = c - 384, h = cc >> 5, sub = cc & 31;
            if (sub < 16) kw[(size_t)n * 192 + h * 16 + sub] = v;
            else          vw[(size_t)n * 192 + h * 16 + (sub - 16)] = v;
        }
    }
    for (int idx = t; idx < 2304; idx += 256) {
        int r = idx / 576, rem = idx % 576;
        int n = n0 + r;
        const float* R = &rots[(size_t)n * 9];
        const float* tr = &trans[(size_t)n * 3];
        if (rem < 144) {
            int pp = rem / 3, d = rem % 3;
            float v = fmaf(R[d*3+0], p[r][768 + pp],
                      fmaf(R[d*3+1], p[r][768 + 48 + pp],
                      fmaf(R[d*3+2], p[r][768 + 96 + pp], tr[d])));
            qpw[(size_t)n * 144 + pp * 3 + d] = v;
        } else {
            int rem2 = rem - 144; int pp = rem2 / 3, d = rem2 % 3;
            float v = fmaf(R[d*3+0], p[r][912 + pp],
                      fmaf(R[d*3+1], p[r][912 + 144 + pp],
                      fmaf(R[d*3+2], p[r][912 + 288 + pp], tr[d])));
            int h = pp / 12, ii = pp % 12;
            if (ii < 4) kpw[(size_t)n * 144 + h * 12 + ii * 3 + d] = v;
            else        vpw[(size_t)n * 288 + h * 24 + (ii - 4) * 3 + d] = v;
        }
    }
}

// ---------------------------------------------------------------- sfeat
__global__ __launch_bounds__(256) void k_sfeat(
    const float* __restrict__ sf, const float* __restrict__ Wse,
    const float* __restrict__ bse, float* __restrict__ sfeat)
{
    __shared__ float wl[16 * 384];
    __shared__ float sfl[8][16];
    const int m0 = blockIdx.x * 8, t = threadIdx.x;
    for (int idx = t; idx < 6144; idx += 256) wl[idx] = Wse[idx];
    if (t < 128) sfl[t >> 4][t & 15] = sf[(size_t)(m0 + (t >> 4)) * 16 + (t & 15)];
    __syncthreads();
    #pragma unroll
    for (int u = 0; u < 12; ++u) {
        int idx = t + u * 256;
        int r = idx / 384, c = idx % 384;
        float a = bse[c];
        #pragma unroll
        for (int kk = 0; kk < 16; ++kk) a = fmaf(sfl[r][kk], wl[kk * 384 + c], a);
        sfeat[(size_t)(m0 + r) * 384 + c] = a;
    }
}

// ---------------------------------------------------------------- zpass
__global__ __launch_bounds__(256) void k_zpass(
    const float* __restrict__ z, const float* __restrict__ Wb, const float* __restrict__ bb,
    const float* __restrict__ Wdz, const float* __restrict__ bdz, float* __restrict__ bpz)
{
    __shared__ float Wt[44][128];
    __shared__ float bias_s[44];
    __shared__ float zt[64][132];
    const int i = blockIdx.x, t = threadIdx.x;
    const float s3 = 0.5773502691896258f;
    for (int idx = t; idx < 44 * 128; idx += 256) {
        int c = idx >> 7, kk = idx & 127;
        Wt[c][kk] = (c < 12) ? s3 * Wb[kk * 12 + c] : Wdz[kk * 32 + (c - 12)];
    }
    if (t < 44) bias_s[t] = (t < 12) ? s3 * bb[t] : bdz[t - 12];
    const int jl = t & 63, cg = t >> 6;
    for (int j0 = 0; j0 < 512; j0 += 64) {
        __syncthreads();
        for (int idx = t; idx < 2048; idx += 256) {
            int r = idx >> 5, c4 = (idx & 31) << 2;
            *(float4*)&zt[r][c4] = *(const float4*)&z[((size_t)i * 512 + j0 + r) * 128 + c4];
        }
        __syncthreads();
        float acc[11];
        #pragma unroll
        for (int u = 0; u < 11; ++u) acc[u] = bias_s[cg * 11 + u];
        #pragma unroll 2
        for (int k4 = 0; k4 < 128; k4 += 4) {
            float4 zv = *(float4*)&zt[jl][k4];
            #pragma unroll
            for (int u = 0; u < 11; ++u) {
                float4 wv = *(float4*)&Wt[cg * 11 + u][k4];
                acc[u] = fmaf(zv.x, wv.x, acc[u]);
                acc[u] = fmaf(zv.y, wv.y, acc[u]);
                acc[u] = fmaf(zv.z, wv.z, acc[u]);
                acc[u] = fmaf(zv.w, wv.w, acc[u]);
            }
        }
        #pragma unroll
        for (int u = 0; u < 11; ++u)
            bpz[((size_t)i * 44 + cg * 11 + u) * 512 + j0 + jl] = acc[u];
    }
}

// ---------------------------------------------------------------- attn_a
// logits + per-wave softmax for 4 heads; writes a[h][i][j] (post-softmax).
__global__ __launch_bounds__(256) void k_attn_a(
    const float* __restrict__ qw, const float* __restrict__ kw,
    const float* __restrict__ qpw, const float* __restrict__ kpw,
    const float* __restrict__ bpz, const float* __restrict__ mask,
    const float* __restrict__ hwp, float* __restrict__ abuf)
{
    __shared__ float pls[4][520];
    __shared__ float qs[64], qps[48], cpt4[4];
    const int i = blockIdx.x, hg = blockIdx.y;
    const int t = threadIdx.x;
    if (t < 64) qs[t] = qw[(size_t)i * 192 + hg * 64 + t];
    if (t < 48) qps[t] = qpw[(size_t)i * 144 + hg * 48 + t];
    if (t < 4) cpt4[t] = -0.5f * 0.13608276348795434f * softplusf(hwp[hg * 4 + t]);
    const float mask_i = mask[i];
    __syncthreads();
    #pragma unroll 2
    for (int it = 0; it < 8; ++it) {
        int idx = t + it * 256;
        int hh = idx >> 9, j = idx & 511;
        int h = hg * 4 + hh;
        float kj[16], kpj[12];
        { const float4* kr = (const float4*)&kw[(size_t)j * 192 + h * 16];
          *(float4*)&kj[0] = kr[0]; *(float4*)&kj[4] = kr[1];
          *(float4*)&kj[8] = kr[2]; *(float4*)&kj[12] = kr[3]; }
        { const float4* kr = (const float4*)&kpw[(size_t)j * 144 + h * 12];
          *(float4*)&kpj[0] = kr[0]; *(float4*)&kpj[4] = kr[1]; *(float4*)&kpj[8] = kr[2]; }
        float qk = 0.f;
        #pragma unroll
        for (int c = 0; c < 16; ++c) qk = fmaf(qs[hh * 16 + c], kj[c], qk);
        float pts = 0.f;
        #pragma unroll
        for (int p = 0; p < 4; ++p) {
            float dx = qps[hh*12+p*3+0] - kpj[p*3+0];
            float dy = qps[hh*12+p*3+1] - kpj[p*3+1];
            float dz = qps[hh*12+p*3+2] - kpj[p*3+2];
            pts += dx*dx + dy*dy + dz*dz;
        }
        float lg = fmaf(0.14433756729740643f, qk, bpz[((size_t)i * 44 + h) * 512 + j]);
        lg = fmaf(cpt4[hh], pts, lg);
        lg += INFV * (mask_i * mask[j] - 1.0f);
        pls[hh][j] = lg;
    }
    __syncthreads();
    // per-wave softmax: wave w handles head hg*4+w, no further barriers
    const int w = t >> 6, lane = t & 63;
    float v[8];
    #pragma unroll
    for (int k = 0; k < 8; ++k) v[k] = pls[w][lane + k * 64];
    float mx = v[0];
    #pragma unroll
    for (int k = 1; k < 8; ++k) mx = fmaxf(mx, v[k]);
    #pragma unroll
    for (int off = 32; off; off >>= 1) mx = fmaxf(mx, __shfl_xor(mx, off));
    float sm = 0.f;
    #pragma unroll
    for (int k = 0; k < 8; ++k) { v[k] = __expf(v[k] - mx); sm += v[k]; }
    #pragma unroll
    for (int off = 32; off; off >>= 1) sm += __shfl_xor(sm, off);
    const float inv = 1.0f / sm;
    float* dst = abuf + ((size_t)(hg * 4 + w) * 512 + i) * 512;
    #pragma unroll
    for (int k = 0; k < 8; ++k) dst[lane + k * 64] = v[k] * inv;
}

// ---------------------------------------------------------------- attn_pair
// o_pair[h][c] = sum_j a[h][j] * pz[c][j]; a staged in LDS (broadcast reads).
__global__ __launch_bounds__(256) void k_attn_pair(
    const float* __restrict__ abuf, const float* __restrict__ bpz,
    float* __restrict__ ocat)
{
    __shared__ float al[12][512];
    const int i = blockIdx.x, t = threadIdx.x;
    #pragma unroll
    for (int u = 0; u < 12; ++u) {
        al[u][t] = abuf[(size_t)u * 262144 + (size_t)i * 512 + t];
        al[u][t + 256] = abuf[(size_t)u * 262144 + (size_t)i * 512 + t + 256];
    }
    __syncthreads();
    const int c = t & 31;
    const int h1 = t >> 5;             // 0..7
    const bool dual = (t < 128);       // also handles h1+8 (8..11)
    const float* pz = bpz + ((size_t)i * 44 + 12 + c) * 512;
    const float* a1 = al[h1];
    const float* a2 = al[dual ? h1 + 8 : 0];
    float acc1 = 0.f, acc2 = 0.f;
    for (int j = 0; j < 512; j += 4) {
        float4 p = *(const float4*)&pz[j];
        acc1 = fmaf(a1[j+0], p.x, acc1);
        acc1 = fmaf(a1[j+1], p.y, acc1);
        acc1 = fmaf(a1[j+2], p.z, acc1);
        acc1 = fmaf(a1[j+3], p.w, acc1);
        if (dual) {
            acc2 = fmaf(a2[j+0], p.x, acc2);
            acc2 = fmaf(a2[j+1], p.y, acc2);
            acc2 = fmaf(a2[j+2], p.z, acc2);
            acc2 = fmaf(a2[j+3], p.w, acc2);
        }
    }
    ocat[(size_t)i * 1152 + 576 + h1 * 32 + c] = acc1;
    if (dual) ocat[(size_t)i * 1152 + 576 + (h1 + 8) * 32 + c] = acc2;
}

// ---------------------------------------------------------------- gemm_ov
// per-head: C_h[512 i][40] = A_h[512 i][512 j] @ [v_h(16) | vp_h(24)]
__global__ __launch_bounds__(256) void k_gemm_ov(
    const float* __restrict__ abuf, const float* __restrict__ vw,
    const float* __restrict__ vpw, float* __restrict__ cbuf)
{
    __shared__ float As[64][68];
    __shared__ float Bs[64][44];
    const int i0 = blockIdx.x * 64, h = blockIdx.y;
    const int t = threadIdx.x;
    const int sr = t >> 4, sk4 = (t & 15) << 2;
    const int r1 = t >> 3;        // 0..31 (also r1+32)
    const int cb = t & 7;
    float acc[2][5];
    #pragma unroll
    for (int u = 0; u < 5; ++u) { acc[0][u] = 0.f; acc[1][u] = 0.f; }
    for (int kc = 0; kc < 512; kc += 64) {
        __syncthreads();
        #pragma unroll
        for (int rep = 0; rep < 4; ++rep) {
            int row = sr + rep * 16;
            *(float4*)&As[row][sk4] =
                *(const float4*)&abuf[(size_t)h * 262144 + (size_t)(i0 + row) * 512 + kc + sk4];
        }
        #pragma unroll
        for (int u = 0; u < 10; ++u) {
            int idx = t + u * 256;
            int r = idx / 40, cc = idx % 40;
            Bs[r][cc] = (cc < 16) ? vw[(size_t)(kc + r) * 192 + h * 16 + cc]
                                  : vpw[(size_t)(kc + r) * 288 + h * 24 + (cc - 16)];
        }
        __syncthreads();
        #pragma unroll 4
        for (int kk = 0; kk < 64; ++kk) {
            float av1 = As[r1][kk], av2 = As[r1 + 32][kk];
            #pragma unroll
            for (int u = 0; u < 5; ++u) {
                float b = Bs[kk][cb + 8 * u];
                acc[0][u] = fmaf(av1, b, acc[0][u]);
                acc[1][u] = fmaf(av2, b, acc[1][u]);
            }
        }
    }
    #pragma unroll
    for (int u = 0; u < 5; ++u) {
        cbuf[((size_t)h * 512 + i0 + r1) * 40 + cb + 8 * u] = acc[0][u];
        cbuf[((size_t)h * 512 + i0 + r1 + 32) * 40 + cb + 8 * u] = acc[1][u];
    }
}

// ---------------------------------------------------------------- optfin
__global__ __launch_bounds__(256) void k_optfin(
    const float* __restrict__ cbuf, const float* __restrict__ rots,
    const float* __restrict__ trans, float* __restrict__ ocat)
{
    __shared__ float cl[4][12][40];
    const int i0 = blockIdx.x * 4, t = threadIdx.x;
    for (int idx = t; idx < 1920; idx += 256) {
        int ii = idx / 480, rem = idx % 480;
        int h = rem / 40, c = rem % 40;
        cl[ii][h][c] = cbuf[((size_t)h * 512 + i0 + ii) * 40 + c];
    }
    __syncthreads();
    for (int idx = t; idx < 768; idx += 256) {
        int ii = idx / 192, o = idx % 192;
        ocat[(size_t)(i0 + ii) * 1152 + o] = cl[ii][o >> 4][o & 15];
    }
    for (int idx = t; idx < 384; idx += 256) {
        int ii = idx / 96, hp = idx % 96;
        int h = hp >> 3, p = hp & 7;
        int i = i0 + ii;
        const float* R = &rots[(size_t)i * 9];
        float gx = cl[ii][h][16 + p*3 + 0] - trans[(size_t)i*3 + 0];
        float gy = cl[ii][h][16 + p*3 + 1] - trans[(size_t)i*3 + 1];
        float gz = cl[ii][h][16 + p*3 + 2] - trans[(size_t)i*3 + 2];
        float lx = R[0]*gx + R[3]*gy + R[6]*gz;
        float ly = R[1]*gx + R[4]*gy + R[7]*gz;
        float lz = R[2]*gx + R[5]*gy + R[8]*gz;
        float nm = sqrtf(lx*lx + ly*ly + lz*lz + 1e-8f);
        int col = h * 8 + p;
        size_t base = (size_t)i * 1152;
        ocat[base + 192 + col] = lx;
        ocat[base + 288 + col] = ly;
        ocat[base + 384 + col] = lz;
        ocat[base + 480 + col] = nm;
    }
}

// ---------------------------------------------------------------- surf attn (single-pass flash)
__global__ __launch_bounds__(256) void k_surf(
    const float* __restrict__ sqw, const float* __restrict__ skv,
    const float* __restrict__ trans, const float* __restrict__ mask,
    const float* __restrict__ sp, const float* __restrict__ smask,
    const float* __restrict__ sbwp, float* __restrict__ ocat)
{
    __shared__ float sk_t[256][17];
    __shared__ float sv_t[256][17];
    __shared__ float sp_t[768];
    __shared__ float smask_t[256];
    const int h = blockIdx.x >> 5;
    const int n0 = (blockIdx.x & 31) * 16;
    const int t = threadIdx.x;
    const int tn = t >> 4, tm = t & 15;
    const int n = n0 + tn;
    const float sbw = softplusf(sbwp[0]);
    float qreg[16];
    #pragma unroll
    for (int c = 0; c < 16; ++c) qreg[c] = sqw[(size_t)n * 192 + h * 16 + c];
    const float trx = trans[(size_t)n*3+0], tryy = trans[(size_t)n*3+1], trz = trans[(size_t)n*3+2];
    const float mask_n = mask[n];
    float mx = -1e30f, l = 0.f;
    float acc[16];
    #pragma unroll
    for (int c = 0; c < 16; ++c) acc[c] = 0.f;
    for (int tile = 0; tile < 8; ++tile) {
        __syncthreads();
        const int mb = tile * 256;
        for (int idx = t; idx < 1024; idx += 256) {
            int ml = idx >> 2, c4 = (idx & 3) << 2;
            float4 v4 = *(const float4*)&skv[(size_t)(mb + ml) * 384 + h * 16 + c4];
            sk_t[ml][c4+0]=v4.x; sk_t[ml][c4+1]=v4.y; sk_t[ml][c4+2]=v4.z; sk_t[ml][c4+3]=v4.w;
            float4 w4 = *(const float4*)&skv[(size_t)(mb + ml) * 384 + 192 + h * 16 + c4];
            sv_t[ml][c4+0]=w4.x; sv_t[ml][c4+1]=w4.y; sv_t[ml][c4+2]=w4.z; sv_t[ml][c4+3]=w4.w;
        }
        for (int idx = t; idx < 768; idx += 256) sp_t[idx] = sp[(size_t)mb * 3 + idx];
        smask_t[t] = smask[mb + t];
        __syncthreads();
        float lgr[16];
        float tmax = -1e30f;
        #pragma unroll
        for (int kk = 0; kk < 16; ++kk) {
            int ml = tm + (kk << 4);
            float dot = 0.f;
            #pragma unroll
            for (int c = 0; c < 16; ++c) dot = fmaf(qreg[c], sk_t[ml][c], dot);
            float dx = trx - sp_t[ml*3+0], dy = tryy - sp_t[ml*3+1], dz = trz - sp_t[ml*3+2];
            float lg = fmaf(0.25f, dot, -0.5f * sbw * (dx*dx + dy*dy + dz*dz));
            lg += INFV * (mask_n * smask_t[ml] - 1.0f);
            lgr[kk] = lg;
            tmax = fmaxf(tmax, lg);
        }
        float mn = fmaxf(mx, tmax);
        float scale = __expf(mx - mn);
        l *= scale;
        #pragma unroll
        for (int c = 0; c < 16; ++c) acc[c] *= scale;
        #pragma unroll
        for (int kk = 0; kk < 16; ++kk) {
            int ml = tm + (kk << 4);
            float w = __expf(lgr[kk] - mn);
            l += w;
            #pragma unroll
            for (int c = 0; c < 16; ++c) acc[c] = fmaf(w, sv_t[ml][c], acc[c]);
        }
        mx = mn;
    }
    #pragma unroll
    for (int off = 1; off < 16; off <<= 1) {
        float m2 = __shfl_xor(mx, off), l2 = __shfl_xor(l, off);
        float mn = fmaxf(mx, m2);
        float e1 = __expf(mx - mn), e2 = __expf(m2 - mn);
        l = l * e1 + l2 * e2;
        #pragma unroll
        for (int c = 0; c < 16; ++c) {
            float a2 = __shfl_xor(acc[c], off);
            acc[c] = acc[c] * e1 + a2 * e2;
        }
        mx = mn;
    }
    const float invl = 1.0f / l;
    float outv = 0.f;
    #pragma unroll
    for (int c = 0; c < 16; ++c) if (tm == c) outv = acc[c];
    ocat[(size_t)n * 1152 + 960 + h * 16 + tm] = outv * invl;
}

// ---------------------------------------------------------------- tlog
__global__ __launch_bounds__(256) void k_tlog(
    const float* __restrict__ sqw, const float* __restrict__ skv,
    const float* __restrict__ trans, const float* __restrict__ mask,
    const float* __restrict__ sp, const float* __restrict__ smask,
    const float* __restrict__ sbwp, float* __restrict__ logits,
    float* __restrict__ stat_m, float* __restrict__ stat_il)
{
    __shared__ float sk_s[32][16];
    __shared__ float sq_s[32][16];
    __shared__ float trans_s[96];
    __shared__ float mask_s[32];
    __shared__ float spm_s[96];
    __shared__ float smask_s[32];
    const int h = blockIdx.y;
    const int m0 = blockIdx.x * 32;
    const int t = threadIdx.x;
    const int tmg = t >> 5, tnl = t & 31;
    const float sbw = softplusf(sbwp[0]);
    for (int idx = t; idx < 512; idx += 256) {
        int row = idx >> 4, c = idx & 15;
        sk_s[row][c] = skv[(size_t)(m0 + row) * 384 + h * 16 + c];
    }
    if (t < 96) spm_s[t] = sp[(size_t)m0 * 3 + t];
    if (t < 32) smask_s[t] = smask[m0 + t];
    __syncthreads();
    float skr[4][16];
    float spx[4], spy[4], spz[4], smk[4];
    #pragma unroll
    for (int mi = 0; mi < 4; ++mi) {
        int row = tmg * 4 + mi;
        #pragma unroll
        for (int c4 = 0; c4 < 16; c4 += 4)
            *(float4*)&skr[mi][c4] = *(float4*)&sk_s[row][c4];
        spx[mi] = spm_s[row*3+0]; spy[mi] = spm_s[row*3+1]; spz[mi] = spm_s[row*3+2];
        smk[mi] = smask_s[row];
    }
    float mxr[4], lr[4];
    #pragma unroll
    for (int mi = 0; mi < 4; ++mi) { mxr[mi] = -1e30f; lr[mi] = 0.f; }
    for (int nt = 0; nt < 16; ++nt) {
        __syncthreads();
        const int nb = nt * 32;
        if (t < 128) {
            int nn = t >> 2, c4 = (t & 3) << 2;
            *(float4*)&sq_s[nn][c4] = *(const float4*)&sqw[(size_t)(nb + nn) * 192 + h * 16 + c4];
        }
        if (t < 96) trans_s[t] = trans[(size_t)nb * 3 + t];
        if (t < 32) mask_s[t] = mask[nb + t];
        __syncthreads();
        float q[16];
        #pragma unroll
        for (int c4 = 0; c4 < 16; c4 += 4)
            *(float4*)&q[c4] = *(float4*)&sq_s[tnl][c4];
        const float tx = trans_s[tnl*3+0], ty = trans_s[tnl*3+1], tz = trans_s[tnl*3+2];
        const float mkn = mask_s[tnl];
        #pragma unroll
        for (int mi = 0; mi < 4; ++mi) {
            float dot = 0.f;
            #pragma unroll
            for (int c = 0; c < 16; ++c) dot = fmaf(skr[mi][c], q[c], dot);
            float dx = tx - spx[mi], dy = ty - spy[mi], dz = tz - spz[mi];
            float mterm = INFV * (mkn * smk[mi] - 1.0f) - 0.5f * sbw * (dx*dx + dy*dy + dz*dz);
            float lg = fmaf(0.25f, dot, mterm);
            logits[((size_t)(m0 + tmg * 4 + mi) * 12 + h) * 512 + nb + tnl] = lg;
            float newm = fmaxf(mxr[mi], lg);
            lr[mi] = lr[mi] * __expf(mxr[mi] - newm) + __expf(lg - newm);
            mxr[mi] = newm;
        }
    }
    #pragma unroll
    for (int off = 1; off < 32; off <<= 1) {
        #pragma unroll
        for (int mi = 0; mi < 4; ++mi) {
            float m2 = __shfl_xor(mxr[mi], off), l2 = __shfl_xor(lr[mi], off);
            float newm = fmaxf(mxr[mi], m2);
            lr[mi] = lr[mi] * __expf(mxr[mi] - newm) + l2 * __expf(m2 - newm);
            mxr[mi] = newm;
        }
    }
    if (tnl == 0) {
        #pragma unroll
        for (int mi = 0; mi < 4; ++mi) {
            int m = m0 + tmg * 4 + mi;
            stat_m[(size_t)m * 12 + h] = mxr[mi];
            stat_il[(size_t)m * 12 + h] = 1.0f / lr[mi];
        }
    }
}

// ---------------------------------------------------------------- tw
__global__ __launch_bounds__(256) void k_tw(
    const float* __restrict__ logits, const float* __restrict__ stat_m,
    const float* __restrict__ stat_il, float* __restrict__ w)
{
    __shared__ float mxs[12], ils[12];
    const int m = blockIdx.x, t = threadIdx.x;
    if (t < 12) { mxs[t] = stat_m[(size_t)m * 12 + t]; ils[t] = stat_il[(size_t)m * 12 + t]; }
    __syncthreads();
    const float* lp = logits + (size_t)m * 12 * 512;
    float a0 = 0.f, a1 = 0.f;
    #pragma unroll
    for (int h = 0; h < 12; ++h) {
        a0 += __expf(lp[h * 512 + t] - mxs[h]) * ils[h];
        a1 += __expf(lp[h * 512 + 256 + t] - mxs[h]) * ils[h];
    }
    w[(size_t)m * 512 + t] = a0 * (1.0f / 12.0f);
    w[(size_t)m * 512 + 256 + t] = a1 * (1.0f / 12.0f);
}

// ---------------------------------------------------------------- surf out
__global__ __launch_bounds__(256) void k_surf_out(
    const float* __restrict__ sfeat, const float* __restrict__ saggw,
    const float* __restrict__ Wso, const float* __restrict__ bso,
    float* __restrict__ out)
{
    __shared__ float wl[12304];
    const int t = threadIdx.x;
    for (int idx = t; idx < 12288; idx += 256) {
        int k = idx >> 4, c = idx & 15;
        wl[(k / 192) * 3076 + (k % 192) * 16 + c] = Wso[idx];
    }
    const int m = blockIdx.x * 64 + (t >> 2);
    const int kq = t & 3;
    const float* src = (kq < 2) ? &sfeat[(size_t)m * 384 + kq * 192]
                                : &saggw[(size_t)m * 384 + (kq - 2) * 192];
    __syncthreads();
    float acc[16];
    #pragma unroll
    for (int c = 0; c < 16; ++c) acc[c] = 0.f;
    const float* wb = &wl[kq * 3076];
    for (int k = 0; k < 192; k += 4) {
        float4 v = *(const float4*)&src[k];
        #pragma unroll
        for (int e = 0; e < 4; ++e) {
            float sv = (&v.x)[e];
            #pragma unroll
            for (int c = 0; c < 16; ++c)
                acc[c] = fmaf(sv, wb[(k + e) * 16 + c], acc[c]);
        }
    }
    #pragma unroll
    for (int c = 0; c < 16; ++c) {
        acc[c] += __shfl_xor(acc[c], 1);
        acc[c] += __shfl_xor(acc[c], 2);
    }
    #pragma unroll
    for (int c = 0; c < 16; ++c) {
        if ((c >> 2) == kq) out[196608 + (size_t)m * 16 + c] = acc[c] + bso[c];
    }
}

// ----------------------------------------------------------------
extern "C" void kernel_launch(void* const* d_in, const int* in_sizes, int n_in,
                              void* d_out, int out_size, void* d_ws, size_t ws_size,
                              hipStream_t stream)
{
    (void)in_sizes; (void)n_in; (void)out_size; (void)ws_size;
    const float* s     = (const float*)d_in[0];
    const float* z     = (const float*)d_in[1];
    const float* rots  = (const float*)d_in[2];
    const float* trans = (const float*)d_in[3];
    const float* mask  = (const float*)d_in[4];
    const float* sp    = (const float*)d_in[5];
    const float* sf    = (const float*)d_in[6];
    const float* smask = (const float*)d_in[7];
    const float* Wq    = (const float*)d_in[8];  const float* bq   = (const float*)d_in[9];
    const float* Wkv   = (const float*)d_in[10]; const float* bkv  = (const float*)d_in[11];
    const float* Wqp   = (const float*)d_in[12]; const float* bqp  = (const float*)d_in[13];
    const float* Wkvp  = (const float*)d_in[14]; const float* bkvp = (const float*)d_in[15];
    const float* Wse   = (const float*)d_in[16]; const float* bse  = (const float*)d_in[17];
    const float* Wsq   = (const float*)d_in[18]; const float* bsq  = (const float*)d_in[19];
    const float* Wsk   = (const float*)d_in[20]; const float* bsk  = (const float*)d_in[21];
    const float* Wsv   = (const float*)d_in[22]; const float* bsv  = (const float*)d_in[23];
    const float* Wb    = (const float*)d_in[24]; const float* bb   = (const float*)d_in[25];
    const float* Wdz   = (const float*)d_in[26]; const float* bdz  = (const float*)d_in[27];
    const float* hw    = (const float*)d_in[28]; const float* sbw  = (const float*)d_in[29];
    const float* Wout  = (const float*)d_in[30]; const float* bout = (const float*)d_in[31];
    const float* Wso   = (const float*)d_in[32]; const float* bso  = (const float*)d_in[33];
    float* out = (float*)d_out;

    float* qw    = (float*)d_ws;
    float* kw    = qw    + (size_t)512 * 192;
    float* vw    = kw    + (size_t)512 * 192;
    float* sqw   = vw    + (size_t)512 * 192;
    float* qpw   = sqw   + (size_t)512 * 192;
    float* kpw   = qpw   + (size_t)512 * 144;
    float* vpw   = kpw   + (size_t)512 * 144;
    float* sfeat = vpw   + (size_t)512 * 288;
    float* skv   = sfeat + (size_t)2048 * 384;
    float* ocat  = skv   + (size_t)2048 * 384;
    float* sagg  = ocat  + (size_t)512 * 1152;
    // region: proj (688K fl) -> bpz (11.5M fl) -> logits (12.6M fl), stream-serialized
    float* region = sagg + (size_t)2048 * 384;
    float* proj   = region;
    float* bpz    = region;
    float* logits = region;
    float* wt1   = region + (size_t)2048 * 12 * 512;
    float* wt2   = wt1   + (size_t)1344 * 384;
    float* wt3   = wt2   + (size_t)384 * 384;
    float* b1    = wt3   + (size_t)384 * 1152;
    float* b2    = b1    + 1344;
    float* st    = b2    + 384;
    float* wbuf  = st    + (size_t)384 * 512;
    float* statm = wbuf  + (size_t)2048 * 512;
    float* stati = statm + (size_t)2048 * 12;
    float* abuf  = stati + (size_t)2048 * 12;     // a[12][512][512]
    float* cbuf  = abuf  + (size_t)12 * 512 * 512; // c[12][512][40]

    k_pack<<<dim3(1099), dim3(256), 0, stream>>>(Wq, Wsq, Wkv, Wqp, Wkvp, Wsk, Wsv, Wout,
        bq, bsq, bkv, bqp, bkvp, bsk, bsv, wt1, wt2, wt3, b1, b2);
    k_transp<<<dim3(12, 16), dim3(256), 0, stream>>>(s, st);
    k_gemm<384, true><<<dim3(21, 8), dim3(256), 0, stream>>>(s, wt1, b1, proj, 1344);
    k_scatter<<<dim3(128), dim3(256), 0, stream>>>(proj, rots, trans,
        qw, kw, vw, sqw, qpw, kpw, vpw);
    k_sfeat<<<dim3(256), dim3(256), 0, stream>>>(sf, Wse, bse, sfeat);
    k_gemm<384, true><<<dim3(6, 32), dim3(256), 0, stream>>>(sfeat, wt2, b2, skv, 384);
    k_zpass<<<dim3(512), dim3(256), 0, stream>>>(z, Wb, bb, Wdz, bdz, bpz);
    k_attn_a<<<dim3(512, 3), dim3(256), 0, stream>>>(qw, kw, qpw, kpw, bpz, mask, hw, abuf);
    k_attn_pair<<<dim3(512), dim3(256), 0, stream>>>(abuf, bpz, ocat);
    k_gemm_ov<<<dim3(8, 12), dim3(256), 0, stream>>>(abuf, vw, vpw, cbuf);
    k_optfin<<<dim3(128), dim3(256), 0, stream>>>(cbuf, rots, trans, ocat);
    k_surf<<<dim3(384), dim3(256), 0, stream>>>(sqw, skv, trans, mask, sp, smask,
        sbw, ocat);
    k_tlog<<<dim3(64, 12), dim3(256), 0, stream>>>(sqw, skv, trans, mask, sp, smask,
        sbw, logits, statm, stati);
    k_tw<<<dim3(2048), dim3(256), 0, stream>>>(logits, statm, stati, wbuf);
    k_gemm<512, false><<<dim3(6, 32), dim3(256), 0, stream>>>(wbuf, st, nullptr, sagg, 384);
    k_surf_out<<<dim3(32), dim3(256), 0, stream>>>(sfeat, sagg, Wso, bso, out);
    k_gemm<1152, true><<<dim3(6, 8), dim3(256), 0, stream>>>(ocat, wt3, bout, out, 384);
}

// Round 8
// 554.902 us; speedup vs baseline: 1.0310x; 1.0275x over previous
//
#include <hip/hip_runtime.h>
#include <cstddef>

// IPA + surface cross-attention, B=1, N=512, M=2048, H=12, C_H=16, C_S=384.
// Round 7: k_zpass rework — prepacked scaled W (k_packz), wave-uniform W via
// readfirstlane -> s_load + v_fmac(v,s,v) inner loop, LDS 57->34KB, grid
// (512,2) for 4 blocks/CU. Rest unchanged from R3.

#define CS 384
#define INFV 100000.0f

__device__ __forceinline__ float softplusf(float x) { return log1pf(__expf(x)); }

// ---------------------------------------------------------------- pack
__global__ __launch_bounds__(256) void k_pack(
    const float* __restrict__ Wq, const float* __restrict__ Wsq,
    const float* __restrict__ Wkv, const float* __restrict__ Wqp,
    const float* __restrict__ Wkvp, const float* __restrict__ Wsk,
    const float* __restrict__ Wsv, const float* __restrict__ Wout,
    const float* __restrict__ bq, const float* __restrict__ bsq,
    const float* __restrict__ bkv, const float* __restrict__ bqp,
    const float* __restrict__ bkvp, const float* __restrict__ bsk,
    const float* __restrict__ bsv,
    float* __restrict__ wt1, float* __restrict__ wt2, float* __restrict__ wt3,
    float* __restrict__ b1, float* __restrict__ b2)
{
    const int b = blockIdx.x, t = threadIdx.x;
    if (b >= 1092) {
        int idx = (b - 1092) * 256 + t;
        if (idx < 1344) {
            float v;
            if (idx < 192) v = bq[idx];
            else if (idx < 384) v = bsq[idx - 192];
            else if (idx < 768) v = bkv[idx - 384];
            else if (idx < 912) v = bqp[idx - 768];
            else v = bkvp[idx - 912];
            b1[idx] = v;
        } else if (idx < 1728) {
            int i2 = idx - 1344;
            b2[i2] = (i2 < 192) ? bsk[i2] : bsv[i2 - 192];
        }
        return;
    }
    const float* src; float* dst; int C, coff, tile, ldd;
    if (b < 72)       { src = Wq;   C = 192; dst = wt1; coff = 0;   ldd = 384;  tile = b; }
    else if (b < 144) { src = Wsq;  C = 192; dst = wt1; coff = 192; ldd = 384;  tile = b - 72; }
    else if (b < 288) { src = Wkv;  C = 384; dst = wt1; coff = 384; ldd = 384;  tile = b - 144; }
    else if (b < 348) { src = Wqp;  C = 144; dst = wt1; coff = 768; ldd = 384;  tile = b - 288; }
    else if (b < 516) { src = Wkvp; C = 432; dst = wt1; coff = 912; ldd = 384;  tile = b - 348; }
    else if (b < 588) { src = Wsk;  C = 192; dst = wt2; coff = 0;   ldd = 384;  tile = b - 516; }
    else if (b < 660) { src = Wsv;  C = 192; dst = wt2; coff = 192; ldd = 384;  tile = b - 588; }
    else              { src = Wout; C = 384; dst = wt3; coff = 0;   ldd = 1152; tile = b - 660; }
    const int cT = (C + 31) >> 5;
    const int tk = tile / cT, tc = tile % cT;
    __shared__ float l[32][33];
    const int tr = t >> 5, tcc = t & 31;
    #pragma unroll
    for (int rr = 0; rr < 4; ++rr) {
        int kloc = tr * 4 + rr;
        int cg = tc * 32 + tcc;
        l[kloc][tcc] = (cg < C) ? src[(size_t)(tk * 32 + kloc) * C + cg] : 0.f;
    }
    __syncthreads();
    #pragma unroll
    for (int rr = 0; rr < 4; ++rr) {
        int cloc = tr * 4 + rr;
        int cg = tc * 32 + cloc;
        if (cg < C) dst[(size_t)(coff + cg) * ldd + tk * 32 + tcc] = l[tcc][cloc];
    }
}

// ---------------------------------------------------------------- packz
// Wz[44][128] (c<12: sqrt(1/3)*Wb col, else Wdz col), bz[44].
__global__ __launch_bounds__(256) void k_packz(
    const float* __restrict__ Wb, const float* __restrict__ bb,
    const float* __restrict__ Wdz, const float* __restrict__ bdz,
    float* __restrict__ wz, float* __restrict__ bz)
{
    const float s3 = 0.5773502691896258f;
    int idx = blockIdx.x * 256 + threadIdx.x;
    if (idx < 5632) {
        int c = idx >> 7, kk = idx & 127;
        wz[idx] = (c < 12) ? s3 * Wb[kk * 12 + c] : Wdz[kk * 32 + (c - 12)];
    } else if (idx < 5676) {
        int c = idx - 5632;
        bz[c] = (c < 12) ? s3 * bb[c] : bdz[c - 12];
    }
}

// ---------------------------------------------------------------- transpose
__global__ __launch_bounds__(256) void k_transp(
    const float* __restrict__ A, float* __restrict__ At)
{
    __shared__ float tile[32][33];
    const int r0 = blockIdx.y * 32, c0 = blockIdx.x * 32;
    const int tr = threadIdx.x >> 5, tc = threadIdx.x & 31;
    #pragma unroll
    for (int rr = 0; rr < 4; ++rr)
        tile[tr + rr * 8][tc] = A[(size_t)(r0 + tr + rr * 8) * 384 + c0 + tc];
    __syncthreads();
    #pragma unroll
    for (int rr = 0; rr < 4; ++rr)
        At[(size_t)(c0 + tr + rr * 8) * 512 + r0 + tc] = tile[tc][tr + rr * 8];
}

// ---------------------------------------------------------------- gemm
template<int KTOT, bool HB>
__global__ __launch_bounds__(256) void k_gemm(
    const float* __restrict__ A, const float* __restrict__ Wt,
    const float* __restrict__ bias, float* __restrict__ C, int ldc)
{
    __shared__ float As[64][68];
    __shared__ float Ws[64][68];
    const int t = threadIdx.x;
    const int c0 = blockIdx.x * 64, m0 = blockIdx.y * 64;
    const int sr = t >> 4, sk4 = (t & 15) << 2;
    const int wid = t >> 6, lane = t & 63;
    const int wr = (wid >> 1) * 32, wc = (wid & 1) * 32;
    const int lr = lane >> 3, lc = lane & 7;
    float acc[4][4];
    #pragma unroll
    for (int j = 0; j < 4; ++j) {
        float bv = HB ? bias[c0 + wc + lc + 8 * j] : 0.f;
        #pragma unroll
        for (int i = 0; i < 4; ++i) acc[i][j] = bv;
    }
    for (int kc = 0; kc < KTOT; kc += 64) {
        __syncthreads();
        #pragma unroll
        for (int rep = 0; rep < 4; ++rep) {
            int row = sr + rep * 16;
            *(float4*)&As[row][sk4] = *(const float4*)&A[(size_t)(m0 + row) * KTOT + kc + sk4];
            *(float4*)&Ws[row][sk4] = *(const float4*)&Wt[(size_t)(c0 + row) * KTOT + kc + sk4];
        }
        __syncthreads();
        #pragma unroll 4
        for (int k4 = 0; k4 < 16; ++k4) {
            float4 a[4], w[4];
            #pragma unroll
            for (int i = 0; i < 4; ++i) a[i] = *(float4*)&As[wr + lr + 8 * i][k4 * 4];
            #pragma unroll
            for (int j = 0; j < 4; ++j) w[j] = *(float4*)&Ws[wc + lc + 8 * j][k4 * 4];
            #pragma unroll
            for (int i = 0; i < 4; ++i) {
                #pragma unroll
                for (int j = 0; j < 4; ++j) {
                    acc[i][j] = fmaf(a[i].x, w[j].x, acc[i][j]);
                    acc[i][j] = fmaf(a[i].y, w[j].y, acc[i][j]);
                    acc[i][j] = fmaf(a[i].z, w[j].z, acc[i][j]);
                    acc[i][j] = fmaf(a[i].w, w[j].w, acc[i][j]);
                }
            }
        }
    }
    #pragma unroll
    for (int i = 0; i < 4; ++i) {
        #pragma unroll
        for (int j = 0; j < 4; ++j)
            C[(size_t)(m0 + wr + lr + 8 * i) * ldc + c0 + wc + lc + 8 * j] = acc[i][j];
    }
}

// ---------------------------------------------------------------- scatter
__global__ __launch_bounds__(256) void k_scatter(
    const float* __restrict__ proj, const float* __restrict__ rots,
    const float* __restrict__ trans,
    float* __restrict__ qw, float* __restrict__ kw, float* __restrict__ vw,
    float* __restrict__ sqw, float* __restrict__ qpw, float* __restrict__ kpw,
    float* __restrict__ vpw)
{
    __shared__ float p[4][1344];
    const int n0 = blockIdx.x * 4, t = threadIdx.x;
    for (int idx = t; idx < 1344; idx += 256) {
        #pragma unroll
        for (int r = 0; r < 4; ++r) p[r][idx] = proj[(size_t)(n0 + r) * 1344 + idx];
    }
    __syncthreads();
    for (int idx = t; idx < 3072; idx += 256) {
        int r = idx / 768, c = idx % 768;
        int n = n0 + r;
        float v = p[r][c];
        if (c < 192) qw[(size_t)n * 192 + c] = v;
        else if (c < 384) sqw[(size_t)n * 192 + (c - 192)] = v;
        else {
            int cc = c - 384, h = cc >> 5, sub = cc & 31;
            if (sub < 16) kw[(size_t)n * 192 + h * 16 + sub] = v;
            else          vw[(size_t)n * 192 + h * 16 + (sub - 16)] = v;
        }
    }
    for (int idx = t; idx < 2304; idx += 256) {
        int r = idx / 576, rem = idx % 576;
        int n = n0 + r;
        const float* R = &rots[(size_t)n * 9];
        const float* tr = &trans[(size_t)n * 3];
        if (rem < 144) {
            int pp = rem / 3, d = rem % 3;
            float v = fmaf(R[d*3+0], p[r][768 + pp],
                      fmaf(R[d*3+1], p[r][768 + 48 + pp],
                      fmaf(R[d*3+2], p[r][768 + 96 + pp], tr[d])));
            qpw[(size_t)n * 144 + pp * 3 + d] = v;
        } else {
            int rem2 = rem - 144; int pp = rem2 / 3, d = rem2 % 3;
            float v = fmaf(R[d*3+0], p[r][912 + pp],
                      fmaf(R[d*3+1], p[r][912 + 144 + pp],
                      fmaf(R[d*3+2], p[r][912 + 288 + pp], tr[d])));
            int h = pp / 12, ii = pp % 12;
            if (ii < 4) kpw[(size_t)n * 144 + h * 12 + ii * 3 + d] = v;
            else        vpw[(size_t)n * 288 + h * 24 + (ii - 4) * 3 + d] = v;
        }
    }
}

// ---------------------------------------------------------------- sfeat
__global__ __launch_bounds__(256) void k_sfeat(
    const float* __restrict__ sf, const float* __restrict__ Wse,
    const float* __restrict__ bse, float* __restrict__ sfeat)
{
    __shared__ float wl[16 * 384];
    __shared__ float sfl[8][16];
    const int m0 = blockIdx.x * 8, t = threadIdx.x;
    for (int idx = t; idx < 6144; idx += 256) wl[idx] = Wse[idx];
    if (t < 128) sfl[t >> 4][t & 15] = sf[(size_t)(m0 + (t >> 4)) * 16 + (t & 15)];
    __syncthreads();
    #pragma unroll
    for (int u = 0; u < 12; ++u) {
        int idx = t + u * 256;
        int r = idx / 384, c = idx % 384;
        float a = bse[c];
        #pragma unroll
        for (int kk = 0; kk < 16; ++kk) a = fmaf(sfl[r][kk], wl[kk * 384 + c], a);
        sfeat[(size_t)(m0 + r) * 384 + c] = a;
    }
}

// ---------------------------------------------------------------- zpass v2
// bpz[i][c][j]; W via wave-uniform scalar loads, z tile in LDS.
__global__ __launch_bounds__(256) void k_zpass(
    const float* __restrict__ z, const float* __restrict__ wz,
    const float* __restrict__ bz, float* __restrict__ bpz)
{
    __shared__ float zt[64][132];
    const int i = blockIdx.x, t = threadIdx.x;
    const int jbase = blockIdx.y * 256;
    const int jl = t & 63;
    const int cgs = __builtin_amdgcn_readfirstlane(t >> 6);  // wave-uniform
    const float* __restrict__ wp = wz + cgs * 11 * 128;      // SGPR base
    float bv[11];
    #pragma unroll
    for (int u = 0; u < 11; ++u) bv[u] = bz[cgs * 11 + u];   // s_load
    for (int ch = 0; ch < 4; ++ch) {
        const int j0 = jbase + ch * 64;
        __syncthreads();
        for (int idx = t; idx < 2048; idx += 256) {
            int r = idx >> 5, c4 = (idx & 31) << 2;
            *(float4*)&zt[r][c4] = *(const float4*)&z[((size_t)i * 512 + j0 + r) * 128 + c4];
        }
        __syncthreads();
        float acc[11];
        #pragma unroll
        for (int u = 0; u < 11; ++u) acc[u] = bv[u];
        #pragma unroll 2
        for (int k4 = 0; k4 < 128; k4 += 4) {
            float4 zv = *(float4*)&zt[jl][k4];
            #pragma unroll
            for (int u = 0; u < 11; ++u) {
                const float* w = wp + u * 128 + k4;           // scalar loads
                acc[u] = fmaf(zv.x, w[0],
                         fmaf(zv.y, w[1],
                         fmaf(zv.z, w[2],
                         fmaf(zv.w, w[3], acc[u]))));
            }
        }
        #pragma unroll
        for (int u = 0; u < 11; ++u)
            bpz[((size_t)i * 44 + cgs * 11 + u) * 512 + j0 + jl] = acc[u];
    }
}

// ---------------------------------------------------------------- attn_a
__global__ __launch_bounds__(256) void k_attn_a(
    const float* __restrict__ qw, const float* __restrict__ kw,
    const float* __restrict__ qpw, const float* __restrict__ kpw,
    const float* __restrict__ bpz, const float* __restrict__ mask,
    const float* __restrict__ hwp, float* __restrict__ abuf)
{
    __shared__ float pls[4][520];
    __shared__ float qs[64], qps[48], cpt4[4];
    const int i = blockIdx.x, hg = blockIdx.y;
    const int t = threadIdx.x;
    if (t < 64) qs[t] = qw[(size_t)i * 192 + hg * 64 + t];
    if (t < 48) qps[t] = qpw[(size_t)i * 144 + hg * 48 + t];
    if (t < 4) cpt4[t] = -0.5f * 0.13608276348795434f * softplusf(hwp[hg * 4 + t]);
    const float mask_i = mask[i];
    __syncthreads();
    #pragma unroll 2
    for (int it = 0; it < 8; ++it) {
        int idx = t + it * 256;
        int hh = idx >> 9, j = idx & 511;
        int h = hg * 4 + hh;
        float kj[16], kpj[12];
        { const float4* kr = (const float4*)&kw[(size_t)j * 192 + h * 16];
          *(float4*)&kj[0] = kr[0]; *(float4*)&kj[4] = kr[1];
          *(float4*)&kj[8] = kr[2]; *(float4*)&kj[12] = kr[3]; }
        { const float4* kr = (const float4*)&kpw[(size_t)j * 144 + h * 12];
          *(float4*)&kpj[0] = kr[0]; *(float4*)&kpj[4] = kr[1]; *(float4*)&kpj[8] = kr[2]; }
        float qk = 0.f;
        #pragma unroll
        for (int c = 0; c < 16; ++c) qk = fmaf(qs[hh * 16 + c], kj[c], qk);
        float pts = 0.f;
        #pragma unroll
        for (int p = 0; p < 4; ++p) {
            float dx = qps[hh*12+p*3+0] - kpj[p*3+0];
            float dy = qps[hh*12+p*3+1] - kpj[p*3+1];
            float dz = qps[hh*12+p*3+2] - kpj[p*3+2];
            pts += dx*dx + dy*dy + dz*dz;
        }
        float lg = fmaf(0.14433756729740643f, qk, bpz[((size_t)i * 44 + h) * 512 + j]);
        lg = fmaf(cpt4[hh], pts, lg);
        lg += INFV * (mask_i * mask[j] - 1.0f);
        pls[hh][j] = lg;
    }
    __syncthreads();
    const int w = t >> 6, lane = t & 63;
    float v[8];
    #pragma unroll
    for (int k = 0; k < 8; ++k) v[k] = pls[w][lane + k * 64];
    float mx = v[0];
    #pragma unroll
    for (int k = 1; k < 8; ++k) mx = fmaxf(mx, v[k]);
    #pragma unroll
    for (int off = 32; off; off >>= 1) mx = fmaxf(mx, __shfl_xor(mx, off));
    float sm = 0.f;
    #pragma unroll
    for (int k = 0; k < 8; ++k) { v[k] = __expf(v[k] - mx); sm += v[k]; }
    #pragma unroll
    for (int off = 32; off; off >>= 1) sm += __shfl_xor(sm, off);
    const float inv = 1.0f / sm;
    float* dst = abuf + ((size_t)(hg * 4 + w) * 512 + i) * 512;
    #pragma unroll
    for (int k = 0; k < 8; ++k) dst[lane + k * 64] = v[k] * inv;
}

// ---------------------------------------------------------------- attn_pair
__global__ __launch_bounds__(256) void k_attn_pair(
    const float* __restrict__ abuf, const float* __restrict__ bpz,
    float* __restrict__ ocat)
{
    __shared__ float al[12][512];
    const int i = blockIdx.x, t = threadIdx.x;
    #pragma unroll
    for (int u = 0; u < 12; ++u) {
        al[u][t] = abuf[(size_t)u * 262144 + (size_t)i * 512 + t];
        al[u][t + 256] = abuf[(size_t)u * 262144 + (size_t)i * 512 + t + 256];
    }
    __syncthreads();
    const int c = t & 31;
    const int h1 = t >> 5;
    const bool dual = (t < 128);
    const float* pz = bpz + ((size_t)i * 44 + 12 + c) * 512;
    const float* a1 = al[h1];
    const float* a2 = al[dual ? h1 + 8 : 0];
    float acc1 = 0.f, acc2 = 0.f;
    for (int j = 0; j < 512; j += 4) {
        float4 p = *(const float4*)&pz[j];
        acc1 = fmaf(a1[j+0], p.x, acc1);
        acc1 = fmaf(a1[j+1], p.y, acc1);
        acc1 = fmaf(a1[j+2], p.z, acc1);
        acc1 = fmaf(a1[j+3], p.w, acc1);
        if (dual) {
            acc2 = fmaf(a2[j+0], p.x, acc2);
            acc2 = fmaf(a2[j+1], p.y, acc2);
            acc2 = fmaf(a2[j+2], p.z, acc2);
            acc2 = fmaf(a2[j+3], p.w, acc2);
        }
    }
    ocat[(size_t)i * 1152 + 576 + h1 * 32 + c] = acc1;
    if (dual) ocat[(size_t)i * 1152 + 576 + (h1 + 8) * 32 + c] = acc2;
}

// ---------------------------------------------------------------- gemm_ov
__global__ __launch_bounds__(256) void k_gemm_ov(
    const float* __restrict__ abuf, const float* __restrict__ vw,
    const float* __restrict__ vpw, float* __restrict__ cbuf)
{
    __shared__ float As[64][68];
    __shared__ float Bs[64][44];
    const int i0 = blockIdx.x * 64, h = blockIdx.y;
    const int t = threadIdx.x;
    const int sr = t >> 4, sk4 = (t & 15) << 2;
    const int r1 = t >> 3;
    const int cb = t & 7;
    float acc[2][5];
    #pragma unroll
    for (int u = 0; u < 5; ++u) { acc[0][u] = 0.f; acc[1][u] = 0.f; }
    for (int kc = 0; kc < 512; kc += 64) {
        __syncthreads();
        #pragma unroll
        for (int rep = 0; rep < 4; ++rep) {
            int row = sr + rep * 16;
            *(float4*)&As[row][sk4] =
                *(const float4*)&abuf[(size_t)h * 262144 + (size_t)(i0 + row) * 512 + kc + sk4];
        }
        #pragma unroll
        for (int u = 0; u < 10; ++u) {
            int idx = t + u * 256;
            int r = idx / 40, cc = idx % 40;
            Bs[r][cc] = (cc < 16) ? vw[(size_t)(kc + r) * 192 + h * 16 + cc]
                                  : vpw[(size_t)(kc + r) * 288 + h * 24 + (cc - 16)];
        }
        __syncthreads();
        #pragma unroll 4
        for (int kk = 0; kk < 64; ++kk) {
            float av1 = As[r1][kk], av2 = As[r1 + 32][kk];
            #pragma unroll
            for (int u = 0; u < 5; ++u) {
                float b = Bs[kk][cb + 8 * u];
                acc[0][u] = fmaf(av1, b, acc[0][u]);
                acc[1][u] = fmaf(av2, b, acc[1][u]);
            }
        }
    }
    #pragma unroll
    for (int u = 0; u < 5; ++u) {
        cbuf[((size_t)h * 512 + i0 + r1) * 40 + cb + 8 * u] = acc[0][u];
        cbuf[((size_t)h * 512 + i0 + r1 + 32) * 40 + cb + 8 * u] = acc[1][u];
    }
}

// ---------------------------------------------------------------- optfin
__global__ __launch_bounds__(256) void k_optfin(
    const float* __restrict__ cbuf, const float* __restrict__ rots,
    const float* __restrict__ trans, float* __restrict__ ocat)
{
    __shared__ float cl[4][12][40];
    const int i0 = blockIdx.x * 4, t = threadIdx.x;
    for (int idx = t; idx < 1920; idx += 256) {
        int ii = idx / 480, rem = idx % 480;
        int h = rem / 40, c = rem % 40;
        cl[ii][h][c] = cbuf[((size_t)h * 512 + i0 + ii) * 40 + c];
    }
    __syncthreads();
    for (int idx = t; idx < 768; idx += 256) {
        int ii = idx / 192, o = idx % 192;
        ocat[(size_t)(i0 + ii) * 1152 + o] = cl[ii][o >> 4][o & 15];
    }
    for (int idx = t; idx < 384; idx += 256) {
        int ii = idx / 96, hp = idx % 96;
        int h = hp >> 3, p = hp & 7;
        int i = i0 + ii;
        const float* R = &rots[(size_t)i * 9];
        float gx = cl[ii][h][16 + p*3 + 0] - trans[(size_t)i*3 + 0];
        float gy = cl[ii][h][16 + p*3 + 1] - trans[(size_t)i*3 + 1];
        float gz = cl[ii][h][16 + p*3 + 2] - trans[(size_t)i*3 + 2];
        float lx = R[0]*gx + R[3]*gy + R[6]*gz;
        float ly = R[1]*gx + R[4]*gy + R[7]*gz;
        float lz = R[2]*gx + R[5]*gy + R[8]*gz;
        float nm = sqrtf(lx*lx + ly*ly + lz*lz + 1e-8f);
        int col = h * 8 + p;
        size_t base = (size_t)i * 1152;
        ocat[base + 192 + col] = lx;
        ocat[base + 288 + col] = ly;
        ocat[base + 384 + col] = lz;
        ocat[base + 480 + col] = nm;
    }
}

// ---------------------------------------------------------------- surf attn
__global__ __launch_bounds__(256) void k_surf(
    const float* __restrict__ sqw, const float* __restrict__ skv,
    const float* __restrict__ trans, const float* __restrict__ mask,
    const float* __restrict__ sp, const float* __restrict__ smask,
    const float* __restrict__ sbwp, float* __restrict__ ocat)
{
    __shared__ float sk_t[256][17];
    __shared__ float sv_t[256][17];
    __shared__ float sp_t[768];
    __shared__ float smask_t[256];
    const int h = blockIdx.x >> 5;
    const int n0 = (blockIdx.x & 31) * 16;
    const int t = threadIdx.x;
    const int tn = t >> 4, tm = t & 15;
    const int n = n0 + tn;
    const float sbw = softplusf(sbwp[0]);
    float qreg[16];
    #pragma unroll
    for (int c = 0; c < 16; ++c) qreg[c] = sqw[(size_t)n * 192 + h * 16 + c];
    const float trx = trans[(size_t)n*3+0], tryy = trans[(size_t)n*3+1], trz = trans[(size_t)n*3+2];
    const float mask_n = mask[n];
    float mx = -1e30f, l = 0.f;
    float acc[16];
    #pragma unroll
    for (int c = 0; c < 16; ++c) acc[c] = 0.f;
    for (int tile = 0; tile < 8; ++tile) {
        __syncthreads();
        const int mb = tile * 256;
        for (int idx = t; idx < 1024; idx += 256) {
            int ml = idx >> 2, c4 = (idx & 3) << 2;
            float4 v4 = *(const float4*)&skv[(size_t)(mb + ml) * 384 + h * 16 + c4];
            sk_t[ml][c4+0]=v4.x; sk_t[ml][c4+1]=v4.y; sk_t[ml][c4+2]=v4.z; sk_t[ml][c4+3]=v4.w;
            float4 w4 = *(const float4*)&skv[(size_t)(mb + ml) * 384 + 192 + h * 16 + c4];
            sv_t[ml][c4+0]=w4.x; sv_t[ml][c4+1]=w4.y; sv_t[ml][c4+2]=w4.z; sv_t[ml][c4+3]=w4.w;
        }
        for (int idx = t; idx < 768; idx += 256) sp_t[idx] = sp[(size_t)mb * 3 + idx];
        smask_t[t] = smask[mb + t];
        __syncthreads();
        float lgr[16];
        float tmax = -1e30f;
        #pragma unroll
        for (int kk = 0; kk < 16; ++kk) {
            int ml = tm + (kk << 4);
            float dot = 0.f;
            #pragma unroll
            for (int c = 0; c < 16; ++c) dot = fmaf(qreg[c], sk_t[ml][c], dot);
            float dx = trx - sp_t[ml*3+0], dy = tryy - sp_t[ml*3+1], dz = trz - sp_t[ml*3+2];
            float lg = fmaf(0.25f, dot, -0.5f * sbw * (dx*dx + dy*dy + dz*dz));
            lg += INFV * (mask_n * smask_t[ml] - 1.0f);
            lgr[kk] = lg;
            tmax = fmaxf(tmax, lg);
        }
        float mn = fmaxf(mx, tmax);
        float scale = __expf(mx - mn);
        l *= scale;
        #pragma unroll
        for (int c = 0; c < 16; ++c) acc[c] *= scale;
        #pragma unroll
        for (int kk = 0; kk < 16; ++kk) {
            int ml = tm + (kk << 4);
            float w = __expf(lgr[kk] - mn);
            l += w;
            #pragma unroll
            for (int c = 0; c < 16; ++c) acc[c] = fmaf(w, sv_t[ml][c], acc[c]);
        }
        mx = mn;
    }
    #pragma unroll
    for (int off = 1; off < 16; off <<= 1) {
        float m2 = __shfl_xor(mx, off), l2 = __shfl_xor(l, off);
        float mn = fmaxf(mx, m2);
        float e1 = __expf(mx - mn), e2 = __expf(m2 - mn);
        l = l * e1 + l2 * e2;
        #pragma unroll
        for (int c = 0; c < 16; ++c) {
            float a2 = __shfl_xor(acc[c], off);
            acc[c] = acc[c] * e1 + a2 * e2;
        }
        mx = mn;
    }
    const float invl = 1.0f / l;
    float outv = 0.f;
    #pragma unroll
    for (int c = 0; c < 16; ++c) if (tm == c) outv = acc[c];
    ocat[(size_t)n * 1152 + 960 + h * 16 + tm] = outv * invl;
}

// ---------------------------------------------------------------- tlog
__global__ __launch_bounds__(256) void k_tlog(
    const float* __restrict__ sqw, const float* __restrict__ skv,
    const float* __restrict__ trans, const float* __restrict__ mask,
    const float* __restrict__ sp, const float* __restrict__ smask,
    const float* __restrict__ sbwp, float* __restrict__ logits,
    float* __restrict__ stat_m, float* __restrict__ stat_il)
{
    __shared__ float sk_s[32][16];
    __shared__ float sq_s[32][16];
    __shared__ float trans_s[96];
    __shared__ float mask_s[32];
    __shared__ float spm_s[96];
    __shared__ float smask_s[32];
    const int h = blockIdx.y;
    const int m0 = blockIdx.x * 32;
    const int t = threadIdx.x;
    const int tmg = t >> 5, tnl = t & 31;
    const float sbw = softplusf(sbwp[0]);
    for (int idx = t; idx < 512; idx += 256) {
        int row = idx >> 4, c = idx & 15;
        sk_s[row][c] = skv[(size_t)(m0 + row) * 384 + h * 16 + c];
    }
    if (t < 96) spm_s[t] = sp[(size_t)m0 * 3 + t];
    if (t < 32) smask_s[t] = smask[m0 + t];
    __syncthreads();
    float skr[4][16];
    float spx[4], spy[4], spz[4], smk[4];
    #pragma unroll
    for (int mi = 0; mi < 4; ++mi) {
        int row = tmg * 4 + mi;
        #pragma unroll
        for (int c4 = 0; c4 < 16; c4 += 4)
            *(float4*)&skr[mi][c4] = *(float4*)&sk_s[row][c4];
        spx[mi] = spm_s[row*3+0]; spy[mi] = spm_s[row*3+1]; spz[mi] = spm_s[row*3+2];
        smk[mi] = smask_s[row];
    }
    float mxr[4], lr[4];
    #pragma unroll
    for (int mi = 0; mi < 4; ++mi) { mxr[mi] = -1e30f; lr[mi] = 0.f; }
    for (int nt = 0; nt < 16; ++nt) {
        __syncthreads();
        const int nb = nt * 32;
        if (t < 128) {
            int nn = t >> 2, c4 = (t & 3) << 2;
            *(float4*)&sq_s[nn][c4] = *(const float4*)&sqw[(size_t)(nb + nn) * 192 + h * 16 + c4];
        }
        if (t < 96) trans_s[t] = trans[(size_t)nb * 3 + t];
        if (t < 32) mask_s[t] = mask[nb + t];
        __syncthreads();
        float q[16];
        #pragma unroll
        for (int c4 = 0; c4 < 16; c4 += 4)
            *(float4*)&q[c4] = *(float4*)&sq_s[tnl][c4];
        const float tx = trans_s[tnl*3+0], ty = trans_s[tnl*3+1], tz = trans_s[tnl*3+2];
        const float mkn = mask_s[tnl];
        #pragma unroll
        for (int mi = 0; mi < 4; ++mi) {
            float dot = 0.f;
            #pragma unroll
            for (int c = 0; c < 16; ++c) dot = fmaf(skr[mi][c], q[c], dot);
            float dx = tx - spx[mi], dy = ty - spy[mi], dz = tz - spz[mi];
            float mterm = INFV * (mkn * smk[mi] - 1.0f) - 0.5f * sbw * (dx*dx + dy*dy + dz*dz);
            float lg = fmaf(0.25f, dot, mterm);
            logits[((size_t)(m0 + tmg * 4 + mi) * 12 + h) * 512 + nb + tnl] = lg;
            float newm = fmaxf(mxr[mi], lg);
            lr[mi] = lr[mi] * __expf(mxr[mi] - newm) + __expf(lg - newm);
            mxr[mi] = newm;
        }
    }
    #pragma unroll
    for (int off = 1; off < 32; off <<= 1) {
        #pragma unroll
        for (int mi = 0; mi < 4; ++mi) {
            float m2 = __shfl_xor(mxr[mi], off), l2 = __shfl_xor(lr[mi], off);
            float newm = fmaxf(mxr[mi], m2);
            lr[mi] = lr[mi] * __expf(mxr[mi] - newm) + l2 * __expf(m2 - newm);
            mxr[mi] = newm;
        }
    }
    if (tnl == 0) {
        #pragma unroll
        for (int mi = 0; mi < 4; ++mi) {
            int m = m0 + tmg * 4 + mi;
            stat_m[(size_t)m * 12 + h] = mxr[mi];
            stat_il[(size_t)m * 12 + h] = 1.0f / lr[mi];
        }
    }
}

// ---------------------------------------------------------------- tw
__global__ __launch_bounds__(256) void k_tw(
    const float* __restrict__ logits, const float* __restrict__ stat_m,
    const float* __restrict__ stat_il, float* __restrict__ w)
{
    __shared__ float mxs[12], ils[12];
    const int m = blockIdx.x, t = threadIdx.x;
    if (t < 12) { mxs[t] = stat_m[(size_t)m * 12 + t]; ils[t] = stat_il[(size_t)m * 12 + t]; }
    __syncthreads();
    const float* lp = logits + (size_t)m * 12 * 512;
    float a0 = 0.f, a1 = 0.f;
    #pragma unroll
    for (int h = 0; h < 12; ++h) {
        a0 += __expf(lp[h * 512 + t] - mxs[h]) * ils[h];
        a1 += __expf(lp[h * 512 + 256 + t] - mxs[h]) * ils[h];
    }
    w[(size_t)m * 512 + t] = a0 * (1.0f / 12.0f);
    w[(size_t)m * 512 + 256 + t] = a1 * (1.0f / 12.0f);
}

// ---------------------------------------------------------------- surf out
__global__ __launch_bounds__(256) void k_surf_out(
    const float* __restrict__ sfeat, const float* __restrict__ saggw,
    const float* __restrict__ Wso, const float* __restrict__ bso,
    float* __restrict__ out)
{
    __shared__ float wl[12304];
    const int t = threadIdx.x;
    for (int idx = t; idx < 12288; idx += 256) {
        int k = idx >> 4, c = idx & 15;
        wl[(k / 192) * 3076 + (k % 192) * 16 + c] = Wso[idx];
    }
    const int m = blockIdx.x * 64 + (t >> 2);
    const int kq = t & 3;
    const float* src = (kq < 2) ? &sfeat[(size_t)m * 384 + kq * 192]
                                : &saggw[(size_t)m * 384 + (kq - 2) * 192];
    __syncthreads();
    float acc[16];
    #pragma unroll
    for (int c = 0; c < 16; ++c) acc[c] = 0.f;
    const float* wb = &wl[kq * 3076];
    for (int k = 0; k < 192; k += 4) {
        float4 v = *(const float4*)&src[k];
        #pragma unroll
        for (int e = 0; e < 4; ++e) {
            float sv = (&v.x)[e];
            #pragma unroll
            for (int c = 0; c < 16; ++c)
                acc[c] = fmaf(sv, wb[(k + e) * 16 + c], acc[c]);
        }
    }
    #pragma unroll
    for (int c = 0; c < 16; ++c) {
        acc[c] += __shfl_xor(acc[c], 1);
        acc[c] += __shfl_xor(acc[c], 2);
    }
    #pragma unroll
    for (int c = 0; c < 16; ++c) {
        if ((c >> 2) == kq) out[196608 + (size_t)m * 16 + c] = acc[c] + bso[c];
    }
}

// ----------------------------------------------------------------
extern "C" void kernel_launch(void* const* d_in, const int* in_sizes, int n_in,
                              void* d_out, int out_size, void* d_ws, size_t ws_size,
                              hipStream_t stream)
{
    (void)in_sizes; (void)n_in; (void)out_size; (void)ws_size;
    const float* s     = (const float*)d_in[0];
    const float* z     = (const float*)d_in[1];
    const float* rots  = (const float*)d_in[2];
    const float* trans = (const float*)d_in[3];
    const float* mask  = (const float*)d_in[4];
    const float* sp    = (const float*)d_in[5];
    const float* sf    = (const float*)d_in[6];
    const float* smask = (const float*)d_in[7];
    const float* Wq    = (const float*)d_in[8];  const float* bq   = (const float*)d_in[9];
    const float* Wkv   = (const float*)d_in[10]; const float* bkv  = (const float*)d_in[11];
    const float* Wqp   = (const float*)d_in[12]; const float* bqp  = (const float*)d_in[13];
    const float* Wkvp  = (const float*)d_in[14]; const float* bkvp = (const float*)d_in[15];
    const float* Wse   = (const float*)d_in[16]; const float* bse  = (const float*)d_in[17];
    const float* Wsq   = (const float*)d_in[18]; const float* bsq  = (const float*)d_in[19];
    const float* Wsk   = (const float*)d_in[20]; const float* bsk  = (const float*)d_in[21];
    const float* Wsv   = (const float*)d_in[22]; const float* bsv  = (const float*)d_in[23];
    const float* Wb    = (const float*)d_in[24]; const float* bb   = (const float*)d_in[25];
    const float* Wdz   = (const float*)d_in[26]; const float* bdz  = (const float*)d_in[27];
    const float* hw    = (const float*)d_in[28]; const float* sbw  = (const float*)d_in[29];
    const float* Wout  = (const float*)d_in[30]; const float* bout = (const float*)d_in[31];
    const float* Wso   = (const float*)d_in[32]; const float* bso  = (const float*)d_in[33];
    float* out = (float*)d_out;

    float* qw    = (float*)d_ws;
    float* kw    = qw    + (size_t)512 * 192;
    float* vw    = kw    + (size_t)512 * 192;
    float* sqw   = vw    + (size_t)512 * 192;
    float* qpw   = sqw   + (size_t)512 * 192;
    float* kpw   = qpw   + (size_t)512 * 144;
    float* vpw   = kpw   + (size_t)512 * 144;
    float* sfeat = vpw   + (size_t)512 * 288;
    float* skv   = sfeat + (size_t)2048 * 384;
    float* ocat  = skv   + (size_t)2048 * 384;
    float* sagg  = ocat  + (size_t)512 * 1152;
    // region: proj (688K fl) -> bpz (11.5M fl) -> logits (12.6M fl), stream-serialized
    float* region = sagg + (size_t)2048 * 384;
    float* proj   = region;
    float* bpz    = region;
    float* logits = region;
    float* wt1   = region + (size_t)2048 * 12 * 512;
    float* wt2   = wt1   + (size_t)1344 * 384;
    float* wt3   = wt2   + (size_t)384 * 384;
    float* b1    = wt3   + (size_t)384 * 1152;
    float* b2    = b1    + 1344;
    float* st    = b2    + 384;
    float* wbuf  = st    + (size_t)384 * 512;
    float* statm = wbuf  + (size_t)2048 * 512;
    float* stati = statm + (size_t)2048 * 12;
    float* abuf  = stati + (size_t)2048 * 12;      // a[12][512][512]
    float* cbuf  = abuf  + (size_t)12 * 512 * 512; // c[12][512][40]
    float* wz    = cbuf  + (size_t)12 * 512 * 40;  // Wz[44][128]
    float* bz    = wz    + (size_t)44 * 128;       // bz[44]

    k_pack<<<dim3(1099), dim3(256), 0, stream>>>(Wq, Wsq, Wkv, Wqp, Wkvp, Wsk, Wsv, Wout,
        bq, bsq, bkv, bqp, bkvp, bsk, bsv, wt1, wt2, wt3, b1, b2);
    k_packz<<<dim3(23), dim3(256), 0, stream>>>(Wb, bb, Wdz, bdz, wz, bz);
    k_transp<<<dim3(12, 16), dim3(256), 0, stream>>>(s, st);
    k_gemm<384, true><<<dim3(21, 8), dim3(256), 0, stream>>>(s, wt1, b1, proj, 1344);
    k_scatter<<<dim3(128), dim3(256), 0, stream>>>(proj, rots, trans,
        qw, kw, vw, sqw, qpw, kpw, vpw);
    k_sfeat<<<dim3(256), dim3(256), 0, stream>>>(sf, Wse, bse, sfeat);
    k_gemm<384, true><<<dim3(6, 32), dim3(256), 0, stream>>>(sfeat, wt2, b2, skv, 384);
    k_zpass<<<dim3(512, 2), dim3(256), 0, stream>>>(z, wz, bz, bpz);
    k_attn_a<<<dim3(512, 3), dim3(256), 0, stream>>>(qw, kw, qpw, kpw, bpz, mask, hw, abuf);
    k_attn_pair<<<dim3(512), dim3(256), 0, stream>>>(abuf, bpz, ocat);
    k_gemm_ov<<<dim3(8, 12), dim3(256), 0, stream>>>(abuf, vw, vpw, cbuf);
    k_optfin<<<dim3(128), dim3(256), 0, stream>>>(cbuf, rots, trans, ocat);
    k_surf<<<dim3(384), dim3(256), 0, stream>>>(sqw, skv, trans, mask, sp, smask,
        sbw, ocat);
    k_tlog<<<dim3(64, 12), dim3(256), 0, stream>>>(sqw, skv, trans, mask, sp, smask,
        sbw, logits, statm, stati);
    k_tw<<<dim3(2048), dim3(256), 0, stream>>>(logits, statm, stati, wbuf);
    k_gemm<512, false><<<dim3(6, 32), dim3(256), 0, stream>>>(wbuf, st, nullptr, sagg, 384);
    k_surf_out<<<dim3(32), dim3(256), 0, stream>>>(sfeat, sagg, Wso, bso, out);
    k_gemm<1152, true><<<dim3(6, 8), dim3(256), 0, stream>>>(ocat, wt3, bout, out, 384);
}

// Round 9
// 524.135 us; speedup vs baseline: 1.0915x; 1.0587x over previous
//
#include <hip/hip_runtime.h>
#include <cstddef>

// IPA + surface cross-attention, B=1, N=512, M=2048, H=12, C_H=16, C_S=384.
// Round 8: kill k_surf (100us, latency-bound, duplicate logit compute) —
// o_surf now computed from the logits tensor k_tlog already materializes:
// k_rstat/k_rcomb (row stats) + k_pv (PV from lbuf+sv) + k_pvcomb.

#define CS 384
#define INFV 100000.0f

__device__ __forceinline__ float softplusf(float x) { return log1pf(__expf(x)); }

// ---------------------------------------------------------------- pack
__global__ __launch_bounds__(256) void k_pack(
    const float* __restrict__ Wq, const float* __restrict__ Wsq,
    const float* __restrict__ Wkv, const float* __restrict__ Wqp,
    const float* __restrict__ Wkvp, const float* __restrict__ Wsk,
    const float* __restrict__ Wsv, const float* __restrict__ Wout,
    const float* __restrict__ bq, const float* __restrict__ bsq,
    const float* __restrict__ bkv, const float* __restrict__ bqp,
    const float* __restrict__ bkvp, const float* __restrict__ bsk,
    const float* __restrict__ bsv,
    float* __restrict__ wt1, float* __restrict__ wt2, float* __restrict__ wt3,
    float* __restrict__ b1, float* __restrict__ b2)
{
    const int b = blockIdx.x, t = threadIdx.x;
    if (b >= 1092) {
        int idx = (b - 1092) * 256 + t;
        if (idx < 1344) {
            float v;
            if (idx < 192) v = bq[idx];
            else if (idx < 384) v = bsq[idx - 192];
            else if (idx < 768) v = bkv[idx - 384];
            else if (idx < 912) v = bqp[idx - 768];
            else v = bkvp[idx - 912];
            b1[idx] = v;
        } else if (idx < 1728) {
            int i2 = idx - 1344;
            b2[i2] = (i2 < 192) ? bsk[i2] : bsv[i2 - 192];
        }
        return;
    }
    const float* src; float* dst; int C, coff, tile, ldd;
    if (b < 72)       { src = Wq;   C = 192; dst = wt1; coff = 0;   ldd = 384;  tile = b; }
    else if (b < 144) { src = Wsq;  C = 192; dst = wt1; coff = 192; ldd = 384;  tile = b - 72; }
    else if (b < 288) { src = Wkv;  C = 384; dst = wt1; coff = 384; ldd = 384;  tile = b - 144; }
    else if (b < 348) { src = Wqp;  C = 144; dst = wt1; coff = 768; ldd = 384;  tile = b - 288; }
    else if (b < 516) { src = Wkvp; C = 432; dst = wt1; coff = 912; ldd = 384;  tile = b - 348; }
    else if (b < 588) { src = Wsk;  C = 192; dst = wt2; coff = 0;   ldd = 384;  tile = b - 516; }
    else if (b < 660) { src = Wsv;  C = 192; dst = wt2; coff = 192; ldd = 384;  tile = b - 588; }
    else              { src = Wout; C = 384; dst = wt3; coff = 0;   ldd = 1152; tile = b - 660; }
    const int cT = (C + 31) >> 5;
    const int tk = tile / cT, tc = tile % cT;
    __shared__ float l[32][33];
    const int tr = t >> 5, tcc = t & 31;
    #pragma unroll
    for (int rr = 0; rr < 4; ++rr) {
        int kloc = tr * 4 + rr;
        int cg = tc * 32 + tcc;
        l[kloc][tcc] = (cg < C) ? src[(size_t)(tk * 32 + kloc) * C + cg] : 0.f;
    }
    __syncthreads();
    #pragma unroll
    for (int rr = 0; rr < 4; ++rr) {
        int cloc = tr * 4 + rr;
        int cg = tc * 32 + cloc;
        if (cg < C) dst[(size_t)(coff + cg) * ldd + tk * 32 + tcc] = l[tcc][cloc];
    }
}

// ---------------------------------------------------------------- packz
__global__ __launch_bounds__(256) void k_packz(
    const float* __restrict__ Wb, const float* __restrict__ bb,
    const float* __restrict__ Wdz, const float* __restrict__ bdz,
    float* __restrict__ wz, float* __restrict__ bz)
{
    const float s3 = 0.5773502691896258f;
    int idx = blockIdx.x * 256 + threadIdx.x;
    if (idx < 5632) {
        int c = idx >> 7, kk = idx & 127;
        wz[idx] = (c < 12) ? s3 * Wb[kk * 12 + c] : Wdz[kk * 32 + (c - 12)];
    } else if (idx < 5676) {
        int c = idx - 5632;
        bz[c] = (c < 12) ? s3 * bb[c] : bdz[c - 12];
    }
}

// ---------------------------------------------------------------- transpose
__global__ __launch_bounds__(256) void k_transp(
    const float* __restrict__ A, float* __restrict__ At)
{
    __shared__ float tile[32][33];
    const int r0 = blockIdx.y * 32, c0 = blockIdx.x * 32;
    const int tr = threadIdx.x >> 5, tc = threadIdx.x & 31;
    #pragma unroll
    for (int rr = 0; rr < 4; ++rr)
        tile[tr + rr * 8][tc] = A[(size_t)(r0 + tr + rr * 8) * 384 + c0 + tc];
    __syncthreads();
    #pragma unroll
    for (int rr = 0; rr < 4; ++rr)
        At[(size_t)(c0 + tr + rr * 8) * 512 + r0 + tc] = tile[tc][tr + rr * 8];
}

// ---------------------------------------------------------------- gemm
template<int KTOT, bool HB>
__global__ __launch_bounds__(256) void k_gemm(
    const float* __restrict__ A, const float* __restrict__ Wt,
    const float* __restrict__ bias, float* __restrict__ C, int ldc)
{
    __shared__ float As[64][68];
    __shared__ float Ws[64][68];
    const int t = threadIdx.x;
    const int c0 = blockIdx.x * 64, m0 = blockIdx.y * 64;
    const int sr = t >> 4, sk4 = (t & 15) << 2;
    const int wid = t >> 6, lane = t & 63;
    const int wr = (wid >> 1) * 32, wc = (wid & 1) * 32;
    const int lr = lane >> 3, lc = lane & 7;
    float acc[4][4];
    #pragma unroll
    for (int j = 0; j < 4; ++j) {
        float bv = HB ? bias[c0 + wc + lc + 8 * j] : 0.f;
        #pragma unroll
        for (int i = 0; i < 4; ++i) acc[i][j] = bv;
    }
    for (int kc = 0; kc < KTOT; kc += 64) {
        __syncthreads();
        #pragma unroll
        for (int rep = 0; rep < 4; ++rep) {
            int row = sr + rep * 16;
            *(float4*)&As[row][sk4] = *(const float4*)&A[(size_t)(m0 + row) * KTOT + kc + sk4];
            *(float4*)&Ws[row][sk4] = *(const float4*)&Wt[(size_t)(c0 + row) * KTOT + kc + sk4];
        }
        __syncthreads();
        #pragma unroll 4
        for (int k4 = 0; k4 < 16; ++k4) {
            float4 a[4], w[4];
            #pragma unroll
            for (int i = 0; i < 4; ++i) a[i] = *(float4*)&As[wr + lr + 8 * i][k4 * 4];
            #pragma unroll
            for (int j = 0; j < 4; ++j) w[j] = *(float4*)&Ws[wc + lc + 8 * j][k4 * 4];
            #pragma unroll
            for (int i = 0; i < 4; ++i) {
                #pragma unroll
                for (int j = 0; j < 4; ++j) {
                    acc[i][j] = fmaf(a[i].x, w[j].x, acc[i][j]);
                    acc[i][j] = fmaf(a[i].y, w[j].y, acc[i][j]);
                    acc[i][j] = fmaf(a[i].z, w[j].z, acc[i][j]);
                    acc[i][j] = fmaf(a[i].w, w[j].w, acc[i][j]);
                }
            }
        }
    }
    #pragma unroll
    for (int i = 0; i < 4; ++i) {
        #pragma unroll
        for (int j = 0; j < 4; ++j)
            C[(size_t)(m0 + wr + lr + 8 * i) * ldc + c0 + wc + lc + 8 * j] = acc[i][j];
    }
}

// ---------------------------------------------------------------- scatter
__global__ __launch_bounds__(256) void k_scatter(
    const float* __restrict__ proj, const float* __restrict__ rots,
    const float* __restrict__ trans,
    float* __restrict__ qw, float* __restrict__ kw, float* __restrict__ vw,
    float* __restrict__ sqw, float* __restrict__ qpw, float* __restrict__ kpw,
    float* __restrict__ vpw)
{
    __shared__ float p[4][1344];
    const int n0 = blockIdx.x * 4, t = threadIdx.x;
    for (int idx = t; idx < 1344; idx += 256) {
        #pragma unroll
        for (int r = 0; r < 4; ++r) p[r][idx] = proj[(size_t)(n0 + r) * 1344 + idx];
    }
    __syncthreads();
    for (int idx = t; idx < 3072; idx += 256) {
        int r = idx / 768, c = idx % 768;
        int n = n0 + r;
        float v = p[r][c];
        if (c < 192) qw[(size_t)n * 192 + c] = v;
        else if (c < 384) sqw[(size_t)n * 192 + (c - 192)] = v;
        else {
            int cc = c - 384, h = cc >> 5, sub = cc & 31;
            if (sub < 16) kw[(size_t)n * 192 + h * 16 + sub] = v;
            else          vw[(size_t)n * 192 + h * 16 + (sub - 16)] = v;
        }
    }
    for (int idx = t; idx < 2304; idx += 256) {
        int r = idx / 576, rem = idx % 576;
        int n = n0 + r;
        const float* R = &rots[(size_t)n * 9];
        const float* tr = &trans[(size_t)n * 3];
        if (rem < 144) {
            int pp = rem / 3, d = rem % 3;
            float v = fmaf(R[d*3+0], p[r][768 + pp],
                      fmaf(R[d*3+1], p[r][768 + 48 + pp],
                      fmaf(R[d*3+2], p[r][768 + 96 + pp], tr[d])));
            qpw[(size_t)n * 144 + pp * 3 + d] = v;
        } else {
            int rem2 = rem - 144; int pp = rem2 / 3, d = rem2 % 3;
            float v = fmaf(R[d*3+0], p[r][912 + pp],
                      fmaf(R[d*3+1], p[r][912 + 144 + pp],
                      fmaf(R[d*3+2], p[r][912 + 288 + pp], tr[d])));
            int h = pp / 12, ii = pp % 12;
            if (ii < 4) kpw[(size_t)n * 144 + h * 12 + ii * 3 + d] = v;
            else        vpw[(size_t)n * 288 + h * 24 + (ii - 4) * 3 + d] = v;
        }
    }
}

// ---------------------------------------------------------------- sfeat
__global__ __launch_bounds__(256) void k_sfeat(
    const float* __restrict__ sf, const float* __restrict__ Wse,
    const float* __restrict__ bse, float* __restrict__ sfeat)
{
    __shared__ float wl[16 * 384];
    __shared__ float sfl[8][16];
    const int m0 = blockIdx.x * 8, t = threadIdx.x;
    for (int idx = t; idx < 6144; idx += 256) wl[idx] = Wse[idx];
    if (t < 128) sfl[t >> 4][t & 15] = sf[(size_t)(m0 + (t >> 4)) * 16 + (t & 15)];
    __syncthreads();
    #pragma unroll
    for (int u = 0; u < 12; ++u) {
        int idx = t + u * 256;
        int r = idx / 384, c = idx % 384;
        float a = bse[c];
        #pragma unroll
        for (int kk = 0; kk < 16; ++kk) a = fmaf(sfl[r][kk], wl[kk * 384 + c], a);
        sfeat[(size_t)(m0 + r) * 384 + c] = a;
    }
}

// ---------------------------------------------------------------- zpass
__global__ __launch_bounds__(256) void k_zpass(
    const float* __restrict__ z, const float* __restrict__ wz,
    const float* __restrict__ bz, float* __restrict__ bpz)
{
    __shared__ float zt[64][132];
    const int i = blockIdx.x, t = threadIdx.x;
    const int jbase = blockIdx.y * 256;
    const int jl = t & 63;
    const int cgs = __builtin_amdgcn_readfirstlane(t >> 6);
    const float* __restrict__ wp = wz + cgs * 11 * 128;
    float bv[11];
    #pragma unroll
    for (int u = 0; u < 11; ++u) bv[u] = bz[cgs * 11 + u];
    for (int ch = 0; ch < 4; ++ch) {
        const int j0 = jbase + ch * 64;
        __syncthreads();
        for (int idx = t; idx < 2048; idx += 256) {
            int r = idx >> 5, c4 = (idx & 31) << 2;
            *(float4*)&zt[r][c4] = *(const float4*)&z[((size_t)i * 512 + j0 + r) * 128 + c4];
        }
        __syncthreads();
        float acc[11];
        #pragma unroll
        for (int u = 0; u < 11; ++u) acc[u] = bv[u];
        #pragma unroll 2
        for (int k4 = 0; k4 < 128; k4 += 4) {
            float4 zv = *(float4*)&zt[jl][k4];
            #pragma unroll
            for (int u = 0; u < 11; ++u) {
                const float* w = wp + u * 128 + k4;
                acc[u] = fmaf(zv.x, w[0],
                         fmaf(zv.y, w[1],
                         fmaf(zv.z, w[2],
                         fmaf(zv.w, w[3], acc[u]))));
            }
        }
        #pragma unroll
        for (int u = 0; u < 11; ++u)
            bpz[((size_t)i * 44 + cgs * 11 + u) * 512 + j0 + jl] = acc[u];
    }
}

// ---------------------------------------------------------------- attn_a
__global__ __launch_bounds__(256) void k_attn_a(
    const float* __restrict__ qw, const float* __restrict__ kw,
    const float* __restrict__ qpw, const float* __restrict__ kpw,
    const float* __restrict__ bpz, const float* __restrict__ mask,
    const float* __restrict__ hwp, float* __restrict__ abuf)
{
    __shared__ float pls[4][520];
    __shared__ float qs[64], qps[48], cpt4[4];
    const int i = blockIdx.x, hg = blockIdx.y;
    const int t = threadIdx.x;
    if (t < 64) qs[t] = qw[(size_t)i * 192 + hg * 64 + t];
    if (t < 48) qps[t] = qpw[(size_t)i * 144 + hg * 48 + t];
    if (t < 4) cpt4[t] = -0.5f * 0.13608276348795434f * softplusf(hwp[hg * 4 + t]);
    const float mask_i = mask[i];
    __syncthreads();
    #pragma unroll 2
    for (int it = 0; it < 8; ++it) {
        int idx = t + it * 256;
        int hh = idx >> 9, j = idx & 511;
        int h = hg * 4 + hh;
        float kj[16], kpj[12];
        { const float4* kr = (const float4*)&kw[(size_t)j * 192 + h * 16];
          *(float4*)&kj[0] = kr[0]; *(float4*)&kj[4] = kr[1];
          *(float4*)&kj[8] = kr[2]; *(float4*)&kj[12] = kr[3]; }
        { const float4* kr = (const float4*)&kpw[(size_t)j * 144 + h * 12];
          *(float4*)&kpj[0] = kr[0]; *(float4*)&kpj[4] = kr[1]; *(float4*)&kpj[8] = kr[2]; }
        float qk = 0.f;
        #pragma unroll
        for (int c = 0; c < 16; ++c) qk = fmaf(qs[hh * 16 + c], kj[c], qk);
        float pts = 0.f;
        #pragma unroll
        for (int p = 0; p < 4; ++p) {
            float dx = qps[hh*12+p*3+0] - kpj[p*3+0];
            float dy = qps[hh*12+p*3+1] - kpj[p*3+1];
            float dz = qps[hh*12+p*3+2] - kpj[p*3+2];
            pts += dx*dx + dy*dy + dz*dz;
        }
        float lg = fmaf(0.14433756729740643f, qk, bpz[((size_t)i * 44 + h) * 512 + j]);
        lg = fmaf(cpt4[hh], pts, lg);
        lg += INFV * (mask_i * mask[j] - 1.0f);
        pls[hh][j] = lg;
    }
    __syncthreads();
    const int w = t >> 6, lane = t & 63;
    float v[8];
    #pragma unroll
    for (int k = 0; k < 8; ++k) v[k] = pls[w][lane + k * 64];
    float mx = v[0];
    #pragma unroll
    for (int k = 1; k < 8; ++k) mx = fmaxf(mx, v[k]);
    #pragma unroll
    for (int off = 32; off; off >>= 1) mx = fmaxf(mx, __shfl_xor(mx, off));
    float sm = 0.f;
    #pragma unroll
    for (int k = 0; k < 8; ++k) { v[k] = __expf(v[k] - mx); sm += v[k]; }
    #pragma unroll
    for (int off = 32; off; off >>= 1) sm += __shfl_xor(sm, off);
    const float inv = 1.0f / sm;
    float* dst = abuf + ((size_t)(hg * 4 + w) * 512 + i) * 512;
    #pragma unroll
    for (int k = 0; k < 8; ++k) dst[lane + k * 64] = v[k] * inv;
}

// ---------------------------------------------------------------- attn_pair
__global__ __launch_bounds__(256) void k_attn_pair(
    const float* __restrict__ abuf, const float* __restrict__ bpz,
    float* __restrict__ ocat)
{
    __shared__ float al[12][512];
    const int i = blockIdx.x, t = threadIdx.x;
    #pragma unroll
    for (int u = 0; u < 12; ++u) {
        al[u][t] = abuf[(size_t)u * 262144 + (size_t)i * 512 + t];
        al[u][t + 256] = abuf[(size_t)u * 262144 + (size_t)i * 512 + t + 256];
    }
    __syncthreads();
    const int c = t & 31;
    const int h1 = t >> 5;
    const bool dual = (t < 128);
    const float* pz = bpz + ((size_t)i * 44 + 12 + c) * 512;
    const float* a1 = al[h1];
    const float* a2 = al[dual ? h1 + 8 : 0];
    float acc1 = 0.f, acc2 = 0.f;
    for (int j = 0; j < 512; j += 4) {
        float4 p = *(const float4*)&pz[j];
        acc1 = fmaf(a1[j+0], p.x, acc1);
        acc1 = fmaf(a1[j+1], p.y, acc1);
        acc1 = fmaf(a1[j+2], p.z, acc1);
        acc1 = fmaf(a1[j+3], p.w, acc1);
        if (dual) {
            acc2 = fmaf(a2[j+0], p.x, acc2);
            acc2 = fmaf(a2[j+1], p.y, acc2);
            acc2 = fmaf(a2[j+2], p.z, acc2);
            acc2 = fmaf(a2[j+3], p.w, acc2);
        }
    }
    ocat[(size_t)i * 1152 + 576 + h1 * 32 + c] = acc1;
    if (dual) ocat[(size_t)i * 1152 + 576 + (h1 + 8) * 32 + c] = acc2;
}

// ---------------------------------------------------------------- gemm_ov
__global__ __launch_bounds__(256) void k_gemm_ov(
    const float* __restrict__ abuf, const float* __restrict__ vw,
    const float* __restrict__ vpw, float* __restrict__ cbuf)
{
    __shared__ float As[64][68];
    __shared__ float Bs[64][44];
    const int i0 = blockIdx.x * 64, h = blockIdx.y;
    const int t = threadIdx.x;
    const int sr = t >> 4, sk4 = (t & 15) << 2;
    const int r1 = t >> 3;
    const int cb = t & 7;
    float acc[2][5];
    #pragma unroll
    for (int u = 0; u < 5; ++u) { acc[0][u] = 0.f; acc[1][u] = 0.f; }
    for (int kc = 0; kc < 512; kc += 64) {
        __syncthreads();
        #pragma unroll
        for (int rep = 0; rep < 4; ++rep) {
            int row = sr + rep * 16;
            *(float4*)&As[row][sk4] =
                *(const float4*)&abuf[(size_t)h * 262144 + (size_t)(i0 + row) * 512 + kc + sk4];
        }
        #pragma unroll
        for (int u = 0; u < 10; ++u) {
            int idx = t + u * 256;
            int r = idx / 40, cc = idx % 40;
            Bs[r][cc] = (cc < 16) ? vw[(size_t)(kc + r) * 192 + h * 16 + cc]
                                  : vpw[(size_t)(kc + r) * 288 + h * 24 + (cc - 16)];
        }
        __syncthreads();
        #pragma unroll 4
        for (int kk = 0; kk < 64; ++kk) {
            float av1 = As[r1][kk], av2 = As[r1 + 32][kk];
            #pragma unroll
            for (int u = 0; u < 5; ++u) {
                float b = Bs[kk][cb + 8 * u];
                acc[0][u] = fmaf(av1, b, acc[0][u]);
                acc[1][u] = fmaf(av2, b, acc[1][u]);
            }
        }
    }
    #pragma unroll
    for (int u = 0; u < 5; ++u) {
        cbuf[((size_t)h * 512 + i0 + r1) * 40 + cb + 8 * u] = acc[0][u];
        cbuf[((size_t)h * 512 + i0 + r1 + 32) * 40 + cb + 8 * u] = acc[1][u];
    }
}

// ---------------------------------------------------------------- optfin
__global__ __launch_bounds__(256) void k_optfin(
    const float* __restrict__ cbuf, const float* __restrict__ rots,
    const float* __restrict__ trans, float* __restrict__ ocat)
{
    __shared__ float cl[4][12][40];
    const int i0 = blockIdx.x * 4, t = threadIdx.x;
    for (int idx = t; idx < 1920; idx += 256) {
        int ii = idx / 480, rem = idx % 480;
        int h = rem / 40, c = rem % 40;
        cl[ii][h][c] = cbuf[((size_t)h * 512 + i0 + ii) * 40 + c];
    }
    __syncthreads();
    for (int idx = t; idx < 768; idx += 256) {
        int ii = idx / 192, o = idx % 192;
        ocat[(size_t)(i0 + ii) * 1152 + o] = cl[ii][o >> 4][o & 15];
    }
    for (int idx = t; idx < 384; idx += 256) {
        int ii = idx / 96, hp = idx % 96;
        int h = hp >> 3, p = hp & 7;
        int i = i0 + ii;
        const float* R = &rots[(size_t)i * 9];
        float gx = cl[ii][h][16 + p*3 + 0] - trans[(size_t)i*3 + 0];
        float gy = cl[ii][h][16 + p*3 + 1] - trans[(size_t)i*3 + 1];
        float gz = cl[ii][h][16 + p*3 + 2] - trans[(size_t)i*3 + 2];
        float lx = R[0]*gx + R[3]*gy + R[6]*gz;
        float ly = R[1]*gx + R[4]*gy + R[7]*gz;
        float lz = R[2]*gx + R[5]*gy + R[8]*gz;
        float nm = sqrtf(lx*lx + ly*ly + lz*lz + 1e-8f);
        int col = h * 8 + p;
        size_t base = (size_t)i * 1152;
        ocat[base + 192 + col] = lx;
        ocat[base + 288 + col] = ly;
        ocat[base + 384 + col] = lz;
        ocat[base + 480 + col] = nm;
    }
}

// ---------------------------------------------------------------- tlog
__global__ __launch_bounds__(256) void k_tlog(
    const float* __restrict__ sqw, const float* __restrict__ skv,
    const float* __restrict__ trans, const float* __restrict__ mask,
    const float* __restrict__ sp, const float* __restrict__ smask,
    const float* __restrict__ sbwp, float* __restrict__ logits,
    float* __restrict__ stat_m, float* __restrict__ stat_il)
{
    __shared__ float sk_s[32][16];
    __shared__ float sq_s[32][16];
    __shared__ float trans_s[96];
    __shared__ float mask_s[32];
    __shared__ float spm_s[96];
    __shared__ float smask_s[32];
    const int h = blockIdx.y;
    const int m0 = blockIdx.x * 32;
    const int t = threadIdx.x;
    const int tmg = t >> 5, tnl = t & 31;
    const float sbw = softplusf(sbwp[0]);
    for (int idx = t; idx < 512; idx += 256) {
        int row = idx >> 4, c = idx & 15;
        sk_s[row][c] = skv[(size_t)(m0 + row) * 384 + h * 16 + c];
    }
    if (t < 96) spm_s[t] = sp[(size_t)m0 * 3 + t];
    if (t < 32) smask_s[t] = smask[m0 + t];
    __syncthreads();
    float skr[4][16];
    float spx[4], spy[4], spz[4], smk[4];
    #pragma unroll
    for (int mi = 0; mi < 4; ++mi) {
        int row = tmg * 4 + mi;
        #pragma unroll
        for (int c4 = 0; c4 < 16; c4 += 4)
            *(float4*)&skr[mi][c4] = *(float4*)&sk_s[row][c4];
        spx[mi] = spm_s[row*3+0]; spy[mi] = spm_s[row*3+1]; spz[mi] = spm_s[row*3+2];
        smk[mi] = smask_s[row];
    }
    float mxr[4], lr[4];
    #pragma unroll
    for (int mi = 0; mi < 4; ++mi) { mxr[mi] = -1e30f; lr[mi] = 0.f; }
    for (int nt = 0; nt < 16; ++nt) {
        __syncthreads();
        const int nb = nt * 32;
        if (t < 128) {
            int nn = t >> 2, c4 = (t & 3) << 2;
            *(float4*)&sq_s[nn][c4] = *(const float4*)&sqw[(size_t)(nb + nn) * 192 + h * 16 + c4];
        }
        if (t < 96) trans_s[t] = trans[(size_t)nb * 3 + t];
        if (t < 32) mask_s[t] = mask[nb + t];
        __syncthreads();
        float q[16];
        #pragma unroll
        for (int c4 = 0; c4 < 16; c4 += 4)
            *(float4*)&q[c4] = *(float4*)&sq_s[tnl][c4];
        const float tx = trans_s[tnl*3+0], ty = trans_s[tnl*3+1], tz = trans_s[tnl*3+2];
        const float mkn = mask_s[tnl];
        #pragma unroll
        for (int mi = 0; mi < 4; ++mi) {
            float dot = 0.f;
            #pragma unroll
            for (int c = 0; c < 16; ++c) dot = fmaf(skr[mi][c], q[c], dot);
            float dx = tx - spx[mi], dy = ty - spy[mi], dz = tz - spz[mi];
            float mterm = INFV * (mkn * smk[mi] - 1.0f) - 0.5f * sbw * (dx*dx + dy*dy + dz*dz);
            float lg = fmaf(0.25f, dot, mterm);
            logits[((size_t)(m0 + tmg * 4 + mi) * 12 + h) * 512 + nb + tnl] = lg;
            float newm = fmaxf(mxr[mi], lg);
            lr[mi] = lr[mi] * __expf(mxr[mi] - newm) + __expf(lg - newm);
            mxr[mi] = newm;
        }
    }
    #pragma unroll
    for (int off = 1; off < 32; off <<= 1) {
        #pragma unroll
        for (int mi = 0; mi < 4; ++mi) {
            float m2 = __shfl_xor(mxr[mi], off), l2 = __shfl_xor(lr[mi], off);
            float newm = fmaxf(mxr[mi], m2);
            lr[mi] = lr[mi] * __expf(mxr[mi] - newm) + l2 * __expf(m2 - newm);
            mxr[mi] = newm;
        }
    }
    if (tnl == 0) {
        #pragma unroll
        for (int mi = 0; mi < 4; ++mi) {
            int m = m0 + tmg * 4 + mi;
            stat_m[(size_t)m * 12 + h] = mxr[mi];
            stat_il[(size_t)m * 12 + h] = 1.0f / lr[mi];
        }
    }
}

// ---------------------------------------------------------------- rstat
// partial row stats (max, sumexp) over m-chunk of 512 for each (h, n).
__global__ __launch_bounds__(256) void k_rstat(
    const float* __restrict__ lbuf, float* __restrict__ rspm,
    float* __restrict__ rsps)
{
    __shared__ float smx[4][64], ssm[4][64];
    const int n0 = blockIdx.x * 64, mc = blockIdx.y, h = blockIdx.z;
    const int t = threadIdx.x, ln = t & 63, mg = t >> 6;
    const int mb = mc * 512;
    const int n = n0 + ln;
    float mx = -1e30f, sm = 0.f;
    #pragma unroll 2
    for (int it = 0; it < 128; ++it) {
        int m = mb + it * 4 + mg;
        float lg = lbuf[((size_t)m * 12 + h) * 512 + n];
        float nm = fmaxf(mx, lg);
        sm = sm * __expf(mx - nm) + __expf(lg - nm);
        mx = nm;
    }
    smx[mg][ln] = mx; ssm[mg][ln] = sm;
    __syncthreads();
    if (t < 64) {
        float M = smx[0][t], S = ssm[0][t];
        #pragma unroll
        for (int g = 1; g < 4; ++g) {
            float m2 = smx[g][t], s2 = ssm[g][t];
            float nm = fmaxf(M, m2);
            S = S * __expf(M - nm) + s2 * __expf(m2 - nm);
            M = nm;
        }
        rspm[((size_t)h * 4 + mc) * 512 + n0 + t] = M;
        rsps[((size_t)h * 4 + mc) * 512 + n0 + t] = S;
    }
}

// ---------------------------------------------------------------- rcomb
__global__ __launch_bounds__(256) void k_rcomb(
    const float* __restrict__ rspm, const float* __restrict__ rsps,
    float* __restrict__ rmax, float* __restrict__ rinv)
{
    int gid = blockIdx.x * 256 + threadIdx.x;  // 6144 = 12h * 512n
    if (gid >= 6144) return;
    int h = gid >> 9, n = gid & 511;
    float M = -1e30f, S = 0.f;
    #pragma unroll
    for (int mc = 0; mc < 4; ++mc) {
        float m2 = rspm[((size_t)h * 4 + mc) * 512 + n];
        float s2 = rsps[((size_t)h * 4 + mc) * 512 + n];
        float nm = fmaxf(M, m2);
        S = S * __expf(M - nm) + s2 * __expf(m2 - nm);
        M = nm;
    }
    rmax[gid] = M;
    rinv[gid] = 1.0f / S;
}

// ---------------------------------------------------------------- pv
// partial o_surf: pvp[h][mc][n][16] = sum_{m in chunk} exp(l-mx)*inv * sv[m]
__global__ __launch_bounds__(256) void k_pv(
    const float* __restrict__ lbuf, const float* __restrict__ skv,
    const float* __restrict__ rmax, const float* __restrict__ rinv,
    float* __restrict__ pvp)
{
    __shared__ float sv_s[512][17];
    const int n0 = blockIdx.x * 64, mc = blockIdx.y, h = blockIdx.z;
    const int t = threadIdx.x, ln = t & 63, mg = t >> 6;
    const int mb = mc * 512;
    for (int idx = t; idx < 2048; idx += 256) {
        int ml = idx >> 2, c4 = (idx & 3) << 2;
        float4 v4 = *(const float4*)&skv[(size_t)(mb + ml) * 384 + 192 + h * 16 + c4];
        sv_s[ml][c4+0]=v4.x; sv_s[ml][c4+1]=v4.y; sv_s[ml][c4+2]=v4.z; sv_s[ml][c4+3]=v4.w;
    }
    const int n = n0 + ln;
    const float rm = rmax[h * 512 + n], ri = rinv[h * 512 + n];
    float acc[16];
    #pragma unroll
    for (int c = 0; c < 16; ++c) acc[c] = 0.f;
    __syncthreads();
    #pragma unroll 2
    for (int it = 0; it < 128; ++it) {
        int ml = it * 4 + mg;
        float w = __expf(lbuf[((size_t)(mb + ml) * 12 + h) * 512 + n] - rm) * ri;
        #pragma unroll
        for (int c = 0; c < 16; ++c) acc[c] = fmaf(w, sv_s[ml][c], acc[c]);
    }
    __syncthreads();
    // reduce 4 mg-partials via LDS (reuse sv_s as [4][64][17])
    float* red = &sv_s[0][0];
    #pragma unroll
    for (int c = 0; c < 16; ++c) red[(mg * 64 + ln) * 17 + c] = acc[c];
    __syncthreads();
    {
        int nl = t >> 2, c4 = (t & 3) << 2;
        float4 o;
        #pragma unroll
        for (int e = 0; e < 4; ++e) {
            float s = 0.f;
            #pragma unroll
            for (int g = 0; g < 4; ++g) s += red[(g * 64 + nl) * 17 + c4 + e];
            (&o.x)[e] = s;
        }
        *(float4*)&pvp[(((size_t)h * 4 + mc) * 512 + n0 + nl) * 16 + c4] = o;
    }
}

// ---------------------------------------------------------------- pvcomb
__global__ __launch_bounds__(256) void k_pvcomb(
    const float* __restrict__ pvp, float* __restrict__ ocat)
{
    int gid = blockIdx.x * 256 + threadIdx.x;  // 98304 = 512n * 192
    int n = gid / 192, rem = gid % 192;
    float o = 0.f;
    #pragma unroll
    for (int mc = 0; mc < 4; ++mc)
        o += pvp[(((size_t)(rem >> 4) * 4 + mc) * 512 + n) * 16 + (rem & 15)];
    ocat[(size_t)n * 1152 + 960 + rem] = o;
}

// ---------------------------------------------------------------- tw
__global__ __launch_bounds__(256) void k_tw(
    const float* __restrict__ logits, const float* __restrict__ stat_m,
    const float* __restrict__ stat_il, float* __restrict__ w)
{
    __shared__ float mxs[12], ils[12];
    const int m = blockIdx.x, t = threadIdx.x;
    if (t < 12) { mxs[t] = stat_m[(size_t)m * 12 + t]; ils[t] = stat_il[(size_t)m * 12 + t]; }
    __syncthreads();
    const float* lp = logits + (size_t)m * 12 * 512;
    float a0 = 0.f, a1 = 0.f;
    #pragma unroll
    for (int h = 0; h < 12; ++h) {
        a0 += __expf(lp[h * 512 + t] - mxs[h]) * ils[h];
        a1 += __expf(lp[h * 512 + 256 + t] - mxs[h]) * ils[h];
    }
    w[(size_t)m * 512 + t] = a0 * (1.0f / 12.0f);
    w[(size_t)m * 512 + 256 + t] = a1 * (1.0f / 12.0f);
}

// ---------------------------------------------------------------- surf out
__global__ __launch_bounds__(256) void k_surf_out(
    const float* __restrict__ sfeat, const float* __restrict__ saggw,
    const float* __restrict__ Wso, const float* __restrict__ bso,
    float* __restrict__ out)
{
    __shared__ float wl[12304];
    const int t = threadIdx.x;
    for (int idx = t; idx < 12288; idx += 256) {
        int k = idx >> 4, c = idx & 15;
        wl[(k / 192) * 3076 + (k % 192) * 16 + c] = Wso[idx];
    }
    const int m = blockIdx.x * 64 + (t >> 2);
    const int kq = t & 3;
    const float* src = (kq < 2) ? &sfeat[(size_t)m * 384 + kq * 192]
                                : &saggw[(size_t)m * 384 + (kq - 2) * 192];
    __syncthreads();
    float acc[16];
    #pragma unroll
    for (int c = 0; c < 16; ++c) acc[c] = 0.f;
    const float* wb = &wl[kq * 3076];
    for (int k = 0; k < 192; k += 4) {
        float4 v = *(const float4*)&src[k];
        #pragma unroll
        for (int e = 0; e < 4; ++e) {
            float sv = (&v.x)[e];
            #pragma unroll
            for (int c = 0; c < 16; ++c)
                acc[c] = fmaf(sv, wb[(k + e) * 16 + c], acc[c]);
        }
    }
    #pragma unroll
    for (int c = 0; c < 16; ++c) {
        acc[c] += __shfl_xor(acc[c], 1);
        acc[c] += __shfl_xor(acc[c], 2);
    }
    #pragma unroll
    for (int c = 0; c < 16; ++c) {
        if ((c >> 2) == kq) out[196608 + (size_t)m * 16 + c] = acc[c] + bso[c];
    }
}

// ----------------------------------------------------------------
extern "C" void kernel_launch(void* const* d_in, const int* in_sizes, int n_in,
                              void* d_out, int out_size, void* d_ws, size_t ws_size,
                              hipStream_t stream)
{
    (void)in_sizes; (void)n_in; (void)out_size; (void)ws_size;
    const float* s     = (const float*)d_in[0];
    const float* z     = (const float*)d_in[1];
    const float* rots  = (const float*)d_in[2];
    const float* trans = (const float*)d_in[3];
    const float* mask  = (const float*)d_in[4];
    const float* sp    = (const float*)d_in[5];
    const float* sf    = (const float*)d_in[6];
    const float* smask = (const float*)d_in[7];
    const float* Wq    = (const float*)d_in[8];  const float* bq   = (const float*)d_in[9];
    const float* Wkv   = (const float*)d_in[10]; const float* bkv  = (const float*)d_in[11];
    const float* Wqp   = (const float*)d_in[12]; const float* bqp  = (const float*)d_in[13];
    const float* Wkvp  = (const float*)d_in[14]; const float* bkvp = (const float*)d_in[15];
    const float* Wse   = (const float*)d_in[16]; const float* bse  = (const float*)d_in[17];
    const float* Wsq   = (const float*)d_in[18]; const float* bsq  = (const float*)d_in[19];
    const float* Wsk   = (const float*)d_in[20]; const float* bsk  = (const float*)d_in[21];
    const float* Wsv   = (const float*)d_in[22]; const float* bsv  = (const float*)d_in[23];
    const float* Wb    = (const float*)d_in[24]; const float* bb   = (const float*)d_in[25];
    const float* Wdz   = (const float*)d_in[26]; const float* bdz  = (const float*)d_in[27];
    const float* hw    = (const float*)d_in[28]; const float* sbw  = (const float*)d_in[29];
    const float* Wout  = (const float*)d_in[30]; const float* bout = (const float*)d_in[31];
    const float* Wso   = (const float*)d_in[32]; const float* bso  = (const float*)d_in[33];
    float* out = (float*)d_out;

    float* qw    = (float*)d_ws;
    float* kw    = qw    + (size_t)512 * 192;
    float* vw    = kw    + (size_t)512 * 192;
    float* sqw   = vw    + (size_t)512 * 192;
    float* qpw   = sqw   + (size_t)512 * 192;
    float* kpw   = qpw   + (size_t)512 * 144;
    float* vpw   = kpw   + (size_t)512 * 144;
    float* sfeat = vpw   + (size_t)512 * 288;
    float* skv   = sfeat + (size_t)2048 * 384;
    float* ocat  = skv   + (size_t)2048 * 384;
    float* sagg  = ocat  + (size_t)512 * 1152;
    // region: proj (688K fl) -> bpz (11.5M fl) -> logits (12.6M fl), stream-serialized
    float* region = sagg + (size_t)2048 * 384;
    float* proj   = region;
    float* bpz    = region;
    float* logits = region;
    float* wt1   = region + (size_t)2048 * 12 * 512;
    float* wt2   = wt1   + (size_t)1344 * 384;
    float* wt3   = wt2   + (size_t)384 * 384;
    float* b1    = wt3   + (size_t)384 * 1152;
    float* b2    = b1    + 1344;
    float* st    = b2    + 384;
    float* wbuf  = st    + (size_t)384 * 512;
    float* statm = wbuf  + (size_t)2048 * 512;
    float* stati = statm + (size_t)2048 * 12;
    float* abuf  = stati + (size_t)2048 * 12;      // a[12][512][512]
    float* cbuf  = abuf  + (size_t)12 * 512 * 512; // c[12][512][40]
    float* wz    = cbuf  + (size_t)12 * 512 * 40;  // Wz[44][128]
    float* bz    = wz    + (size_t)44 * 128;       // bz[44]
    float* rspm  = bz    + 64;                     // [12][4][512]
    float* rsps  = rspm  + (size_t)12 * 4 * 512;
    float* rmax  = rsps  + (size_t)12 * 4 * 512;   // [12][512]
    float* rinv  = rmax  + (size_t)12 * 512;
    float* pvp   = rinv  + (size_t)12 * 512;       // [12][4][512][16]

    k_pack<<<dim3(1099), dim3(256), 0, stream>>>(Wq, Wsq, Wkv, Wqp, Wkvp, Wsk, Wsv, Wout,
        bq, bsq, bkv, bqp, bkvp, bsk, bsv, wt1, wt2, wt3, b1, b2);
    k_packz<<<dim3(23), dim3(256), 0, stream>>>(Wb, bb, Wdz, bdz, wz, bz);
    k_transp<<<dim3(12, 16), dim3(256), 0, stream>>>(s, st);
    k_gemm<384, true><<<dim3(21, 8), dim3(256), 0, stream>>>(s, wt1, b1, proj, 1344);
    k_scatter<<<dim3(128), dim3(256), 0, stream>>>(proj, rots, trans,
        qw, kw, vw, sqw, qpw, kpw, vpw);
    k_sfeat<<<dim3(256), dim3(256), 0, stream>>>(sf, Wse, bse, sfeat);
    k_gemm<384, true><<<dim3(6, 32), dim3(256), 0, stream>>>(sfeat, wt2, b2, skv, 384);
    k_zpass<<<dim3(512, 2), dim3(256), 0, stream>>>(z, wz, bz, bpz);
    k_attn_a<<<dim3(512, 3), dim3(256), 0, stream>>>(qw, kw, qpw, kpw, bpz, mask, hw, abuf);
    k_attn_pair<<<dim3(512), dim3(256), 0, stream>>>(abuf, bpz, ocat);
    k_gemm_ov<<<dim3(8, 12), dim3(256), 0, stream>>>(abuf, vw, vpw, cbuf);
    k_optfin<<<dim3(128), dim3(256), 0, stream>>>(cbuf, rots, trans, ocat);
    k_tlog<<<dim3(64, 12), dim3(256), 0, stream>>>(sqw, skv, trans, mask, sp, smask,
        sbw, logits, statm, stati);
    k_rstat<<<dim3(8, 4, 12), dim3(256), 0, stream>>>(logits, rspm, rsps);
    k_rcomb<<<dim3(24), dim3(256), 0, stream>>>(rspm, rsps, rmax, rinv);
    k_pv<<<dim3(8, 4, 12), dim3(256), 0, stream>>>(logits, skv, rmax, rinv, pvp);
    k_pvcomb<<<dim3(384), dim3(256), 0, stream>>>(pvp, ocat);
    k_tw<<<dim3(2048), dim3(256), 0, stream>>>(logits, statm, stati, wbuf);
    k_gemm<512, false><<<dim3(6, 32), dim3(256), 0, stream>>>(wbuf, st, nullptr, sagg, 384);
    k_surf_out<<<dim3(32), dim3(256), 0, stream>>>(sfeat, sagg, Wso, bso, out);
    k_gemm<1152, true><<<dim3(6, 8), dim3(256), 0, stream>>>(ocat, wt3, bout, out, 384);
}